// Round 1
// baseline (519.169 us; speedup 1.0000x reference)
//
#include <hip/hip_runtime.h>

#define D_MODEL 1024
#define D_INNER 2048
#define N_ST    16
#define DT_RANK 64
#define BSZ     2
#define SEQL    1024
#define NTOK    (BSZ*SEQL)   // 2048

typedef __attribute__((ext_vector_type(4))) float f32x4;
typedef __attribute__((ext_vector_type(8))) short bf16x8;

__device__ __forceinline__ short f2b(float f) {
  unsigned u = __builtin_bit_cast(unsigned, f);
  u += 0x7fffu + ((u >> 16) & 1u);           // round-to-nearest-even
  return (short)(u >> 16);
}

#define BMT 128
#define BNT 128
#define BKT 32
#define LP  40   // padded LDS row stride in bf16 elems (80B, 16B-aligned)

// C[M,N] = epi(A[M,K]@B[K,N] + bias). fp32 in/out, bf16 MFMA inside.
// grid: (N/BNT, M/BMT, ksplit); ATOMIC=1 accumulates partials with atomicAdd
// (C must be zeroed first; bias added only by blockIdx.z==0).
template<int SOFTPLUS, int ATOMIC>
__global__ __launch_bounds__(256)
void gemm_kernel(const float* __restrict__ A, const float* __restrict__ B,
                 const float* __restrict__ bias, float* __restrict__ C,
                 int M, int N, int K, int lda, int ldb, int ldc, int kChunk)
{
  __shared__ short sA[BMT][LP];
  __shared__ short sB[BNT][LP];   // transposed: sB[n][k]
  const int tid  = threadIdx.x;
  const int lane = tid & 63;
  const int wave = tid >> 6;
  const int wr = wave >> 1, wc = wave & 1;
  const int lr = lane & 15, lg = lane >> 4;
  const int m0 = blockIdx.y * BMT;
  const int n0 = blockIdx.x * BNT;
  int kStart = blockIdx.z * kChunk;
  int kEnd   = kStart + kChunk; if (kEnd > K) kEnd = K;

  f32x4 acc[4][4];
#pragma unroll
  for (int i = 0; i < 4; ++i)
#pragma unroll
    for (int j = 0; j < 4; ++j) acc[i][j] = (f32x4){0.f, 0.f, 0.f, 0.f};

  for (int k0 = kStart; k0 < kEnd; k0 += BKT) {
    __syncthreads();
    // stage A tile [BMT][BKT], fp32->bf16
#pragma unroll
    for (int i = 0; i < 4; ++i) {
      int idx = tid + 256 * i;
      int row = idx >> 3, cv = idx & 7;
      const float4 v = *reinterpret_cast<const float4*>(
          A + (size_t)(m0 + row) * lda + k0 + cv * 4);
      *reinterpret_cast<short4*>(&sA[row][cv * 4]) =
          make_short4(f2b(v.x), f2b(v.y), f2b(v.z), f2b(v.w));
    }
    // stage B tile transposed into sB[n][k]
#pragma unroll
    for (int i = 0; i < 4; ++i) {
      int idx = tid + 256 * i;
      int nn = idx & 127, kg = idx >> 7;
      int gn = n0 + nn;
      float v0, v1, v2, v3;
      if (gn < N) {
        const float* src = B + (size_t)(k0 + kg * 4) * ldb + gn;
        v0 = src[0]; v1 = src[ldb]; v2 = src[2 * (size_t)ldb]; v3 = src[3 * (size_t)ldb];
      } else { v0 = v1 = v2 = v3 = 0.f; }
      *reinterpret_cast<short4*>(&sB[nn][kg * 4]) =
          make_short4(f2b(v0), f2b(v1), f2b(v2), f2b(v3));
    }
    __syncthreads();

    bf16x8 aF[4], bF[4];
#pragma unroll
    for (int mi = 0; mi < 4; ++mi)
      aF[mi] = *reinterpret_cast<const bf16x8*>(&sA[wr * 64 + mi * 16 + lr][lg * 8]);
#pragma unroll
    for (int ni = 0; ni < 4; ++ni)
      bF[ni] = *reinterpret_cast<const bf16x8*>(&sB[wc * 64 + ni * 16 + lr][lg * 8]);
#pragma unroll
    for (int mi = 0; mi < 4; ++mi)
#pragma unroll
      for (int ni = 0; ni < 4; ++ni)
        acc[mi][ni] = __builtin_amdgcn_mfma_f32_16x16x32_bf16(
            aF[mi], bF[ni], acc[mi][ni], 0, 0, 0);
  }

  // epilogue: C/D layout col=lane&15, row=(lane>>4)*4+reg
#pragma unroll
  for (int mi = 0; mi < 4; ++mi) {
    const int row = m0 + wr * 64 + mi * 16 + lg * 4;
#pragma unroll
    for (int ni = 0; ni < 4; ++ni) {
      const int col = n0 + wc * 64 + ni * 16 + lr;
      if (col < N) {
        float bv = (bias != nullptr && blockIdx.z == 0) ? bias[col] : 0.f;
#pragma unroll
        for (int j = 0; j < 4; ++j) {
          float v = acc[mi][ni][j] + bv;
          if (SOFTPLUS) v = fmaxf(v, 0.f) + log1pf(__expf(-fabsf(v)));
          if (ATOMIC) atomicAdd(&C[(size_t)(row + j) * ldc + col], v);
          else        C[(size_t)(row + j) * ldc + col] = v;
        }
      }
    }
  }
}

// causal depthwise conv(K=3) + bias + silu; xr=[2048][4096] (u_pre|res) -> u=[2048][2048]
__global__ __launch_bounds__(256)
void conv_silu_kernel(const float* __restrict__ xr, const float* __restrict__ cw,
                      const float* __restrict__ cb, float* __restrict__ u)
{
  int i  = blockIdx.x * 256 + threadIdx.x;   // over NTOK*512
  int t  = i >> 9;
  int dq = (i & 511) << 2;
  int l  = t & (SEQL - 1);
  float4 w0 = *reinterpret_cast<const float4*>(cw + dq * 3);
  float4 w1 = *reinterpret_cast<const float4*>(cw + dq * 3 + 4);
  float4 w2 = *reinterpret_cast<const float4*>(cw + dq * 3 + 8);
  float4 bb = *reinterpret_cast<const float4*>(cb + dq);
  float4 x2 = *reinterpret_cast<const float4*>(xr + (size_t)t * 4096 + dq);
  float4 x1 = (l >= 1) ? *reinterpret_cast<const float4*>(xr + (size_t)(t - 1) * 4096 + dq)
                       : make_float4(0.f, 0.f, 0.f, 0.f);
  float4 x0 = (l >= 2) ? *reinterpret_cast<const float4*>(xr + (size_t)(t - 2) * 4096 + dq)
                       : make_float4(0.f, 0.f, 0.f, 0.f);
  float r0 = bb.x + w0.x * x0.x + w0.y * x1.x + w0.z * x2.x;
  float r1 = bb.y + w0.w * x0.y + w1.x * x1.y + w1.y * x2.y;
  float r2 = bb.z + w1.z * x0.z + w1.w * x1.z + w2.x * x2.z;
  float r3 = bb.w + w2.y * x0.w + w2.z * x1.w + w2.w * x2.w;
  float4 o;
  o.x = r0 / (1.f + __expf(-r0));
  o.y = r1 / (1.f + __expf(-r1));
  o.z = r2 / (1.f + __expf(-r2));
  o.w = r3 / (1.f + __expf(-r3));
  *reinterpret_cast<float4*>(u + (size_t)t * 2048 + dq) = o;
}

// selective scan: thread=(b,d,n); 16 lanes (n) reduce via shfl_xor; PF=8 pipeline
__global__ __launch_bounds__(256)
void scan_kernel(const float* __restrict__ delta, const float* __restrict__ u,
                 const float* __restrict__ xp, const float* __restrict__ A_log,
                 float* __restrict__ y)
{
  const int tid  = threadIdx.x;
  const int n    = tid & 15, dloc = tid >> 4;
  const int b    = blockIdx.x >> 7;
  const int d    = ((blockIdx.x & 127) << 4) + dloc;
  const float Ac = -__expf(A_log[d * N_ST + n]);
  const int t0   = b << 10;
  const float* dp = delta + (size_t)t0 * 2048 + d;
  const float* up = u     + (size_t)t0 * 2048 + d;
  const float* bp = xp + (size_t)t0 * 96 + DT_RANK + n;
  const float* cp = xp + (size_t)t0 * 96 + DT_RANK + N_ST + n;
  float* yp = y + (size_t)t0 * 2048 + d;

  constexpr int PF = 8;
  float dl[PF], ul[PF], Bv[PF], Cv[PF];
#pragma unroll
  for (int j = 0; j < PF; ++j) {
    dl[j] = dp[j * 2048]; ul[j] = up[j * 2048];
    Bv[j] = bp[j * 96];   Cv[j] = cp[j * 96];
  }
  float h = 0.f;
  for (int lb = 0; lb < SEQL; lb += PF) {
    float dln[PF], uln[PF], Bvn[PF], Cvn[PF];
    const int nb = lb + PF;
    if (nb < SEQL) {
#pragma unroll
      for (int j = 0; j < PF; ++j) {
        dln[j] = dp[(size_t)(nb + j) * 2048]; uln[j] = up[(size_t)(nb + j) * 2048];
        Bvn[j] = bp[(nb + j) * 96];           Cvn[j] = cp[(nb + j) * 96];
      }
    } else {
#pragma unroll
      for (int j = 0; j < PF; ++j) { dln[j] = uln[j] = Bvn[j] = Cvn[j] = 0.f; }
    }
#pragma unroll
    for (int j = 0; j < PF; ++j) {
      float dA = __expf(dl[j] * Ac);
      h = dA * h + dl[j] * Bv[j] * ul[j];
      float p = h * Cv[j];
      p += __shfl_xor(p, 1, 16);
      p += __shfl_xor(p, 2, 16);
      p += __shfl_xor(p, 4, 16);
      p += __shfl_xor(p, 8, 16);
      if (n == 0) yp[(size_t)(lb + j) * 2048] = p;
    }
#pragma unroll
    for (int j = 0; j < PF; ++j) { dl[j] = dln[j]; ul[j] = uln[j]; Bv[j] = Bvn[j]; Cv[j] = Cvn[j]; }
  }
}

// z = y * silu(res); res = xr[:, 2048:]
__global__ __launch_bounds__(256)
void zmul_kernel(const float* __restrict__ y, const float* __restrict__ xr,
                 float* __restrict__ z)
{
  int i  = blockIdx.x * 256 + threadIdx.x;
  int t  = i >> 9;
  int dq = (i & 511) << 2;
  float4 yv = *reinterpret_cast<const float4*>(y  + (size_t)t * 2048 + dq);
  float4 rv = *reinterpret_cast<const float4*>(xr + (size_t)t * 4096 + 2048 + dq);
  float4 o;
  o.x = yv.x * (rv.x / (1.f + __expf(-rv.x)));
  o.y = yv.y * (rv.y / (1.f + __expf(-rv.y)));
  o.z = yv.z * (rv.z / (1.f + __expf(-rv.z)));
  o.w = yv.w * (rv.w / (1.f + __expf(-rv.w)));
  *reinterpret_cast<float4*>(z + (size_t)t * 2048 + dq) = o;
}

extern "C" void kernel_launch(void* const* d_in, const int* in_sizes, int n_in,
                              void* d_out, int out_size, void* d_ws, size_t ws_size,
                              hipStream_t stream)
{
  const float* x      = (const float*)d_in[0];
  const float* A_log  = (const float*)d_in[1];
  const float* W_in   = (const float*)d_in[2];
  const float* b_in   = (const float*)d_in[3];
  const float* conv_w = (const float*)d_in[4];
  const float* conv_b = (const float*)d_in[5];
  const float* W_x    = (const float*)d_in[6];
  const float* W_dt   = (const float*)d_in[7];
  const float* b_dt   = (const float*)d_in[8];
  const float* W_out  = (const float*)d_in[9];
  const float* b_out  = (const float*)d_in[10];
  float* out = (float*)d_out;

  // workspace layout (~81 MB)
  char* p = (char*)d_ws;
  float* xr    = (float*)p; p += (size_t)NTOK * 4096 * 4;   // 32MB u_pre|res
  float* u     = (float*)p; p += (size_t)NTOK * 2048 * 4;   // 16MB
  float* xp    = (float*)p; p += (size_t)NTOK * 96 * 4;     // .75MB dt|B|C
  float* delta = (float*)p; p += (size_t)NTOK * 2048 * 4;   // 16MB
  float* y     = (float*)p; p += (size_t)NTOK * 2048 * 4;   // 16MB
  float* z     = u;  // u dead after scan

  hipMemsetAsync(xp,  0, (size_t)NTOK * 96 * 4, stream);
  hipMemsetAsync(out, 0, (size_t)NTOK * 1024 * 4, stream);

  // xr = x @ W_in + b_in
  gemm_kernel<0, 0><<<dim3(32, 16, 1), 256, 0, stream>>>(
      x, W_in, b_in, xr, NTOK, 4096, 1024, 1024, 4096, 4096, 1024);
  // u = silu(conv(u_pre) + conv_b)
  conv_silu_kernel<<<dim3(4096), 256, 0, stream>>>(xr, conv_w, conv_b, u);
  // xp = u @ W_x   (split-K 8, atomic)
  gemm_kernel<0, 1><<<dim3(1, 16, 8), 256, 0, stream>>>(
      u, W_x, nullptr, xp, NTOK, 96, 2048, 2048, 96, 96, 256);
  // delta = softplus(dt @ W_dt + b_dt)
  gemm_kernel<1, 0><<<dim3(16, 16, 1), 256, 0, stream>>>(
      xp, W_dt, b_dt, delta, NTOK, 2048, 64, 96, 2048, 2048, 64);
  // selective scan -> y
  scan_kernel<<<dim3(256), 256, 0, stream>>>(delta, u, xp, A_log, y);
  // z = y * silu(res)
  zmul_kernel<<<dim3(4096), 256, 0, stream>>>(y, xr, z);
  // out = z @ W_out + b_out   (split-K 2, atomic)
  gemm_kernel<0, 1><<<dim3(8, 16, 2), 256, 0, stream>>>(
      z, W_out, b_out, out, NTOK, 1024, 2048, 2048, 1024, 1024, 1024);
}

// Round 2
// 418.421 us; speedup vs baseline: 1.2408x; 1.2408x over previous
//
#include <hip/hip_runtime.h>

#define D_MODEL 1024
#define D_INNER 2048
#define N_ST    16
#define DT_RANK 64
#define BSZ     2
#define SEQL    1024
#define NTOK    (BSZ*SEQL)   // 2048
#define NC      16           // scan chunks
#define LC      (SEQL/NC)    // 64 steps per chunk

typedef __attribute__((ext_vector_type(4))) float f32x4;
typedef __attribute__((ext_vector_type(8))) short bf16x8;

__device__ __forceinline__ short f2b(float f) {
  unsigned u = __builtin_bit_cast(unsigned, f);
  u += 0x7fffu + ((u >> 16) & 1u);           // round-to-nearest-even
  return (short)(u >> 16);
}

#define BMT 128
#define BNT 128
#define BKT 32
#define LP  40   // padded LDS row stride in bf16 elems (80B, 16B-aligned)

// C[M,N] = epi(A[M,K]@B[K,N] + bias). fp32 in/out, bf16 MFMA inside.
template<int SOFTPLUS, int ATOMIC>
__global__ __launch_bounds__(256)
void gemm_kernel(const float* __restrict__ A, const float* __restrict__ B,
                 const float* __restrict__ bias, float* __restrict__ C,
                 int M, int N, int K, int lda, int ldb, int ldc, int kChunk)
{
  __shared__ short sA[BMT][LP];
  __shared__ short sB[BNT][LP];   // transposed: sB[n][k]
  const int tid  = threadIdx.x;
  const int lane = tid & 63;
  const int wave = tid >> 6;
  const int wr = wave >> 1, wc = wave & 1;
  const int lr = lane & 15, lg = lane >> 4;
  const int m0 = blockIdx.y * BMT;
  const int n0 = blockIdx.x * BNT;
  int kStart = blockIdx.z * kChunk;
  int kEnd   = kStart + kChunk; if (kEnd > K) kEnd = K;

  f32x4 acc[4][4];
#pragma unroll
  for (int i = 0; i < 4; ++i)
#pragma unroll
    for (int j = 0; j < 4; ++j) acc[i][j] = (f32x4){0.f, 0.f, 0.f, 0.f};

  for (int k0 = kStart; k0 < kEnd; k0 += BKT) {
    __syncthreads();
#pragma unroll
    for (int i = 0; i < 4; ++i) {
      int idx = tid + 256 * i;
      int row = idx >> 3, cv = idx & 7;
      const float4 v = *reinterpret_cast<const float4*>(
          A + (size_t)(m0 + row) * lda + k0 + cv * 4);
      *reinterpret_cast<short4*>(&sA[row][cv * 4]) =
          make_short4(f2b(v.x), f2b(v.y), f2b(v.z), f2b(v.w));
    }
#pragma unroll
    for (int i = 0; i < 4; ++i) {
      int idx = tid + 256 * i;
      int nn = idx & 127, kg = idx >> 7;
      int gn = n0 + nn;
      float v0, v1, v2, v3;
      if (gn < N) {
        const float* src = B + (size_t)(k0 + kg * 4) * ldb + gn;
        v0 = src[0]; v1 = src[ldb]; v2 = src[2 * (size_t)ldb]; v3 = src[3 * (size_t)ldb];
      } else { v0 = v1 = v2 = v3 = 0.f; }
      *reinterpret_cast<short4*>(&sB[nn][kg * 4]) =
          make_short4(f2b(v0), f2b(v1), f2b(v2), f2b(v3));
    }
    __syncthreads();

    bf16x8 aF[4], bF[4];
#pragma unroll
    for (int mi = 0; mi < 4; ++mi)
      aF[mi] = *reinterpret_cast<const bf16x8*>(&sA[wr * 64 + mi * 16 + lr][lg * 8]);
#pragma unroll
    for (int ni = 0; ni < 4; ++ni)
      bF[ni] = *reinterpret_cast<const bf16x8*>(&sB[wc * 64 + ni * 16 + lr][lg * 8]);
#pragma unroll
    for (int mi = 0; mi < 4; ++mi)
#pragma unroll
      for (int ni = 0; ni < 4; ++ni)
        acc[mi][ni] = __builtin_amdgcn_mfma_f32_16x16x32_bf16(
            aF[mi], bF[ni], acc[mi][ni], 0, 0, 0);
  }

#pragma unroll
  for (int mi = 0; mi < 4; ++mi) {
    const int row = m0 + wr * 64 + mi * 16 + lg * 4;
#pragma unroll
    for (int ni = 0; ni < 4; ++ni) {
      const int col = n0 + wc * 64 + ni * 16 + lr;
      if (col < N) {
        float bv = (bias != nullptr && blockIdx.z == 0) ? bias[col] : 0.f;
#pragma unroll
        for (int j = 0; j < 4; ++j) {
          float v = acc[mi][ni][j] + bv;
          if (SOFTPLUS) v = fmaxf(v, 0.f) + log1pf(__expf(-fabsf(v)));
          if (ATOMIC) atomicAdd(&C[(size_t)(row + j) * ldc + col], v);
          else        C[(size_t)(row + j) * ldc + col] = v;
        }
      }
    }
  }
}

// causal depthwise conv(K=3) + bias + silu
__global__ __launch_bounds__(256)
void conv_silu_kernel(const float* __restrict__ xr, const float* __restrict__ cw,
                      const float* __restrict__ cb, float* __restrict__ u)
{
  int i  = blockIdx.x * 256 + threadIdx.x;
  int t  = i >> 9;
  int dq = (i & 511) << 2;
  int l  = t & (SEQL - 1);
  float4 w0 = *reinterpret_cast<const float4*>(cw + dq * 3);
  float4 w1 = *reinterpret_cast<const float4*>(cw + dq * 3 + 4);
  float4 w2 = *reinterpret_cast<const float4*>(cw + dq * 3 + 8);
  float4 bb = *reinterpret_cast<const float4*>(cb + dq);
  float4 x2 = *reinterpret_cast<const float4*>(xr + (size_t)t * 4096 + dq);
  float4 x1 = (l >= 1) ? *reinterpret_cast<const float4*>(xr + (size_t)(t - 1) * 4096 + dq)
                       : make_float4(0.f, 0.f, 0.f, 0.f);
  float4 x0 = (l >= 2) ? *reinterpret_cast<const float4*>(xr + (size_t)(t - 2) * 4096 + dq)
                       : make_float4(0.f, 0.f, 0.f, 0.f);
  float r0 = bb.x + w0.x * x0.x + w0.y * x1.x + w0.z * x2.x;
  float r1 = bb.y + w0.w * x0.y + w1.x * x1.y + w1.y * x2.y;
  float r2 = bb.z + w1.z * x0.z + w1.w * x1.z + w2.x * x2.z;
  float r3 = bb.w + w2.y * x0.w + w2.z * x1.w + w2.w * x2.w;
  float4 o;
  o.x = r0 / (1.f + __expf(-r0));
  o.y = r1 / (1.f + __expf(-r1));
  o.z = r2 / (1.f + __expf(-r2));
  o.w = r3 / (1.f + __expf(-r3));
  *reinterpret_cast<float4*>(u + (size_t)t * 2048 + dq) = o;
}

// ---- chunked selective scan ----
// pass1: per (b,d,n,chunk) local scan from h=0 -> P = prod(dA), S = h_end
__global__ __launch_bounds__(256)
void scan_pass1(const float* __restrict__ delta, const float* __restrict__ u,
                const float* __restrict__ xp, const float* __restrict__ A_log,
                float* __restrict__ Pbuf, float* __restrict__ Sbuf)
{
  const int tid = threadIdx.x;
  const int n = tid & 15, dloc = tid >> 4;
  const int c = blockIdx.x;
  const int d = blockIdx.y * 16 + dloc;
  const int b = blockIdx.z;
  const float Ac = -__expf(A_log[d * N_ST + n]);
  const int t0 = (b << 10) + c * LC;
  const float* dp = delta + (size_t)t0 * 2048 + d;
  const float* up = u     + (size_t)t0 * 2048 + d;
  const float* bp = xp + (size_t)t0 * 96 + DT_RANK + n;
  float h = 0.f, P = 1.f;
  for (int lb = 0; lb < LC; lb += 8) {
#pragma unroll
    for (int j = 0; j < 8; ++j) {
      const int t = lb + j;
      float dl = dp[(size_t)t * 2048];
      float ul = up[(size_t)t * 2048];
      float Bv = bp[(size_t)t * 96];
      float dA = __expf(dl * Ac);
      h = dA * h + dl * Bv * ul;
      P *= dA;
    }
  }
  const int idx = ((b * NC + c) * 2048 + d) * 16 + n;
  Pbuf[idx] = P;
  Sbuf[idx] = h;
}

// pass2: sequential combine over chunks -> Hinit per (b,d,n,chunk)
__global__ __launch_bounds__(256)
void scan_pass2(const float* __restrict__ Pbuf, const float* __restrict__ Sbuf,
                float* __restrict__ Hinit)
{
  const int gid = blockIdx.x * 256 + threadIdx.x;  // 0..65535
  const int b = gid >> 15, rest = gid & 32767;
  float h = 0.f;
#pragma unroll
  for (int c = 0; c < NC; ++c) {
    const int idx = ((b * NC + c) << 15) + rest;
    Hinit[idx] = h;
    h = Pbuf[idx] * h + Sbuf[idx];
  }
}

// pass3: local scan from Hinit, n-reduce, fused z = y*silu(res)
__global__ __launch_bounds__(256)
void scan_pass3(const float* __restrict__ delta, const float* __restrict__ u,
                const float* __restrict__ xp, const float* __restrict__ A_log,
                const float* __restrict__ Hinit, const float* __restrict__ xr,
                float* __restrict__ z)
{
  const int tid = threadIdx.x;
  const int n = tid & 15, dloc = tid >> 4;
  const int c = blockIdx.x;
  const int d = blockIdx.y * 16 + dloc;
  const int b = blockIdx.z;
  const float Ac = -__expf(A_log[d * N_ST + n]);
  const int t0 = (b << 10) + c * LC;
  const float* dp = delta + (size_t)t0 * 2048 + d;
  const float* up = u     + (size_t)t0 * 2048 + d;
  const float* bp = xp + (size_t)t0 * 96 + DT_RANK + n;
  const float* cp = xp + (size_t)t0 * 96 + DT_RANK + N_ST + n;
  const float* rp = xr + (size_t)t0 * 4096 + 2048 + d;
  float* zp = z + (size_t)t0 * 2048 + d;
  float h = Hinit[((b * NC + c) * 2048 + d) * 16 + n];
  for (int lb = 0; lb < LC; lb += 8) {
#pragma unroll
    for (int j = 0; j < 8; ++j) {
      const int t = lb + j;
      float dl = dp[(size_t)t * 2048];
      float ul = up[(size_t)t * 2048];
      float Bv = bp[(size_t)t * 96];
      float Cv = cp[(size_t)t * 96];
      float rv = rp[(size_t)t * 4096];
      float dA = __expf(dl * Ac);
      h = dA * h + dl * Bv * ul;
      float p = h * Cv;
      p += __shfl_xor(p, 1, 16);
      p += __shfl_xor(p, 2, 16);
      p += __shfl_xor(p, 4, 16);
      p += __shfl_xor(p, 8, 16);
      if (n == 0) zp[(size_t)t * 2048] = p * (rv / (1.f + __expf(-rv)));
    }
  }
}

extern "C" void kernel_launch(void* const* d_in, const int* in_sizes, int n_in,
                              void* d_out, int out_size, void* d_ws, size_t ws_size,
                              hipStream_t stream)
{
  const float* x      = (const float*)d_in[0];
  const float* A_log  = (const float*)d_in[1];
  const float* W_in   = (const float*)d_in[2];
  const float* b_in   = (const float*)d_in[3];
  const float* conv_w = (const float*)d_in[4];
  const float* conv_b = (const float*)d_in[5];
  const float* W_x    = (const float*)d_in[6];
  const float* W_dt   = (const float*)d_in[7];
  const float* b_dt   = (const float*)d_in[8];
  const float* W_out  = (const float*)d_in[9];
  const float* b_out  = (const float*)d_in[10];
  float* out = (float*)d_out;

  // workspace layout (~93 MB)
  char* p = (char*)d_ws;
  float* xr    = (float*)p; p += (size_t)NTOK * 4096 * 4;   // 32MB u_pre|res
  float* u     = (float*)p; p += (size_t)NTOK * 2048 * 4;   // 16MB
  float* xp    = (float*)p; p += (size_t)NTOK * 96 * 4;     // .75MB dt|B|C
  float* delta = (float*)p; p += (size_t)NTOK * 2048 * 4;   // 16MB
  float* z     = (float*)p; p += (size_t)NTOK * 2048 * 4;   // 16MB
  float* Pbuf  = (float*)p; p += (size_t)BSZ * NC * 2048 * 16 * 4;  // 4MB
  float* Sbuf  = (float*)p; p += (size_t)BSZ * NC * 2048 * 16 * 4;  // 4MB
  float* Hinit = (float*)p; p += (size_t)BSZ * NC * 2048 * 16 * 4;  // 4MB

  hipMemsetAsync(xp,  0, (size_t)NTOK * 96 * 4, stream);
  hipMemsetAsync(out, 0, (size_t)NTOK * 1024 * 4, stream);

  // xr = x @ W_in + b_in
  gemm_kernel<0, 0><<<dim3(32, 16, 1), 256, 0, stream>>>(
      x, W_in, b_in, xr, NTOK, 4096, 1024, 1024, 4096, 4096, 1024);
  // u = silu(conv(u_pre) + conv_b)
  conv_silu_kernel<<<dim3(4096), 256, 0, stream>>>(xr, conv_w, conv_b, u);
  // xp = u @ W_x   (split-K 8, atomic)
  gemm_kernel<0, 1><<<dim3(1, 16, 8), 256, 0, stream>>>(
      u, W_x, nullptr, xp, NTOK, 96, 2048, 2048, 96, 96, 256);
  // delta = softplus(dt @ W_dt + b_dt)
  gemm_kernel<1, 0><<<dim3(16, 16, 1), 256, 0, stream>>>(
      xp, W_dt, b_dt, delta, NTOK, 2048, 64, 96, 2048, 2048, 64);
  // chunked selective scan -> z (zmul fused into pass3)
  scan_pass1<<<dim3(NC, 128, BSZ), 256, 0, stream>>>(delta, u, xp, A_log, Pbuf, Sbuf);
  scan_pass2<<<dim3(256), 256, 0, stream>>>(Pbuf, Sbuf, Hinit);
  scan_pass3<<<dim3(NC, 128, BSZ), 256, 0, stream>>>(delta, u, xp, A_log, Hinit, xr, z);
  // out = z @ W_out + b_out   (split-K 2, atomic)
  gemm_kernel<0, 1><<<dim3(8, 16, 2), 256, 0, stream>>>(
      z, W_out, b_out, out, NTOK, 1024, 2048, 2048, 1024, 1024, 1024);
}

// Round 4
// 288.877 us; speedup vs baseline: 1.7972x; 1.4484x over previous
//
#include <hip/hip_runtime.h>

#define D_MODEL 1024
#define D_INNER 2048
#define N_ST    16
#define DT_RANK 64
#define BSZ     2
#define SEQL    1024
#define NTOK    (BSZ*SEQL)   // 2048
#define NC      16           // scan chunks
#define LC      (SEQL/NC)    // 64 steps per chunk

typedef __attribute__((ext_vector_type(4))) float f32x4;
typedef __attribute__((ext_vector_type(8))) short bf16x8;

__device__ __forceinline__ short f2b(float f) {
  unsigned u = __builtin_bit_cast(unsigned, f);
  u += 0x7fffu + ((u >> 16) & 1u);           // round-to-nearest-even
  return (short)(u >> 16);
}

__device__ __forceinline__ void gload16(const void* g, void* l) {
  __builtin_amdgcn_global_load_lds(
      (const __attribute__((address_space(1))) void*)g,
      (__attribute__((address_space(3))) void*)l, 16, 0, 0);
}

#define BMT 128
#define BNT 128
#define BKT 32

// C[M,N] = epi(A[M,K] @ B[N,K]^T + bias); A,B bf16 (B pre-transposed), C fp32.
// m97 structure: global_load_lds staging, linear LDS, ds_read_b128 frags.
template<int SOFTPLUS, int ATOMIC>
__global__ __launch_bounds__(256)
void gemm_kernel(const short* __restrict__ A, const short* __restrict__ Bm,
                 const float* __restrict__ bias, float* __restrict__ C,
                 int M, int N, int K, int lda, int ldb, int ldc, int kChunk)
{
  __shared__ short sA[BMT * BKT];   // 8 KB, linear [row][k]
  __shared__ short sB[BNT * BKT];   // 8 KB, linear [n][k]
  const int tid  = threadIdx.x;
  const int lane = tid & 63;
  const int wave = tid >> 6;
  const int wr = wave >> 1, wc = wave & 1;
  const int lr = lane & 15, lg = lane >> 4;
  const int m0 = blockIdx.y * BMT;
  const int n0 = blockIdx.x * BNT;
  const int kStart = blockIdx.z * kChunk;
  int kEnd = kStart + kChunk; if (kEnd > K) kEnd = K;

  // staging geometry: wave covers chunks {2w, 2w+1}; chunk = 16 rows x 32 k (1 KB)
  const int srow = lane >> 2;          // row within chunk
  const int scol = (lane & 3) * 8;     // bf16 col within row
  const short* aS0 = A + (size_t)(m0 + wave * 32 + srow) * lda + scol + kStart;
  const short* aS1 = aS0 + (size_t)16 * lda;
  const short* bS0 = Bm + (size_t)(n0 + wave * 32 + srow) * ldb + scol + kStart;
  const short* bS1 = bS0 + (size_t)16 * ldb;
  short* aD0 = &sA[wave * 1024];
  short* aD1 = &sA[wave * 1024 + 512];
  short* bD0 = &sB[wave * 1024];
  short* bD1 = &sB[wave * 1024 + 512];

  f32x4 acc[4][4];
#pragma unroll
  for (int i = 0; i < 4; ++i)
#pragma unroll
    for (int j = 0; j < 4; ++j) acc[i][j] = (f32x4){0.f, 0.f, 0.f, 0.f};

  for (int k0 = kStart; k0 < kEnd; k0 += BKT) {
    __syncthreads();
    gload16(aS0, aD0); gload16(aS1, aD1);
    gload16(bS0, bD0); gload16(bS1, bD1);
    aS0 += BKT; aS1 += BKT; bS0 += BKT; bS1 += BKT;
    __syncthreads();

    bf16x8 aF[4], bF[4];
#pragma unroll
    for (int mi = 0; mi < 4; ++mi)
      aF[mi] = *reinterpret_cast<const bf16x8*>(&sA[(wr * 64 + mi * 16 + lr) * 32 + lg * 8]);
#pragma unroll
    for (int ni = 0; ni < 4; ++ni)
      bF[ni] = *reinterpret_cast<const bf16x8*>(&sB[(wc * 64 + ni * 16 + lr) * 32 + lg * 8]);
#pragma unroll
    for (int mi = 0; mi < 4; ++mi)
#pragma unroll
      for (int ni = 0; ni < 4; ++ni)
        acc[mi][ni] = __builtin_amdgcn_mfma_f32_16x16x32_bf16(
            aF[mi], bF[ni], acc[mi][ni], 0, 0, 0);
  }

  // epilogue: C/D layout col=lane&15, row=(lane>>4)*4+reg
#pragma unroll
  for (int mi = 0; mi < 4; ++mi) {
    const int row = m0 + wr * 64 + mi * 16 + lg * 4;
#pragma unroll
    for (int ni = 0; ni < 4; ++ni) {
      const int col = n0 + wc * 64 + ni * 16 + lr;
      if (col < N) {
        float bv = (bias != nullptr && blockIdx.z == 0) ? bias[col] : 0.f;
#pragma unroll
        for (int j = 0; j < 4; ++j) {
          float v = acc[mi][ni][j] + bv;
          if (SOFTPLUS) v = fmaxf(v, 0.f) + log1pf(__expf(-fabsf(v)));
          if (ATOMIC) atomicAdd(&C[(size_t)(row + j) * ldc + col], v);
          else        C[(size_t)(row + j) * ldc + col] = v;
        }
      }
    }
  }
}

// straight cast fp32 -> bf16, 4 elems/thread
__global__ __launch_bounds__(256)
void castA_kernel(const float* __restrict__ in, short* __restrict__ out)
{
  int i = blockIdx.x * 256 + threadIdx.x;
  float4 v = *reinterpret_cast<const float4*>(in + (size_t)i * 4);
  *reinterpret_cast<short4*>(out + (size_t)i * 4) =
      make_short4(f2b(v.x), f2b(v.y), f2b(v.z), f2b(v.w));
}

// transpose-cast: in[R][C] fp32 -> out[C][R] bf16; grid = (C/32, R/32)
__global__ __launch_bounds__(256)
void transW_kernel(const float* __restrict__ in, short* __restrict__ out, int R, int C)
{
  __shared__ short t[32][33];
  const int c0 = blockIdx.x * 32, r0 = blockIdx.y * 32;
  const int cc = threadIdx.x & 31, rr = threadIdx.x >> 5;  // rr 0..7
#pragma unroll
  for (int i = 0; i < 4; ++i)
    t[rr + i * 8][cc] = f2b(in[(size_t)(r0 + rr + i * 8) * C + c0 + cc]);
  __syncthreads();
#pragma unroll
  for (int i = 0; i < 4; ++i)
    out[(size_t)(c0 + rr + i * 8) * R + r0 + cc] = t[cc][rr + i * 8];
}

// dt slice of xp -> bf16 [2048][64]
__global__ __launch_bounds__(256)
void castDT_kernel(const float* __restrict__ xp, short* __restrict__ dtb)
{
  int i = blockIdx.x * 256 + threadIdx.x;    // over 2048*16
  int r = i >> 4, q = i & 15;
  float4 v = *reinterpret_cast<const float4*>(xp + (size_t)r * 96 + q * 4);
  *reinterpret_cast<short4*>(dtb + (size_t)r * 64 + q * 4) =
      make_short4(f2b(v.x), f2b(v.y), f2b(v.z), f2b(v.w));
}

// causal depthwise conv(K=3) + bias + silu; writes u fp32 (scan) and bf16 (GEMM2)
__global__ __launch_bounds__(256)
void conv_silu_kernel(const float* __restrict__ xr, const float* __restrict__ cw,
                      const float* __restrict__ cb, float* __restrict__ u,
                      short* __restrict__ ub)
{
  int i  = blockIdx.x * 256 + threadIdx.x;
  int t  = i >> 9;
  int dq = (i & 511) << 2;
  int l  = t & (SEQL - 1);
  float4 w0 = *reinterpret_cast<const float4*>(cw + dq * 3);
  float4 w1 = *reinterpret_cast<const float4*>(cw + dq * 3 + 4);
  float4 w2 = *reinterpret_cast<const float4*>(cw + dq * 3 + 8);
  float4 bb = *reinterpret_cast<const float4*>(cb + dq);
  float4 x2 = *reinterpret_cast<const float4*>(xr + (size_t)t * 4096 + dq);
  float4 x1 = (l >= 1) ? *reinterpret_cast<const float4*>(xr + (size_t)(t - 1) * 4096 + dq)
                       : make_float4(0.f, 0.f, 0.f, 0.f);
  float4 x0 = (l >= 2) ? *reinterpret_cast<const float4*>(xr + (size_t)(t - 2) * 4096 + dq)
                       : make_float4(0.f, 0.f, 0.f, 0.f);
  float r0 = bb.x + w0.x * x0.x + w0.y * x1.x + w0.z * x2.x;
  float r1 = bb.y + w0.w * x0.y + w1.x * x1.y + w1.y * x2.y;
  float r2 = bb.z + w1.z * x0.z + w1.w * x1.z + w2.x * x2.z;
  float r3 = bb.w + w2.y * x0.w + w2.z * x1.w + w2.w * x2.w;
  float4 o;
  o.x = r0 / (1.f + __expf(-r0));
  o.y = r1 / (1.f + __expf(-r1));
  o.z = r2 / (1.f + __expf(-r2));
  o.w = r3 / (1.f + __expf(-r3));
  *reinterpret_cast<float4*>(u + (size_t)t * 2048 + dq) = o;
  *reinterpret_cast<short4*>(ub + (size_t)t * 2048 + dq) =
      make_short4(f2b(o.x), f2b(o.y), f2b(o.z), f2b(o.w));
}

// ---- chunked selective scan ----
__global__ __launch_bounds__(256)
void scan_pass1(const float* __restrict__ delta, const float* __restrict__ u,
                const float* __restrict__ xp, const float* __restrict__ A_log,
                float* __restrict__ Pbuf, float* __restrict__ Sbuf)
{
  const int tid = threadIdx.x;
  const int n = tid & 15, dloc = tid >> 4;
  const int c = blockIdx.x;
  const int d = blockIdx.y * 16 + dloc;
  const int b = blockIdx.z;
  const float Ac = -__expf(A_log[d * N_ST + n]);
  const int t0 = (b << 10) + c * LC;
  const float* dp = delta + (size_t)t0 * 2048 + d;
  const float* up = u     + (size_t)t0 * 2048 + d;
  const float* bp = xp + (size_t)t0 * 96 + DT_RANK + n;
  float h = 0.f, P = 1.f;
  for (int lb = 0; lb < LC; lb += 8) {
#pragma unroll
    for (int j = 0; j < 8; ++j) {
      const int t = lb + j;
      float dl = dp[(size_t)t * 2048];
      float ul = up[(size_t)t * 2048];
      float Bv = bp[(size_t)t * 96];
      float dA = __expf(dl * Ac);
      h = dA * h + dl * Bv * ul;
      P *= dA;
    }
  }
  const int idx = ((b * NC + c) * 2048 + d) * 16 + n;
  Pbuf[idx] = P;
  Sbuf[idx] = h;
}

__global__ __launch_bounds__(256)
void scan_pass2(const float* __restrict__ Pbuf, const float* __restrict__ Sbuf,
                float* __restrict__ Hinit)
{
  const int gid = blockIdx.x * 256 + threadIdx.x;  // 0..65535
  const int b = gid >> 15, rest = gid & 32767;
  float h = 0.f;
#pragma unroll
  for (int c = 0; c < NC; ++c) {
    const int idx = ((b * NC + c) << 15) + rest;
    Hinit[idx] = h;
    h = Pbuf[idx] * h + Sbuf[idx];
  }
}

// pass3: local scan from Hinit, n-reduce, fused z = y*silu(res), bf16 out
__global__ __launch_bounds__(256)
void scan_pass3(const float* __restrict__ delta, const float* __restrict__ u,
                const float* __restrict__ xp, const float* __restrict__ A_log,
                const float* __restrict__ Hinit, const float* __restrict__ xr,
                short* __restrict__ zb)
{
  const int tid = threadIdx.x;
  const int n = tid & 15, dloc = tid >> 4;
  const int c = blockIdx.x;
  const int d = blockIdx.y * 16 + dloc;
  const int b = blockIdx.z;
  const float Ac = -__expf(A_log[d * N_ST + n]);
  const int t0 = (b << 10) + c * LC;
  const float* dp = delta + (size_t)t0 * 2048 + d;
  const float* up = u     + (size_t)t0 * 2048 + d;
  const float* bp = xp + (size_t)t0 * 96 + DT_RANK + n;
  const float* cp = xp + (size_t)t0 * 96 + DT_RANK + N_ST + n;
  const float* rp = xr + (size_t)t0 * 4096 + 2048 + d;
  short* zp = zb + (size_t)t0 * 2048 + d;
  float h = Hinit[((b * NC + c) * 2048 + d) * 16 + n];
  for (int lb = 0; lb < LC; lb += 8) {
#pragma unroll
    for (int j = 0; j < 8; ++j) {
      const int t = lb + j;
      float dl = dp[(size_t)t * 2048];
      float ul = up[(size_t)t * 2048];
      float Bv = bp[(size_t)t * 96];
      float Cv = cp[(size_t)t * 96];
      float rv = rp[(size_t)t * 4096];
      float dA = __expf(dl * Ac);
      h = dA * h + dl * Bv * ul;
      float p = h * Cv;
      p += __shfl_xor(p, 1, 16);
      p += __shfl_xor(p, 2, 16);
      p += __shfl_xor(p, 4, 16);
      p += __shfl_xor(p, 8, 16);
      if (n == 0) zp[(size_t)t * 2048] = f2b(p * (rv / (1.f + __expf(-rv))));
    }
  }
}

extern "C" void kernel_launch(void* const* d_in, const int* in_sizes, int n_in,
                              void* d_out, int out_size, void* d_ws, size_t ws_size,
                              hipStream_t stream)
{
  const float* x      = (const float*)d_in[0];
  const float* A_log  = (const float*)d_in[1];
  const float* W_in   = (const float*)d_in[2];
  const float* b_in   = (const float*)d_in[3];
  const float* conv_w = (const float*)d_in[4];
  const float* conv_b = (const float*)d_in[5];
  const float* W_x    = (const float*)d_in[6];
  const float* W_dt   = (const float*)d_in[7];
  const float* b_dt   = (const float*)d_in[8];
  const float* W_out  = (const float*)d_in[9];
  const float* b_out  = (const float*)d_in[10];
  float* out = (float*)d_out;

  // workspace layout (~98 MB)
  char* p = (char*)d_ws;
  float* xr    = (float*)p; p += (size_t)NTOK * 4096 * 4;          // 32MB u_pre|res
  float* u     = (float*)p; p += (size_t)NTOK * 2048 * 4;          // 16MB
  short* ub    = (short*)p; p += (size_t)NTOK * 2048 * 2;          // 8MB
  float* xp    = (float*)p; p += (size_t)NTOK * 96 * 4;            // .75MB dt|B|C
  short* dtb   = (short*)p; p += (size_t)NTOK * 64 * 2;            // .25MB
  float* delta = (float*)p; p += (size_t)NTOK * 2048 * 4;          // 16MB
  short* zb    = (short*)p; p += (size_t)NTOK * 2048 * 2;          // 8MB
  short* xb    = (short*)p;                                        // 4MB (dead after GEMM1)
  short* Wob   = xb;        p += (size_t)NTOK * 1024 * 2;          //   Wob aliases xb
  short* Wib   = (short*)p;                                        // 8MB (dead after GEMM1)
  float* Pbuf  = (float*)Wib;                                      //   P aliases Wib[0:4MB]
  float* Sbuf  = (float*)(Wib + (size_t)2048 * 1024);              //   S aliases Wib[4:8MB]
  p += (size_t)4096 * 1024 * 2;
  short* Wxb   = (short*)p; p += (size_t)128 * 2048 * 2;           // .5MB (96 rows + pad)
  short* Wdtb  = (short*)p; p += (size_t)2048 * 64 * 2;            // .25MB
  float* Hinit = (float*)p; p += (size_t)BSZ * NC * 2048 * 16 * 4; // 4MB

  hipMemsetAsync(xp,  0, (size_t)NTOK * 96 * 4, stream);
  hipMemsetAsync(out, 0, (size_t)NTOK * 1024 * 4, stream);
  hipMemsetAsync(Wxb + (size_t)96 * 2048, 0, (size_t)32 * 2048 * 2, stream); // pad rows

  // pre-casts
  castA_kernel<<<dim3(2048), 256, 0, stream>>>(x, xb);                       // x -> bf16
  transW_kernel<<<dim3(128, 32), 256, 0, stream>>>(W_in, Wib, 1024, 4096);   // [4096][1024]
  transW_kernel<<<dim3(3, 64), 256, 0, stream>>>(W_x, Wxb, 2048, 96);        // [96][2048]
  transW_kernel<<<dim3(64, 2), 256, 0, stream>>>(W_dt, Wdtb, 64, 2048);      // [2048][64]

  // xr = x @ W_in + b_in
  gemm_kernel<0, 0><<<dim3(32, 16, 1), 256, 0, stream>>>(
      xb, Wib, b_in, xr, NTOK, 4096, 1024, 1024, 1024, 4096, 1024);
  // W_out transpose (after GEMM1: Wob aliases xb, now dead). grid=(C/32,R/32)=(32,64)
  transW_kernel<<<dim3(32, 64), 256, 0, stream>>>(W_out, Wob, 2048, 1024);   // [1024][2048]
  // u = silu(conv(u_pre) + conv_b), fp32 + bf16
  conv_silu_kernel<<<dim3(4096), 256, 0, stream>>>(xr, conv_w, conv_b, u, ub);
  // xp = u @ W_x   (split-K 8, atomic)
  gemm_kernel<0, 1><<<dim3(1, 16, 8), 256, 0, stream>>>(
      ub, Wxb, nullptr, xp, NTOK, 96, 2048, 2048, 2048, 96, 256);
  castDT_kernel<<<dim3(128), 256, 0, stream>>>(xp, dtb);
  // delta = softplus(dt @ W_dt + b_dt)
  gemm_kernel<1, 0><<<dim3(16, 16, 1), 256, 0, stream>>>(
      dtb, Wdtb, b_dt, delta, NTOK, 2048, 64, 64, 64, 2048, 64);
  // chunked selective scan -> zb (bf16, zmul fused)
  scan_pass1<<<dim3(NC, 128, BSZ), 256, 0, stream>>>(delta, u, xp, A_log, Pbuf, Sbuf);
  scan_pass2<<<dim3(256), 256, 0, stream>>>(Pbuf, Sbuf, Hinit);
  scan_pass3<<<dim3(NC, 128, BSZ), 256, 0, stream>>>(delta, u, xp, A_log, Hinit, xr, zb);
  // out = z @ W_out + b_out   (split-K 2, atomic)
  gemm_kernel<0, 1><<<dim3(8, 16, 2), 256, 0, stream>>>(
      zb, Wob, b_out, out, NTOK, 1024, 2048, 2048, 2048, 1024, 1024);
}

// Round 5
// 196.271 us; speedup vs baseline: 2.6452x; 1.4718x over previous
//
#include <hip/hip_runtime.h>

#define D_MODEL 1024
#define D_INNER 2048
#define N_ST    16
#define DT_RANK 64
#define BSZ     2
#define SEQL    1024
#define NTOK    (BSZ*SEQL)   // 2048
#define NC      64           // scan chunks
#define LC      (SEQL/NC)    // 16 steps per chunk

typedef __attribute__((ext_vector_type(4))) float f32x4;
typedef __attribute__((ext_vector_type(8))) short bf16x8;

__device__ __forceinline__ short f2b(float f) {
  unsigned u = __builtin_bit_cast(unsigned, f);
  u += 0x7fffu + ((u >> 16) & 1u);           // round-to-nearest-even
  return (short)(u >> 16);
}

__device__ __forceinline__ float b2f(unsigned short s) {
  return __builtin_bit_cast(float, (unsigned)s << 16);
}

__device__ __forceinline__ void gload16(const void* g, void* l) {
  __builtin_amdgcn_global_load_lds(
      (const __attribute__((address_space(1))) void*)g,
      (__attribute__((address_space(3))) void*)l, 16, 0, 0);
}

#define BMT 128
#define BNT 128
#define BKT 32

// C[M,N] = epi(A[M,K] @ B[N,K]^T + bias); A,B bf16 (B pre-transposed), C fp32.
template<int SOFTPLUS, int ATOMIC>
__global__ __launch_bounds__(256)
void gemm_kernel(const short* __restrict__ A, const short* __restrict__ Bm,
                 const float* __restrict__ bias, float* __restrict__ C,
                 int M, int N, int K, int lda, int ldb, int ldc, int kChunk)
{
  __shared__ short sA[BMT * BKT];   // 8 KB, linear [row][k]
  __shared__ short sB[BNT * BKT];   // 8 KB, linear [n][k]
  const int tid  = threadIdx.x;
  const int lane = tid & 63;
  const int wave = tid >> 6;
  const int wr = wave >> 1, wc = wave & 1;
  const int lr = lane & 15, lg = lane >> 4;
  const int m0 = blockIdx.y * BMT;
  const int n0 = blockIdx.x * BNT;
  const int kStart = blockIdx.z * kChunk;
  int kEnd = kStart + kChunk; if (kEnd > K) kEnd = K;

  const int srow = lane >> 2;          // row within 16x32 chunk
  const int scol = (lane & 3) * 8;     // bf16 col within row
  const short* aS0 = A + (size_t)(m0 + wave * 32 + srow) * lda + scol + kStart;
  const short* aS1 = aS0 + (size_t)16 * lda;
  const short* bS0 = Bm + (size_t)(n0 + wave * 32 + srow) * ldb + scol + kStart;
  const short* bS1 = bS0 + (size_t)16 * ldb;
  short* aD0 = &sA[wave * 1024];
  short* aD1 = &sA[wave * 1024 + 512];
  short* bD0 = &sB[wave * 1024];
  short* bD1 = &sB[wave * 1024 + 512];

  f32x4 acc[4][4];
#pragma unroll
  for (int i = 0; i < 4; ++i)
#pragma unroll
    for (int j = 0; j < 4; ++j) acc[i][j] = (f32x4){0.f, 0.f, 0.f, 0.f};

  for (int k0 = kStart; k0 < kEnd; k0 += BKT) {
    __syncthreads();
    gload16(aS0, aD0); gload16(aS1, aD1);
    gload16(bS0, bD0); gload16(bS1, bD1);
    aS0 += BKT; aS1 += BKT; bS0 += BKT; bS1 += BKT;
    __syncthreads();

    bf16x8 aF[4], bF[4];
#pragma unroll
    for (int mi = 0; mi < 4; ++mi)
      aF[mi] = *reinterpret_cast<const bf16x8*>(&sA[(wr * 64 + mi * 16 + lr) * 32 + lg * 8]);
#pragma unroll
    for (int ni = 0; ni < 4; ++ni)
      bF[ni] = *reinterpret_cast<const bf16x8*>(&sB[(wc * 64 + ni * 16 + lr) * 32 + lg * 8]);
#pragma unroll
    for (int mi = 0; mi < 4; ++mi)
#pragma unroll
      for (int ni = 0; ni < 4; ++ni)
        acc[mi][ni] = __builtin_amdgcn_mfma_f32_16x16x32_bf16(
            aF[mi], bF[ni], acc[mi][ni], 0, 0, 0);
  }

#pragma unroll
  for (int mi = 0; mi < 4; ++mi) {
    const int row = m0 + wr * 64 + mi * 16 + lg * 4;
#pragma unroll
    for (int ni = 0; ni < 4; ++ni) {
      const int col = n0 + wc * 64 + ni * 16 + lr;
      if (col < N) {
        float bv = (bias != nullptr && blockIdx.z == 0) ? bias[col] : 0.f;
#pragma unroll
        for (int j = 0; j < 4; ++j) {
          float v = acc[mi][ni][j] + bv;
          if (SOFTPLUS) v = fmaxf(v, 0.f) + log1pf(__expf(-fabsf(v)));
          if (ATOMIC) atomicAdd(&C[(size_t)(row + j) * ldc + col], v);
          else        C[(size_t)(row + j) * ldc + col] = v;
        }
      }
    }
  }
}

// straight cast fp32 -> bf16, 4 elems/thread
__global__ __launch_bounds__(256)
void castA_kernel(const float* __restrict__ in, short* __restrict__ out)
{
  int i = blockIdx.x * 256 + threadIdx.x;
  float4 v = *reinterpret_cast<const float4*>(in + (size_t)i * 4);
  *reinterpret_cast<short4*>(out + (size_t)i * 4) =
      make_short4(f2b(v.x), f2b(v.y), f2b(v.z), f2b(v.w));
}

// transpose-cast: in[R][C] fp32 -> out[C][R] bf16; grid = (C/32, R/32)
__global__ __launch_bounds__(256)
void transW_kernel(const float* __restrict__ in, short* __restrict__ out, int R, int C)
{
  __shared__ short t[32][33];
  const int c0 = blockIdx.x * 32, r0 = blockIdx.y * 32;
  const int cc = threadIdx.x & 31, rr = threadIdx.x >> 5;  // rr 0..7
#pragma unroll
  for (int i = 0; i < 4; ++i)
    t[rr + i * 8][cc] = f2b(in[(size_t)(r0 + rr + i * 8) * C + c0 + cc]);
  __syncthreads();
#pragma unroll
  for (int i = 0; i < 4; ++i)
    out[(size_t)(c0 + rr + i * 8) * R + r0 + cc] = t[cc][rr + i * 8];
}

// dt slice of xp -> bf16 [2048][64]
__global__ __launch_bounds__(256)
void castDT_kernel(const float* __restrict__ xp, short* __restrict__ dtb)
{
  int i = blockIdx.x * 256 + threadIdx.x;    // over 2048*16
  int r = i >> 4, q = i & 15;
  float4 v = *reinterpret_cast<const float4*>(xp + (size_t)r * 96 + q * 4);
  *reinterpret_cast<short4*>(dtb + (size_t)r * 64 + q * 4) =
      make_short4(f2b(v.x), f2b(v.y), f2b(v.z), f2b(v.w));
}

// causal depthwise conv(K=3) + bias + silu; writes u bf16 only
__global__ __launch_bounds__(256)
void conv_silu_kernel(const float* __restrict__ xr, const float* __restrict__ cw,
                      const float* __restrict__ cb, short* __restrict__ ub)
{
  int i  = blockIdx.x * 256 + threadIdx.x;
  int t  = i >> 9;
  int dq = (i & 511) << 2;
  int l  = t & (SEQL - 1);
  float4 w0 = *reinterpret_cast<const float4*>(cw + dq * 3);
  float4 w1 = *reinterpret_cast<const float4*>(cw + dq * 3 + 4);
  float4 w2 = *reinterpret_cast<const float4*>(cw + dq * 3 + 8);
  float4 bb = *reinterpret_cast<const float4*>(cb + dq);
  float4 x2 = *reinterpret_cast<const float4*>(xr + (size_t)t * 4096 + dq);
  float4 x1 = (l >= 1) ? *reinterpret_cast<const float4*>(xr + (size_t)(t - 1) * 4096 + dq)
                       : make_float4(0.f, 0.f, 0.f, 0.f);
  float4 x0 = (l >= 2) ? *reinterpret_cast<const float4*>(xr + (size_t)(t - 2) * 4096 + dq)
                       : make_float4(0.f, 0.f, 0.f, 0.f);
  float r0 = bb.x + w0.x * x0.x + w0.y * x1.x + w0.z * x2.x;
  float r1 = bb.y + w0.w * x0.y + w1.x * x1.y + w1.y * x2.y;
  float r2 = bb.z + w1.z * x0.z + w1.w * x1.z + w2.x * x2.z;
  float r3 = bb.w + w2.y * x0.w + w2.z * x1.w + w2.w * x2.w;
  float o0 = r0 / (1.f + __expf(-r0));
  float o1 = r1 / (1.f + __expf(-r1));
  float o2 = r2 / (1.f + __expf(-r2));
  float o3 = r3 / (1.f + __expf(-r3));
  *reinterpret_cast<short4*>(ub + (size_t)t * 2048 + dq) =
      make_short4(f2b(o0), f2b(o1), f2b(o2), f2b(o3));
}

// ---- chunked selective scan: thread owns (b, chunk, d) with all 16 n ----
// pass1: local scan from h=0 -> HS = h_end[16], sdl = sum(delta)
__global__ __launch_bounds__(256, 4)
void scan_pass1(const float* __restrict__ delta, const unsigned short* __restrict__ ub,
                const float* __restrict__ xp, const float* __restrict__ A_log,
                float* __restrict__ sdl, float* __restrict__ HS)
{
  const int d = blockIdx.y * 256 + threadIdx.x;
  const int c = blockIdx.x, b = blockIdx.z;
  const int t0 = (b << 10) + c * LC;
  float Ac[16];
#pragma unroll
  for (int q = 0; q < 4; ++q) {
    float4 a = *reinterpret_cast<const float4*>(A_log + (size_t)d * 16 + q * 4);
    Ac[q * 4 + 0] = -__expf(a.x); Ac[q * 4 + 1] = -__expf(a.y);
    Ac[q * 4 + 2] = -__expf(a.z); Ac[q * 4 + 3] = -__expf(a.w);
  }
  float h[16];
#pragma unroll
  for (int n = 0; n < 16; ++n) h[n] = 0.f;
  float sd = 0.f;
  const float* dp = delta + (size_t)t0 * 2048 + d;
  const unsigned short* up = ub + (size_t)t0 * 2048 + d;
  const float* xb = xp + (size_t)t0 * 96 + DT_RANK;
#pragma unroll 4
  for (int t = 0; t < LC; ++t) {
    float dl = dp[(size_t)t * 2048];
    float ul = b2f(up[(size_t)t * 2048]);
    float Bf[16];
#pragma unroll
    for (int q = 0; q < 4; ++q)
      *reinterpret_cast<float4*>(&Bf[q * 4]) =
          *reinterpret_cast<const float4*>(xb + (size_t)t * 96 + q * 4);
    float dlu = dl * ul;
    sd += dl;
#pragma unroll
    for (int n = 0; n < 16; ++n)
      h[n] = __expf(dl * Ac[n]) * h[n] + dlu * Bf[n];
  }
  sdl[((size_t)b * NC + c) * 2048 + d] = sd;
  float* hs = HS + (((size_t)b * NC + c) * 2048 + d) * 16;
#pragma unroll
  for (int q = 0; q < 4; ++q)
    *reinterpret_cast<float4*>(hs + q * 4) =
        make_float4(h[q * 4], h[q * 4 + 1], h[q * 4 + 2], h[q * 4 + 3]);
}

// pass2: in-place combine over chunks: HS[c] := h_init(c); thread=(b,d,n)
__global__ __launch_bounds__(256)
void scan_pass2(const float* __restrict__ sdl, const float* __restrict__ A_log,
                float* __restrict__ HS)
{
  const int gid = blockIdx.x * 256 + threadIdx.x;  // 0..65535
  const int b = gid >> 15, rest = gid & 32767;     // rest = d*16+n
  const int d = rest >> 4;
  const float Ac = -__expf(A_log[rest]);
  float h = 0.f;
  for (int c = 0; c < NC; ++c) {
    const size_t idx = (((size_t)b * NC + c) << 15) + rest;
    float S = HS[idx];
    float sd = sdl[((size_t)b * NC + c) * 2048 + d];
    HS[idx] = h;
    h = __expf(sd * Ac) * h + S;
  }
}

// pass3: local scan from HS (=h_init), local n-reduce, fused z = y*silu(res), bf16 out
__global__ __launch_bounds__(256, 4)
void scan_pass3(const float* __restrict__ delta, const unsigned short* __restrict__ ub,
                const float* __restrict__ xp, const float* __restrict__ A_log,
                const float* __restrict__ HS, const float* __restrict__ xr,
                short* __restrict__ zb)
{
  const int d = blockIdx.y * 256 + threadIdx.x;
  const int c = blockIdx.x, b = blockIdx.z;
  const int t0 = (b << 10) + c * LC;
  float Ac[16];
#pragma unroll
  for (int q = 0; q < 4; ++q) {
    float4 a = *reinterpret_cast<const float4*>(A_log + (size_t)d * 16 + q * 4);
    Ac[q * 4 + 0] = -__expf(a.x); Ac[q * 4 + 1] = -__expf(a.y);
    Ac[q * 4 + 2] = -__expf(a.z); Ac[q * 4 + 3] = -__expf(a.w);
  }
  float h[16];
  const float* hs = HS + (((size_t)b * NC + c) * 2048 + d) * 16;
#pragma unroll
  for (int q = 0; q < 4; ++q) {
    float4 v = *reinterpret_cast<const float4*>(hs + q * 4);
    h[q * 4 + 0] = v.x; h[q * 4 + 1] = v.y; h[q * 4 + 2] = v.z; h[q * 4 + 3] = v.w;
  }
  const float* dp = delta + (size_t)t0 * 2048 + d;
  const unsigned short* up = ub + (size_t)t0 * 2048 + d;
  const float* xb = xp + (size_t)t0 * 96 + DT_RANK;
  const float* xc = xp + (size_t)t0 * 96 + DT_RANK + N_ST;
  const float* rp = xr + (size_t)t0 * 4096 + 2048 + d;
  short* zp = zb + (size_t)t0 * 2048 + d;
#pragma unroll 4
  for (int t = 0; t < LC; ++t) {
    float dl = dp[(size_t)t * 2048];
    float ul = b2f(up[(size_t)t * 2048]);
    float rv = rp[(size_t)t * 4096];
    float Bf[16], Cf[16];
#pragma unroll
    for (int q = 0; q < 4; ++q) {
      *reinterpret_cast<float4*>(&Bf[q * 4]) =
          *reinterpret_cast<const float4*>(xb + (size_t)t * 96 + q * 4);
      *reinterpret_cast<float4*>(&Cf[q * 4]) =
          *reinterpret_cast<const float4*>(xc + (size_t)t * 96 + q * 4);
    }
    float dlu = dl * ul;
    float p0 = 0.f, p1 = 0.f, p2 = 0.f, p3 = 0.f;
#pragma unroll
    for (int n = 0; n < 16; ++n) {
      h[n] = __expf(dl * Ac[n]) * h[n] + dlu * Bf[n];
      float t2 = h[n] * Cf[n];
      if ((n & 3) == 0) p0 += t2;
      else if ((n & 3) == 1) p1 += t2;
      else if ((n & 3) == 2) p2 += t2;
      else p3 += t2;
    }
    float p = (p0 + p1) + (p2 + p3);
    zp[(size_t)t * 2048] = f2b(p * (rv / (1.f + __expf(-rv))));
  }
}

extern "C" void kernel_launch(void* const* d_in, const int* in_sizes, int n_in,
                              void* d_out, int out_size, void* d_ws, size_t ws_size,
                              hipStream_t stream)
{
  const float* x      = (const float*)d_in[0];
  const float* A_log  = (const float*)d_in[1];
  const float* W_in   = (const float*)d_in[2];
  const float* b_in   = (const float*)d_in[3];
  const float* conv_w = (const float*)d_in[4];
  const float* conv_b = (const float*)d_in[5];
  const float* W_x    = (const float*)d_in[6];
  const float* W_dt   = (const float*)d_in[7];
  const float* b_dt   = (const float*)d_in[8];
  const float* W_out  = (const float*)d_in[9];
  const float* b_out  = (const float*)d_in[10];
  float* out = (float*)d_out;

  // workspace layout (~95 MB)
  char* p = (char*)d_ws;
  float* xr    = (float*)p; p += (size_t)NTOK * 4096 * 4;          // 32MB u_pre|res
  short* ub    = (short*)p; p += (size_t)NTOK * 2048 * 2;          // 8MB bf16
  float* xp    = (float*)p; p += (size_t)NTOK * 96 * 4;            // .75MB dt|B|C
  short* dtb   = (short*)p; p += (size_t)NTOK * 64 * 2;            // .25MB
  float* delta = (float*)p; p += (size_t)NTOK * 2048 * 4;          // 16MB
  short* zb    = (short*)p; p += (size_t)NTOK * 2048 * 2;          // 8MB
  short* xb    = (short*)p;                                        // 4MB (dead after GEMM1)
  short* Wob   = xb;        p += (size_t)NTOK * 1024 * 2;          //   Wob aliases xb
  short* Wib   = (short*)p; p += (size_t)4096 * 1024 * 2;          // 8MB
  short* Wxb   = (short*)p; p += (size_t)128 * 2048 * 2;           // .5MB (96 rows + pad)
  short* Wdtb  = (short*)p; p += (size_t)2048 * 64 * 2;            // .25MB
  float* sdl   = (float*)p; p += (size_t)BSZ * NC * 2048 * 4;      // 1MB
  float* HS    = (float*)p; p += (size_t)BSZ * NC * 2048 * 16 * 4; // 16MB

  hipMemsetAsync(xp,  0, (size_t)NTOK * 96 * 4, stream);
  hipMemsetAsync(out, 0, (size_t)NTOK * 1024 * 4, stream);
  hipMemsetAsync(Wxb + (size_t)96 * 2048, 0, (size_t)32 * 2048 * 2, stream); // pad rows

  // pre-casts
  castA_kernel<<<dim3(2048), 256, 0, stream>>>(x, xb);                       // x -> bf16
  transW_kernel<<<dim3(128, 32), 256, 0, stream>>>(W_in, Wib, 1024, 4096);   // [4096][1024]
  transW_kernel<<<dim3(3, 64), 256, 0, stream>>>(W_x, Wxb, 2048, 96);        // [96][2048]
  transW_kernel<<<dim3(64, 2), 256, 0, stream>>>(W_dt, Wdtb, 64, 2048);      // [2048][64]

  // xr = x @ W_in + b_in
  gemm_kernel<0, 0><<<dim3(32, 16, 1), 256, 0, stream>>>(
      xb, Wib, b_in, xr, NTOK, 4096, 1024, 1024, 1024, 4096, 1024);
  // W_out transpose (Wob aliases xb, dead after GEMM1). grid=(C/32,R/32)=(32,64)
  transW_kernel<<<dim3(32, 64), 256, 0, stream>>>(W_out, Wob, 2048, 1024);   // [1024][2048]
  // u = silu(conv(u_pre) + conv_b), bf16
  conv_silu_kernel<<<dim3(4096), 256, 0, stream>>>(xr, conv_w, conv_b, ub);
  // xp = u @ W_x   (split-K 8, atomic)
  gemm_kernel<0, 1><<<dim3(1, 16, 8), 256, 0, stream>>>(
      ub, Wxb, nullptr, xp, NTOK, 96, 2048, 2048, 2048, 96, 256);
  castDT_kernel<<<dim3(128), 256, 0, stream>>>(xp, dtb);
  // delta = softplus(dt @ W_dt + b_dt)
  gemm_kernel<1, 0><<<dim3(16, 16, 1), 256, 0, stream>>>(
      dtb, Wdtb, b_dt, delta, NTOK, 2048, 64, 64, 64, 2048, 64);
  // chunked selective scan -> zb (bf16, zmul fused)
  scan_pass1<<<dim3(NC, 8, BSZ), 256, 0, stream>>>(delta, (const unsigned short*)ub, xp, A_log, sdl, HS);
  scan_pass2<<<dim3(256), 256, 0, stream>>>(sdl, A_log, HS);
  scan_pass3<<<dim3(NC, 8, BSZ), 256, 0, stream>>>(delta, (const unsigned short*)ub, xp, A_log, HS, xr, zb);
  // out = z @ W_out + b_out   (split-K 2, atomic)
  gemm_kernel<0, 1><<<dim3(8, 16, 2), 256, 0, stream>>>(
      zb, Wob, b_out, out, NTOK, 1024, 2048, 2048, 2048, 1024, 1024);
}

// Round 6
// 171.996 us; speedup vs baseline: 3.0185x; 1.1411x over previous
//
#include <hip/hip_runtime.h>

#define D_MODEL 1024
#define D_INNER 2048
#define N_ST    16
#define DT_RANK 64
#define BSZ     2
#define SEQL    1024
#define NTOK    (BSZ*SEQL)   // 2048
#define NC      64           // scan chunks
#define LC      (SEQL/NC)    // 16 steps per chunk

typedef __attribute__((ext_vector_type(4))) float f32x4;
typedef __attribute__((ext_vector_type(8))) short bf16x8;

__device__ __forceinline__ short f2b(float f) {
  unsigned u = __builtin_bit_cast(unsigned, f);
  u += 0x7fffu + ((u >> 16) & 1u);           // round-to-nearest-even
  return (short)(u >> 16);
}

__device__ __forceinline__ float b2f(unsigned short s) {
  return __builtin_bit_cast(float, (unsigned)s << 16);
}

__device__ __forceinline__ void gload16(const void* g, void* l) {
  __builtin_amdgcn_global_load_lds(
      (const __attribute__((address_space(1))) void*)g,
      (__attribute__((address_space(3))) void*)l, 16, 0, 0);
}

// C[M,N] = epi(A[M,K] @ B[N,K]^T + bias); A,B bf16 (B pre-transposed [N][K]).
// 128x128 tile, BK=64, XOR-swizzled LDS (swizzle applied on global source +
// on ds_read; LDS linear for global_load_lds — rule "both sides or neither").
// PARTIAL: C += z*M*ldc (split-K partial buffers, no atomics).
// RESSPLIT: cols >= 2048 store silu(v) as bf16 to resb instead of fp32 C.
template<int SOFTPLUS, int ATOMIC, int PARTIAL, int RESSPLIT>
__global__ __launch_bounds__(256)
void gemm_kernel(const short* __restrict__ A, const short* __restrict__ Bm,
                 const float* __restrict__ bias, float* __restrict__ C,
                 short* __restrict__ resb,
                 int M, int N, int K, int lda, int ldb, int ldc, int kChunk)
{
  __shared__ short sA[128 * 64];   // 16 KB, linear [row][k], ld 64
  __shared__ short sB[128 * 64];   // 16 KB
  const int tid  = threadIdx.x;
  const int lane = tid & 63;
  const int wave = tid >> 6;
  const int wr = wave >> 1, wc = wave & 1;
  const int lr = lane & 15, lg = lane >> 4;
  const int m0 = blockIdx.y * 128;
  const int n0 = blockIdx.x * 128;
  const int kStart = blockIdx.z * kChunk;
  int kEnd = kStart + kChunk; if (kEnd > K) kEnd = K;

  if (PARTIAL) C += (size_t)blockIdx.z * M * ldc;

  // staging: wave covers 32 rows; one gload16 covers 8 rows x 64k (1 KB).
  // source col-block XOR-swizzled by row&7 so swizzled ds_read sees G[row][cb].
  const int srow = lane >> 3;                 // 0..7 row within 8-row group
  const int scol = ((lane & 7) ^ srow) * 8;   // swizzled source col (bf16)
  const short* aS = A + (size_t)(m0 + wave * 32 + srow) * lda + scol + kStart;
  const short* bS = Bm + (size_t)(n0 + wave * 32 + srow) * ldb + scol + kStart;
  short* aD = &sA[wave * 32 * 64];
  short* bD = &sB[wave * 32 * 64];

  f32x4 acc[4][4];
#pragma unroll
  for (int i = 0; i < 4; ++i)
#pragma unroll
    for (int j = 0; j < 4; ++j) acc[i][j] = (f32x4){0.f, 0.f, 0.f, 0.f};

  for (int k0 = kStart; k0 < kEnd; k0 += 64) {
    __syncthreads();
#pragma unroll
    for (int i = 0; i < 4; ++i) {
      gload16(aS + (size_t)(i * 8) * lda, aD + i * 512);
      gload16(bS + (size_t)(i * 8) * ldb, bD + i * 512);
    }
    aS += 64; bS += 64;
    __syncthreads();

#pragma unroll
    for (int kk = 0; kk < 2; ++kk) {
      bf16x8 aF[4], bF[4];
#pragma unroll
      for (int mi = 0; mi < 4; ++mi) {
        const int row = wr * 64 + mi * 16 + lr;
        aF[mi] = *reinterpret_cast<const bf16x8*>(
            &sA[row * 64 + (((kk * 4 + lg) ^ (lr & 7)) * 8)]);
      }
#pragma unroll
      for (int ni = 0; ni < 4; ++ni) {
        const int row = wc * 64 + ni * 16 + lr;
        bF[ni] = *reinterpret_cast<const bf16x8*>(
            &sB[row * 64 + (((kk * 4 + lg) ^ (lr & 7)) * 8)]);
      }
#pragma unroll
      for (int mi = 0; mi < 4; ++mi)
#pragma unroll
        for (int ni = 0; ni < 4; ++ni)
          acc[mi][ni] = __builtin_amdgcn_mfma_f32_16x16x32_bf16(
              aF[mi], bF[ni], acc[mi][ni], 0, 0, 0);
    }
  }

  // epilogue: C/D layout col=lane&15, row=(lane>>4)*4+reg
#pragma unroll
  for (int mi = 0; mi < 4; ++mi) {
    const int row = m0 + wr * 64 + mi * 16 + lg * 4;
#pragma unroll
    for (int ni = 0; ni < 4; ++ni) {
      const int col = n0 + wc * 64 + ni * 16 + lr;
      if (RESSPLIT && col >= 2048) {
        const float bv = bias[col];
#pragma unroll
        for (int j = 0; j < 4; ++j) {
          float v = acc[mi][ni][j] + bv;
          resb[(size_t)(row + j) * 2048 + (col - 2048)] =
              f2b(v / (1.f + __expf(-v)));
        }
      } else if (col < N) {
        float bv = (bias != nullptr && blockIdx.z == 0) ? bias[col] : 0.f;
#pragma unroll
        for (int j = 0; j < 4; ++j) {
          float v = acc[mi][ni][j] + bv;
          if (SOFTPLUS) v = fmaxf(v, 0.f) + log1pf(__expf(-fabsf(v)));
          if (ATOMIC) atomicAdd(&C[(size_t)(row + j) * ldc + col], v);
          else        C[(size_t)(row + j) * ldc + col] = v;
        }
      }
    }
  }
}

// ---- fused prep: castA(x) + transpose-cast of all 4 weights, one dispatch ----
__device__ __forceinline__ void trans_body(const float* __restrict__ in,
                                           short* __restrict__ out,
                                           int R, int C, int bx, int by,
                                           short (*t)[33], int tidx)
{
  const int c0 = bx * 32, r0 = by * 32;
  const int cc = tidx & 31, rr = tidx >> 5;  // rr 0..7
#pragma unroll
  for (int i = 0; i < 4; ++i)
    t[rr + i * 8][cc] = f2b(in[(size_t)(r0 + rr + i * 8) * C + c0 + cc]);
  __syncthreads();
#pragma unroll
  for (int i = 0; i < 4; ++i)
    out[(size_t)(c0 + rr + i * 8) * R + r0 + cc] = t[cc][rr + i * 8];
}

#define PB_CAST  2048
#define PB_WIN   4096
#define PB_WX    192
#define PB_WDT   128
#define PB_WOUT  2048

__global__ __launch_bounds__(256)
void prep_kernel(const float* __restrict__ x,    const float* __restrict__ W_in,
                 const float* __restrict__ W_x,  const float* __restrict__ W_dt,
                 const float* __restrict__ W_out,
                 short* __restrict__ xb,  short* __restrict__ Wib,
                 short* __restrict__ Wxb, short* __restrict__ Wdtb,
                 short* __restrict__ Wob)
{
  __shared__ short t[32][33];
  const int bid = blockIdx.x, tidx = threadIdx.x;
  if (bid < PB_CAST) {
    const int i = bid * 256 + tidx;
    float4 v = *reinterpret_cast<const float4*>(x + (size_t)i * 4);
    *reinterpret_cast<short4*>(xb + (size_t)i * 4) =
        make_short4(f2b(v.x), f2b(v.y), f2b(v.z), f2b(v.w));
  } else if (bid < PB_CAST + PB_WIN) {
    const int b = bid - PB_CAST;
    trans_body(W_in, Wib, 1024, 4096, b % 128, b / 128, t, tidx);
  } else if (bid < PB_CAST + PB_WIN + PB_WX) {
    const int b = bid - PB_CAST - PB_WIN;
    trans_body(W_x, Wxb, 2048, 96, b % 3, b / 3, t, tidx);
  } else if (bid < PB_CAST + PB_WIN + PB_WX + PB_WDT) {
    const int b = bid - PB_CAST - PB_WIN - PB_WX;
    trans_body(W_dt, Wdtb, 64, 2048, b % 64, b / 64, t, tidx);
  } else {
    const int b = bid - PB_CAST - PB_WIN - PB_WX - PB_WDT;
    trans_body(W_out, Wob, 2048, 1024, b % 32, b / 32, t, tidx);
  }
}

// combine 8 split-K partials of GEMM2 -> xp fp32 [2048][96]; dt cols -> dtb bf16
__global__ __launch_bounds__(256)
void combine8_kernel(const float* __restrict__ part, float* __restrict__ xp,
                     short* __restrict__ dtb)
{
  const int gid = blockIdx.x * 256 + threadIdx.x;   // 0 .. 2048*24-1
  const int r = gid / 24, q = gid - r * 24;
  float4 s = make_float4(0.f, 0.f, 0.f, 0.f);
#pragma unroll
  for (int c = 0; c < 8; ++c) {
    const float4 v = *reinterpret_cast<const float4*>(
        part + (size_t)c * 2048 * 96 + (size_t)r * 96 + q * 4);
    s.x += v.x; s.y += v.y; s.z += v.z; s.w += v.w;
  }
  *reinterpret_cast<float4*>(xp + (size_t)r * 96 + q * 4) = s;
  if (q < 16)
    *reinterpret_cast<short4*>(dtb + (size_t)r * 64 + q * 4) =
        make_short4(f2b(s.x), f2b(s.y), f2b(s.z), f2b(s.w));
}

// causal depthwise conv(K=3) + bias + silu; u_pre fp32 [t][2048] -> ub bf16
__global__ __launch_bounds__(256)
void conv_silu_kernel(const float* __restrict__ up, const float* __restrict__ cw,
                      const float* __restrict__ cb, short* __restrict__ ub)
{
  int i  = blockIdx.x * 256 + threadIdx.x;
  int t  = i >> 9;
  int dq = (i & 511) << 2;
  int l  = t & (SEQL - 1);
  float4 w0 = *reinterpret_cast<const float4*>(cw + dq * 3);
  float4 w1 = *reinterpret_cast<const float4*>(cw + dq * 3 + 4);
  float4 w2 = *reinterpret_cast<const float4*>(cw + dq * 3 + 8);
  float4 bb = *reinterpret_cast<const float4*>(cb + dq);
  float4 x2 = *reinterpret_cast<const float4*>(up + (size_t)t * 2048 + dq);
  float4 x1 = (l >= 1) ? *reinterpret_cast<const float4*>(up + (size_t)(t - 1) * 2048 + dq)
                       : make_float4(0.f, 0.f, 0.f, 0.f);
  float4 x0 = (l >= 2) ? *reinterpret_cast<const float4*>(up + (size_t)(t - 2) * 2048 + dq)
                       : make_float4(0.f, 0.f, 0.f, 0.f);
  float r0 = bb.x + w0.x * x0.x + w0.y * x1.x + w0.z * x2.x;
  float r1 = bb.y + w0.w * x0.y + w1.x * x1.y + w1.y * x2.y;
  float r2 = bb.z + w1.z * x0.z + w1.w * x1.z + w2.x * x2.z;
  float r3 = bb.w + w2.y * x0.w + w2.z * x1.w + w2.w * x2.w;
  float o0 = r0 / (1.f + __expf(-r0));
  float o1 = r1 / (1.f + __expf(-r1));
  float o2 = r2 / (1.f + __expf(-r2));
  float o3 = r3 / (1.f + __expf(-r3));
  *reinterpret_cast<short4*>(ub + (size_t)t * 2048 + dq) =
      make_short4(f2b(o0), f2b(o1), f2b(o2), f2b(o3));
}

// ---- chunked selective scan: thread owns (b, chunk, d) with all 16 n ----
__global__ __launch_bounds__(256, 4)
void scan_pass1(const float* __restrict__ delta, const unsigned short* __restrict__ ub,
                const float* __restrict__ xp, const float* __restrict__ A_log,
                float* __restrict__ sdl, float* __restrict__ HS)
{
  const int d = blockIdx.y * 256 + threadIdx.x;
  const int c = blockIdx.x, b = blockIdx.z;
  const int t0 = (b << 10) + c * LC;
  float Ac[16];
#pragma unroll
  for (int q = 0; q < 4; ++q) {
    float4 a = *reinterpret_cast<const float4*>(A_log + (size_t)d * 16 + q * 4);
    Ac[q * 4 + 0] = -__expf(a.x); Ac[q * 4 + 1] = -__expf(a.y);
    Ac[q * 4 + 2] = -__expf(a.z); Ac[q * 4 + 3] = -__expf(a.w);
  }
  float h[16];
#pragma unroll
  for (int n = 0; n < 16; ++n) h[n] = 0.f;
  float sd = 0.f;
  const float* dp = delta + (size_t)t0 * 2048 + d;
  const unsigned short* up = ub + (size_t)t0 * 2048 + d;
  const float* xb = xp + (size_t)t0 * 96 + DT_RANK;
#pragma unroll 4
  for (int t = 0; t < LC; ++t) {
    float dl = dp[(size_t)t * 2048];
    float ul = b2f(up[(size_t)t * 2048]);
    float Bf[16];
#pragma unroll
    for (int q = 0; q < 4; ++q)
      *reinterpret_cast<float4*>(&Bf[q * 4]) =
          *reinterpret_cast<const float4*>(xb + (size_t)t * 96 + q * 4);
    float dlu = dl * ul;
    sd += dl;
#pragma unroll
    for (int n = 0; n < 16; ++n)
      h[n] = __expf(dl * Ac[n]) * h[n] + dlu * Bf[n];
  }
  sdl[((size_t)b * NC + c) * 2048 + d] = sd;
  float* hs = HS + (((size_t)b * NC + c) * 2048 + d) * 16;
#pragma unroll
  for (int q = 0; q < 4; ++q)
    *reinterpret_cast<float4*>(hs + q * 4) =
        make_float4(h[q * 4], h[q * 4 + 1], h[q * 4 + 2], h[q * 4 + 3]);
}

__global__ __launch_bounds__(256)
void scan_pass2(const float* __restrict__ sdl, const float* __restrict__ A_log,
                float* __restrict__ HS)
{
  const int gid = blockIdx.x * 256 + threadIdx.x;  // 0..65535
  const int b = gid >> 15, rest = gid & 32767;     // rest = d*16+n
  const int d = rest >> 4;
  const float Ac = -__expf(A_log[rest]);
  float h = 0.f;
  for (int c = 0; c < NC; ++c) {
    const size_t idx = (((size_t)b * NC + c) << 15) + rest;
    float S = HS[idx];
    float sd = sdl[((size_t)b * NC + c) * 2048 + d];
    HS[idx] = h;
    h = __expf(sd * Ac) * h + S;
  }
}

// pass3: scan from HS, local n-reduce, z = y * silu_res (rb already silu'd bf16)
__global__ __launch_bounds__(256, 4)
void scan_pass3(const float* __restrict__ delta, const unsigned short* __restrict__ ub,
                const float* __restrict__ xp, const float* __restrict__ A_log,
                const float* __restrict__ HS, const unsigned short* __restrict__ rb,
                short* __restrict__ zb)
{
  const int d = blockIdx.y * 256 + threadIdx.x;
  const int c = blockIdx.x, b = blockIdx.z;
  const int t0 = (b << 10) + c * LC;
  float Ac[16];
#pragma unroll
  for (int q = 0; q < 4; ++q) {
    float4 a = *reinterpret_cast<const float4*>(A_log + (size_t)d * 16 + q * 4);
    Ac[q * 4 + 0] = -__expf(a.x); Ac[q * 4 + 1] = -__expf(a.y);
    Ac[q * 4 + 2] = -__expf(a.z); Ac[q * 4 + 3] = -__expf(a.w);
  }
  float h[16];
  const float* hs = HS + (((size_t)b * NC + c) * 2048 + d) * 16;
#pragma unroll
  for (int q = 0; q < 4; ++q) {
    float4 v = *reinterpret_cast<const float4*>(hs + q * 4);
    h[q * 4 + 0] = v.x; h[q * 4 + 1] = v.y; h[q * 4 + 2] = v.z; h[q * 4 + 3] = v.w;
  }
  const float* dp = delta + (size_t)t0 * 2048 + d;
  const unsigned short* up = ub + (size_t)t0 * 2048 + d;
  const float* xb = xp + (size_t)t0 * 96 + DT_RANK;
  const float* xc = xp + (size_t)t0 * 96 + DT_RANK + N_ST;
  const unsigned short* rp = rb + (size_t)t0 * 2048 + d;
  short* zp = zb + (size_t)t0 * 2048 + d;
#pragma unroll 4
  for (int t = 0; t < LC; ++t) {
    float dl = dp[(size_t)t * 2048];
    float ul = b2f(up[(size_t)t * 2048]);
    float rv = b2f(rp[(size_t)t * 2048]);   // silu(res) already applied
    float Bf[16], Cf[16];
#pragma unroll
    for (int q = 0; q < 4; ++q) {
      *reinterpret_cast<float4*>(&Bf[q * 4]) =
          *reinterpret_cast<const float4*>(xb + (size_t)t * 96 + q * 4);
      *reinterpret_cast<float4*>(&Cf[q * 4]) =
          *reinterpret_cast<const float4*>(xc + (size_t)t * 96 + q * 4);
    }
    float dlu = dl * ul;
    float p0 = 0.f, p1 = 0.f, p2 = 0.f, p3 = 0.f;
#pragma unroll
    for (int n = 0; n < 16; ++n) {
      h[n] = __expf(dl * Ac[n]) * h[n] + dlu * Bf[n];
      float t2 = h[n] * Cf[n];
      if ((n & 3) == 0) p0 += t2;
      else if ((n & 3) == 1) p1 += t2;
      else if ((n & 3) == 2) p2 += t2;
      else p3 += t2;
    }
    float p = (p0 + p1) + (p2 + p3);
    zp[(size_t)t * 2048] = f2b(p * rv);
  }
}

extern "C" void kernel_launch(void* const* d_in, const int* in_sizes, int n_in,
                              void* d_out, int out_size, void* d_ws, size_t ws_size,
                              hipStream_t stream)
{
  const float* x      = (const float*)d_in[0];
  const float* A_log  = (const float*)d_in[1];
  const float* W_in   = (const float*)d_in[2];
  const float* b_in   = (const float*)d_in[3];
  const float* conv_w = (const float*)d_in[4];
  const float* conv_b = (const float*)d_in[5];
  const float* W_x    = (const float*)d_in[6];
  const float* W_dt   = (const float*)d_in[7];
  const float* b_dt   = (const float*)d_in[8];
  const float* W_out  = (const float*)d_in[9];
  const float* b_out  = (const float*)d_in[10];
  float* out = (float*)d_out;

  // workspace layout (~97 MB)
  char* p = (char*)d_ws;
  float* xr     = (float*)p; p += (size_t)NTOK * 2048 * 4;          // 16MB u_pre fp32
  short* rb     = (short*)p; p += (size_t)NTOK * 2048 * 2;          // 8MB silu(res) bf16
  short* ub     = (short*)p; p += (size_t)NTOK * 2048 * 2;          // 8MB
  float* xp     = (float*)p; p += (size_t)NTOK * 96 * 4;            // .75MB dt|B|C fp32
  short* dtb    = (short*)p; p += (size_t)NTOK * 64 * 2;            // .25MB
  float* delta  = (float*)p; p += (size_t)NTOK * 2048 * 4;          // 16MB
  short* zb     = (short*)p; p += (size_t)NTOK * 2048 * 2;          // 8MB
  short* xb     = (short*)p; p += (size_t)NTOK * 1024 * 2;          // 4MB
  short* Wib    = (short*)p; p += (size_t)4096 * 1024 * 2;          // 8MB
  short* Wxb    = (short*)p; p += (size_t)128 * 2048 * 2;           // .5MB (96 rows + pad)
  short* Wdtb   = (short*)p; p += (size_t)2048 * 64 * 2;            // .25MB
  short* Wob    = (short*)p; p += (size_t)1024 * 2048 * 2;          // 4MB
  float* xppart = (float*)p; p += (size_t)8 * 2048 * 96 * 4;        // 6MB
  float* sdl    = (float*)p; p += (size_t)BSZ * NC * 2048 * 4;      // 1MB
  float* HS     = (float*)p; p += (size_t)BSZ * NC * 2048 * 16 * 4; // 16MB

  hipMemsetAsync(out, 0, (size_t)NTOK * 1024 * 4, stream);  // GEMM4 atomic target

  // all pre-casts/transposes in one dispatch
  prep_kernel<<<dim3(PB_CAST + PB_WIN + PB_WX + PB_WDT + PB_WOUT), 256, 0, stream>>>(
      x, W_in, W_x, W_dt, W_out, xb, Wib, Wxb, Wdtb, Wob);

  // xr(u_pre fp32) | rb(silu(res) bf16) = x @ W_in + b_in
  gemm_kernel<0, 0, 0, 1><<<dim3(32, 16, 1), 256, 0, stream>>>(
      xb, Wib, b_in, xr, rb, NTOK, 4096, 1024, 1024, 1024, 2048, 1024);
  // u = silu(conv(u_pre) + conv_b), bf16
  conv_silu_kernel<<<dim3(4096), 256, 0, stream>>>(xr, conv_w, conv_b, ub);
  // xp partials = u @ W_x (split-K 8, no atomics)
  gemm_kernel<0, 0, 1, 0><<<dim3(1, 16, 8), 256, 0, stream>>>(
      ub, Wxb, nullptr, xppart, nullptr, NTOK, 96, 2048, 2048, 2048, 96, 256);
  // xp = sum(partials); dtb = bf16(dt cols)
  combine8_kernel<<<dim3(192), 256, 0, stream>>>(xppart, xp, dtb);
  // delta = softplus(dt @ W_dt + b_dt)
  gemm_kernel<1, 0, 0, 0><<<dim3(16, 16, 1), 256, 0, stream>>>(
      dtb, Wdtb, b_dt, delta, nullptr, NTOK, 2048, 64, 64, 64, 2048, 64);
  // chunked selective scan -> zb (bf16, zmul fused)
  scan_pass1<<<dim3(NC, 8, BSZ), 256, 0, stream>>>(
      delta, (const unsigned short*)ub, xp, A_log, sdl, HS);
  scan_pass2<<<dim3(256), 256, 0, stream>>>(sdl, A_log, HS);
  scan_pass3<<<dim3(NC, 8, BSZ), 256, 0, stream>>>(
      delta, (const unsigned short*)ub, xp, A_log, HS, (const unsigned short*)rb, zb);
  // out = z @ W_out + b_out (split-K 2, atomic)
  gemm_kernel<0, 1, 0, 0><<<dim3(8, 16, 2), 256, 0, stream>>>(
      zb, Wob, b_out, out, nullptr, NTOK, 1024, 2048, 2048, 2048, 1024, 1024);
}

// Round 7
// 159.504 us; speedup vs baseline: 3.2549x; 1.0783x over previous
//
#include <hip/hip_runtime.h>

#define D_MODEL 1024
#define D_INNER 2048
#define N_ST    16
#define DT_RANK 64
#define BSZ     2
#define SEQL    1024
#define NTOK    (BSZ*SEQL)   // 2048
#define NC      64           // scan chunks
#define LC      (SEQL/NC)    // 16 steps per chunk

typedef __attribute__((ext_vector_type(4))) float f32x4;
typedef __attribute__((ext_vector_type(8))) short bf16x8;

__device__ __forceinline__ short f2b(float f) {
  unsigned u = __builtin_bit_cast(unsigned, f);
  u += 0x7fffu + ((u >> 16) & 1u);           // round-to-nearest-even
  return (short)(u >> 16);
}

__device__ __forceinline__ float b2f(unsigned short s) {
  return __builtin_bit_cast(float, (unsigned)s << 16);
}

__device__ __forceinline__ void gload16(const void* g, void* l) {
  __builtin_amdgcn_global_load_lds(
      (const __attribute__((address_space(1))) void*)g,
      (__attribute__((address_space(3))) void*)l, 16, 0, 0);
}

// C[M,N] = epi(A[M,K] @ B[N,K]^T + bias); A,B bf16 (B pre-transposed [N][K]).
// 128x128 tile, BK=64, XOR-swizzled LDS (swizzle on global source + on ds_read;
// LDS linear for global_load_lds — rule "both sides or neither").
// PARTIAL: C += z*M*ldc (split-K partial buffers, no atomics).
// RESSPLIT: cols >= 2048 store silu(v) as bf16 to resb instead of fp32 C.
template<int SOFTPLUS, int PARTIAL, int RESSPLIT>
__global__ __launch_bounds__(256)
void gemm_kernel(const short* __restrict__ A, const short* __restrict__ Bm,
                 const float* __restrict__ bias, float* __restrict__ C,
                 short* __restrict__ resb,
                 int M, int N, int K, int lda, int ldb, int ldc, int kChunk)
{
  __shared__ short sA[128 * 64];   // 16 KB, linear [row][k], ld 64
  __shared__ short sB[128 * 64];   // 16 KB
  const int tid  = threadIdx.x;
  const int lane = tid & 63;
  const int wave = tid >> 6;
  const int wr = wave >> 1, wc = wave & 1;
  const int lr = lane & 15, lg = lane >> 4;
  const int m0 = blockIdx.y * 128;
  const int n0 = blockIdx.x * 128;
  const int kStart = blockIdx.z * kChunk;
  int kEnd = kStart + kChunk; if (kEnd > K) kEnd = K;

  if (PARTIAL) C += (size_t)blockIdx.z * M * ldc;

  // staging: wave covers 32 rows; one gload16 covers 8 rows x 64k (1 KB).
  // source col-block XOR-swizzled by row&7 so swizzled ds_read sees G[row][cb].
  const int srow = lane >> 3;                 // 0..7 row within 8-row group
  const int scol = ((lane & 7) ^ srow) * 8;   // swizzled source col (bf16)
  const short* aS = A + (size_t)(m0 + wave * 32 + srow) * lda + scol + kStart;
  const short* bS = Bm + (size_t)(n0 + wave * 32 + srow) * ldb + scol + kStart;
  short* aD = &sA[wave * 32 * 64];
  short* bD = &sB[wave * 32 * 64];

  f32x4 acc[4][4];
#pragma unroll
  for (int i = 0; i < 4; ++i)
#pragma unroll
    for (int j = 0; j < 4; ++j) acc[i][j] = (f32x4){0.f, 0.f, 0.f, 0.f};

  for (int k0 = kStart; k0 < kEnd; k0 += 64) {
    __syncthreads();
#pragma unroll
    for (int i = 0; i < 4; ++i) {
      gload16(aS + (size_t)(i * 8) * lda, aD + i * 512);
      gload16(bS + (size_t)(i * 8) * ldb, bD + i * 512);
    }
    aS += 64; bS += 64;
    __syncthreads();

#pragma unroll
    for (int kk = 0; kk < 2; ++kk) {
      bf16x8 aF[4], bF[4];
#pragma unroll
      for (int mi = 0; mi < 4; ++mi) {
        const int row = wr * 64 + mi * 16 + lr;
        aF[mi] = *reinterpret_cast<const bf16x8*>(
            &sA[row * 64 + (((kk * 4 + lg) ^ (lr & 7)) * 8)]);
      }
#pragma unroll
      for (int ni = 0; ni < 4; ++ni) {
        const int row = wc * 64 + ni * 16 + lr;
        bF[ni] = *reinterpret_cast<const bf16x8*>(
            &sB[row * 64 + (((kk * 4 + lg) ^ (lr & 7)) * 8)]);
      }
#pragma unroll
      for (int mi = 0; mi < 4; ++mi)
#pragma unroll
        for (int ni = 0; ni < 4; ++ni)
          acc[mi][ni] = __builtin_amdgcn_mfma_f32_16x16x32_bf16(
              aF[mi], bF[ni], acc[mi][ni], 0, 0, 0);
    }
  }

  // epilogue: C/D layout col=lane&15, row=(lane>>4)*4+reg
#pragma unroll
  for (int mi = 0; mi < 4; ++mi) {
    const int row = m0 + wr * 64 + mi * 16 + lg * 4;
#pragma unroll
    for (int ni = 0; ni < 4; ++ni) {
      const int col = n0 + wc * 64 + ni * 16 + lr;
      if (RESSPLIT && col >= 2048) {
        const float bv = bias[col];
#pragma unroll
        for (int j = 0; j < 4; ++j) {
          float v = acc[mi][ni][j] + bv;
          resb[(size_t)(row + j) * 2048 + (col - 2048)] =
              f2b(v / (1.f + __expf(-v)));
        }
      } else if (col < N) {
        float bv = (bias != nullptr && blockIdx.z == 0) ? bias[col] : 0.f;
#pragma unroll
        for (int j = 0; j < 4; ++j) {
          float v = acc[mi][ni][j] + bv;
          if (SOFTPLUS) v = fmaxf(v, 0.f) + log1pf(__expf(-fabsf(v)));
          C[(size_t)(row + j) * ldc + col] = v;
        }
      }
    }
  }
}

// ---- fused prep: castA(x) + transpose-cast of all 4 weights, one dispatch ----
__device__ __forceinline__ void trans_body(const float* __restrict__ in,
                                           short* __restrict__ out,
                                           int R, int C, int bx, int by,
                                           short (*t)[33], int tidx)
{
  const int c0 = bx * 32, r0 = by * 32;
  const int cc = tidx & 31, rr = tidx >> 5;  // rr 0..7
#pragma unroll
  for (int i = 0; i < 4; ++i)
    t[rr + i * 8][cc] = f2b(in[(size_t)(r0 + rr + i * 8) * C + c0 + cc]);
  __syncthreads();
#pragma unroll
  for (int i = 0; i < 4; ++i)
    out[(size_t)(c0 + rr + i * 8) * R + r0 + cc] = t[cc][rr + i * 8];
}

#define PB_CAST  2048
#define PB_WIN   4096
#define PB_WX    192
#define PB_WDT   128
#define PB_WOUT  2048

__global__ __launch_bounds__(256)
void prep_kernel(const float* __restrict__ x,    const float* __restrict__ W_in,
                 const float* __restrict__ W_x,  const float* __restrict__ W_dt,
                 const float* __restrict__ W_out,
                 short* __restrict__ xb,  short* __restrict__ Wib,
                 short* __restrict__ Wxb, short* __restrict__ Wdtb,
                 short* __restrict__ Wob)
{
  __shared__ short t[32][33];
  const int bid = blockIdx.x, tidx = threadIdx.x;
  if (bid < PB_CAST) {
    const int i = bid * 256 + tidx;
    float4 v = *reinterpret_cast<const float4*>(x + (size_t)i * 4);
    *reinterpret_cast<short4*>(xb + (size_t)i * 4) =
        make_short4(f2b(v.x), f2b(v.y), f2b(v.z), f2b(v.w));
  } else if (bid < PB_CAST + PB_WIN) {
    const int b = bid - PB_CAST;
    trans_body(W_in, Wib, 1024, 4096, b % 128, b / 128, t, tidx);
  } else if (bid < PB_CAST + PB_WIN + PB_WX) {
    const int b = bid - PB_CAST - PB_WIN;
    trans_body(W_x, Wxb, 2048, 96, b % 3, b / 3, t, tidx);
  } else if (bid < PB_CAST + PB_WIN + PB_WX + PB_WDT) {
    const int b = bid - PB_CAST - PB_WIN - PB_WX;
    trans_body(W_dt, Wdtb, 64, 2048, b % 64, b / 64, t, tidx);
  } else {
    const int b = bid - PB_CAST - PB_WIN - PB_WX - PB_WDT;
    trans_body(W_out, Wob, 2048, 1024, b % 32, b / 32, t, tidx);
  }
}

// combine 8 split-K partials of GEMM2 -> xp fp32 [2048][96]; dt cols -> dtb bf16
__global__ __launch_bounds__(256)
void combine8_kernel(const float* __restrict__ part, float* __restrict__ xp,
                     short* __restrict__ dtb)
{
  const int gid = blockIdx.x * 256 + threadIdx.x;   // 0 .. 2048*24-1
  const int r = gid / 24, q = gid - r * 24;
  float4 s = make_float4(0.f, 0.f, 0.f, 0.f);
#pragma unroll
  for (int c = 0; c < 8; ++c) {
    const float4 v = *reinterpret_cast<const float4*>(
        part + (size_t)c * 2048 * 96 + (size_t)r * 96 + q * 4);
    s.x += v.x; s.y += v.y; s.z += v.z; s.w += v.w;
  }
  *reinterpret_cast<float4*>(xp + (size_t)r * 96 + q * 4) = s;
  if (q < 16)
    *reinterpret_cast<short4*>(dtb + (size_t)r * 64 + q * 4) =
        make_short4(f2b(s.x), f2b(s.y), f2b(s.z), f2b(s.w));
}

// combine 4 split-K partials of GEMM4 + bias -> out fp32 [2048][1024]
__global__ __launch_bounds__(256)
void combine4_kernel(const float* __restrict__ part, const float* __restrict__ bias,
                     float* __restrict__ out)
{
  const int gid = blockIdx.x * 256 + threadIdx.x;   // over 2048*256 float4s
  const int r = gid >> 8, c4 = gid & 255;
  const float4 bv = *reinterpret_cast<const float4*>(bias + c4 * 4);
  float4 s = bv;
#pragma unroll
  for (int z = 0; z < 4; ++z) {
    const float4 v = *reinterpret_cast<const float4*>(
        part + (size_t)z * 2048 * 1024 + (size_t)r * 1024 + c4 * 4);
    s.x += v.x; s.y += v.y; s.z += v.z; s.w += v.w;
  }
  *reinterpret_cast<float4*>(out + (size_t)r * 1024 + c4 * 4) = s;
}

// causal depthwise conv(K=3) + bias + silu; u_pre fp32 [t][2048] -> ub bf16
__global__ __launch_bounds__(256)
void conv_silu_kernel(const float* __restrict__ up, const float* __restrict__ cw,
                      const float* __restrict__ cb, short* __restrict__ ub)
{
  int i  = blockIdx.x * 256 + threadIdx.x;
  int t  = i >> 9;
  int dq = (i & 511) << 2;
  int l  = t & (SEQL - 1);
  float4 w0 = *reinterpret_cast<const float4*>(cw + dq * 3);
  float4 w1 = *reinterpret_cast<const float4*>(cw + dq * 3 + 4);
  float4 w2 = *reinterpret_cast<const float4*>(cw + dq * 3 + 8);
  float4 bb = *reinterpret_cast<const float4*>(cb + dq);
  float4 x2 = *reinterpret_cast<const float4*>(up + (size_t)t * 2048 + dq);
  float4 x1 = (l >= 1) ? *reinterpret_cast<const float4*>(up + (size_t)(t - 1) * 2048 + dq)
                       : make_float4(0.f, 0.f, 0.f, 0.f);
  float4 x0 = (l >= 2) ? *reinterpret_cast<const float4*>(up + (size_t)(t - 2) * 2048 + dq)
                       : make_float4(0.f, 0.f, 0.f, 0.f);
  float r0 = bb.x + w0.x * x0.x + w0.y * x1.x + w0.z * x2.x;
  float r1 = bb.y + w0.w * x0.y + w1.x * x1.y + w1.y * x2.y;
  float r2 = bb.z + w1.z * x0.z + w1.w * x1.z + w2.x * x2.z;
  float r3 = bb.w + w2.y * x0.w + w2.z * x1.w + w2.w * x2.w;
  float o0 = r0 / (1.f + __expf(-r0));
  float o1 = r1 / (1.f + __expf(-r1));
  float o2 = r2 / (1.f + __expf(-r2));
  float o3 = r3 / (1.f + __expf(-r3));
  *reinterpret_cast<short4*>(ub + (size_t)t * 2048 + dq) =
      make_short4(f2b(o0), f2b(o1), f2b(o2), f2b(o3));
}

// ---- chunked selective scan: thread owns (b, chunk, d) with all 16 n ----
__global__ __launch_bounds__(256, 4)
void scan_pass1(const float* __restrict__ delta, const unsigned short* __restrict__ ub,
                const float* __restrict__ xp, const float* __restrict__ A_log,
                float* __restrict__ sdl, float* __restrict__ HS)
{
  const int d = blockIdx.y * 256 + threadIdx.x;
  const int c = blockIdx.x, b = blockIdx.z;
  const int t0 = (b << 10) + c * LC;
  float Ac[16];
#pragma unroll
  for (int q = 0; q < 4; ++q) {
    float4 a = *reinterpret_cast<const float4*>(A_log + (size_t)d * 16 + q * 4);
    Ac[q * 4 + 0] = -__expf(a.x); Ac[q * 4 + 1] = -__expf(a.y);
    Ac[q * 4 + 2] = -__expf(a.z); Ac[q * 4 + 3] = -__expf(a.w);
  }
  float h[16];
#pragma unroll
  for (int n = 0; n < 16; ++n) h[n] = 0.f;
  float sd = 0.f;
  const float* dp = delta + (size_t)t0 * 2048 + d;
  const unsigned short* up = ub + (size_t)t0 * 2048 + d;
  const float* xb = xp + (size_t)t0 * 96 + DT_RANK;
#pragma unroll 4
  for (int t = 0; t < LC; ++t) {
    float dl = dp[(size_t)t * 2048];
    float ul = b2f(up[(size_t)t * 2048]);
    float Bf[16];
#pragma unroll
    for (int q = 0; q < 4; ++q)
      *reinterpret_cast<float4*>(&Bf[q * 4]) =
          *reinterpret_cast<const float4*>(xb + (size_t)t * 96 + q * 4);
    float dlu = dl * ul;
    sd += dl;
#pragma unroll
    for (int n = 0; n < 16; ++n)
      h[n] = __expf(dl * Ac[n]) * h[n] + dlu * Bf[n];
  }
  sdl[((size_t)b * NC + c) * 2048 + d] = sd;
  float* hs = HS + (((size_t)b * NC + c) * 2048 + d) * 16;
#pragma unroll
  for (int q = 0; q < 4; ++q)
    *reinterpret_cast<float4*>(hs + q * 4) =
        make_float4(h[q * 4], h[q * 4 + 1], h[q * 4 + 2], h[q * 4 + 3]);
}

__global__ __launch_bounds__(256)
void scan_pass2(const float* __restrict__ sdl, const float* __restrict__ A_log,
                float* __restrict__ HS)
{
  const int gid = blockIdx.x * 256 + threadIdx.x;  // 0..65535
  const int b = gid >> 15, rest = gid & 32767;     // rest = d*16+n
  const int d = rest >> 4;
  const float Ac = -__expf(A_log[rest]);
  float h = 0.f;
  for (int c = 0; c < NC; ++c) {
    const size_t idx = (((size_t)b * NC + c) << 15) + rest;
    float S = HS[idx];
    float sd = sdl[((size_t)b * NC + c) * 2048 + d];
    HS[idx] = h;
    h = __expf(sd * Ac) * h + S;
  }
}

// pass3: scan from HS, local n-reduce, z = y * silu_res (rb already silu'd bf16)
__global__ __launch_bounds__(256, 4)
void scan_pass3(const float* __restrict__ delta, const unsigned short* __restrict__ ub,
                const float* __restrict__ xp, const float* __restrict__ A_log,
                const float* __restrict__ HS, const unsigned short* __restrict__ rb,
                short* __restrict__ zb)
{
  const int d = blockIdx.y * 256 + threadIdx.x;
  const int c = blockIdx.x, b = blockIdx.z;
  const int t0 = (b << 10) + c * LC;
  float Ac[16];
#pragma unroll
  for (int q = 0; q < 4; ++q) {
    float4 a = *reinterpret_cast<const float4*>(A_log + (size_t)d * 16 + q * 4);
    Ac[q * 4 + 0] = -__expf(a.x); Ac[q * 4 + 1] = -__expf(a.y);
    Ac[q * 4 + 2] = -__expf(a.z); Ac[q * 4 + 3] = -__expf(a.w);
  }
  float h[16];
  const float* hs = HS + (((size_t)b * NC + c) * 2048 + d) * 16;
#pragma unroll
  for (int q = 0; q < 4; ++q) {
    float4 v = *reinterpret_cast<const float4*>(hs + q * 4);
    h[q * 4 + 0] = v.x; h[q * 4 + 1] = v.y; h[q * 4 + 2] = v.z; h[q * 4 + 3] = v.w;
  }
  const float* dp = delta + (size_t)t0 * 2048 + d;
  const unsigned short* up = ub + (size_t)t0 * 2048 + d;
  const float* xb = xp + (size_t)t0 * 96 + DT_RANK;
  const float* xc = xp + (size_t)t0 * 96 + DT_RANK + N_ST;
  const unsigned short* rp = rb + (size_t)t0 * 2048 + d;
  short* zp = zb + (size_t)t0 * 2048 + d;
#pragma unroll 4
  for (int t = 0; t < LC; ++t) {
    float dl = dp[(size_t)t * 2048];
    float ul = b2f(up[(size_t)t * 2048]);
    float rv = b2f(rp[(size_t)t * 2048]);   // silu(res) already applied
    float Bf[16], Cf[16];
#pragma unroll
    for (int q = 0; q < 4; ++q) {
      *reinterpret_cast<float4*>(&Bf[q * 4]) =
          *reinterpret_cast<const float4*>(xb + (size_t)t * 96 + q * 4);
      *reinterpret_cast<float4*>(&Cf[q * 4]) =
          *reinterpret_cast<const float4*>(xc + (size_t)t * 96 + q * 4);
    }
    float dlu = dl * ul;
    float p0 = 0.f, p1 = 0.f, p2 = 0.f, p3 = 0.f;
#pragma unroll
    for (int n = 0; n < 16; ++n) {
      h[n] = __expf(dl * Ac[n]) * h[n] + dlu * Bf[n];
      float t2 = h[n] * Cf[n];
      if ((n & 3) == 0) p0 += t2;
      else if ((n & 3) == 1) p1 += t2;
      else if ((n & 3) == 2) p2 += t2;
      else p3 += t2;
    }
    float p = (p0 + p1) + (p2 + p3);
    zp[(size_t)t * 2048] = f2b(p * rv);
  }
}

extern "C" void kernel_launch(void* const* d_in, const int* in_sizes, int n_in,
                              void* d_out, int out_size, void* d_ws, size_t ws_size,
                              hipStream_t stream)
{
  const float* x      = (const float*)d_in[0];
  const float* A_log  = (const float*)d_in[1];
  const float* W_in   = (const float*)d_in[2];
  const float* b_in   = (const float*)d_in[3];
  const float* conv_w = (const float*)d_in[4];
  const float* conv_b = (const float*)d_in[5];
  const float* W_x    = (const float*)d_in[6];
  const float* W_dt   = (const float*)d_in[7];
  const float* b_dt   = (const float*)d_in[8];
  const float* W_out  = (const float*)d_in[9];
  const float* b_out  = (const float*)d_in[10];
  float* out = (float*)d_out;

  // workspace layout (~129 MB)
  char* p = (char*)d_ws;
  float* xr     = (float*)p; p += (size_t)NTOK * 2048 * 4;          // 16MB u_pre fp32
  short* rb     = (short*)p; p += (size_t)NTOK * 2048 * 2;          // 8MB silu(res) bf16
  short* ub     = (short*)p; p += (size_t)NTOK * 2048 * 2;          // 8MB
  float* xp     = (float*)p; p += (size_t)NTOK * 96 * 4;            // .75MB dt|B|C fp32
  short* dtb    = (short*)p; p += (size_t)NTOK * 64 * 2;            // .25MB
  float* delta  = (float*)p; p += (size_t)NTOK * 2048 * 4;          // 16MB
  short* zb     = (short*)p; p += (size_t)NTOK * 2048 * 2;          // 8MB
  short* xb     = (short*)p; p += (size_t)NTOK * 1024 * 2;          // 4MB
  short* Wib    = (short*)p; p += (size_t)4096 * 1024 * 2;          // 8MB
  short* Wxb    = (short*)p; p += (size_t)128 * 2048 * 2;           // .5MB (96 rows + pad)
  short* Wdtb   = (short*)p; p += (size_t)2048 * 64 * 2;            // .25MB
  short* Wob    = (short*)p; p += (size_t)1024 * 2048 * 2;          // 4MB
  float* xppart = (float*)p; p += (size_t)8 * 2048 * 96 * 4;        // 6MB
  float* opart  = (float*)p; p += (size_t)4 * 2048 * 1024 * 4;      // 32MB
  float* sdl    = (float*)p; p += (size_t)BSZ * NC * 2048 * 4;      // 1MB
  float* HS     = (float*)p; p += (size_t)BSZ * NC * 2048 * 16 * 4; // 16MB

  // all pre-casts/transposes in one dispatch
  prep_kernel<<<dim3(PB_CAST + PB_WIN + PB_WX + PB_WDT + PB_WOUT), 256, 0, stream>>>(
      x, W_in, W_x, W_dt, W_out, xb, Wib, Wxb, Wdtb, Wob);

  // xr(u_pre fp32) | rb(silu(res) bf16) = x @ W_in + b_in
  gemm_kernel<0, 0, 1><<<dim3(32, 16, 1), 256, 0, stream>>>(
      xb, Wib, b_in, xr, rb, NTOK, 4096, 1024, 1024, 1024, 2048, 1024);
  // u = silu(conv(u_pre) + conv_b), bf16
  conv_silu_kernel<<<dim3(4096), 256, 0, stream>>>(xr, conv_w, conv_b, ub);
  // xp partials = u @ W_x (split-K 8, no atomics)
  gemm_kernel<0, 1, 0><<<dim3(1, 16, 8), 256, 0, stream>>>(
      ub, Wxb, nullptr, xppart, nullptr, NTOK, 96, 2048, 2048, 2048, 96, 256);
  // xp = sum(partials); dtb = bf16(dt cols)
  combine8_kernel<<<dim3(192), 256, 0, stream>>>(xppart, xp, dtb);
  // delta = softplus(dt @ W_dt + b_dt)
  gemm_kernel<1, 0, 0><<<dim3(16, 16, 1), 256, 0, stream>>>(
      dtb, Wdtb, b_dt, delta, nullptr, NTOK, 2048, 64, 64, 64, 2048, 64);
  // chunked selective scan -> zb (bf16, zmul fused)
  scan_pass1<<<dim3(NC, 8, BSZ), 256, 0, stream>>>(
      delta, (const unsigned short*)ub, xp, A_log, sdl, HS);
  scan_pass2<<<dim3(256), 256, 0, stream>>>(sdl, A_log, HS);
  scan_pass3<<<dim3(NC, 8, BSZ), 256, 0, stream>>>(
      delta, (const unsigned short*)ub, xp, A_log, HS, (const unsigned short*)rb, zb);
  // opart = z @ W_out partials (split-K 4, no atomics)
  gemm_kernel<0, 1, 0><<<dim3(8, 16, 4), 256, 0, stream>>>(
      zb, Wob, nullptr, opart, nullptr, NTOK, 1024, 2048, 2048, 2048, 1024, 512);
  // out = sum(partials) + b_out
  combine4_kernel<<<dim3(2048), 256, 0, stream>>>(opart, b_out, out);
}

// Round 8
// 158.004 us; speedup vs baseline: 3.2858x; 1.0095x over previous
//
#include <hip/hip_runtime.h>

#define D_MODEL 1024
#define D_INNER 2048
#define N_ST    16
#define DT_RANK 64
#define BSZ     2
#define SEQL    1024
#define NTOK    (BSZ*SEQL)   // 2048
#define NC      64           // scan chunks
#define LC      (SEQL/NC)    // 16 steps per chunk

typedef __attribute__((ext_vector_type(4))) float f32x4;
typedef __attribute__((ext_vector_type(8))) short bf16x8;

__device__ __forceinline__ short f2b(float f) {
  unsigned u = __builtin_bit_cast(unsigned, f);
  u += 0x7fffu + ((u >> 16) & 1u);           // round-to-nearest-even
  return (short)(u >> 16);
}

__device__ __forceinline__ float b2f(unsigned short s) {
  return __builtin_bit_cast(float, (unsigned)s << 16);
}

__device__ __forceinline__ void gload16(const void* g, void* l) {
  __builtin_amdgcn_global_load_lds(
      (const __attribute__((address_space(1))) void*)g,
      (__attribute__((address_space(3))) void*)l, 16, 0, 0);
}

// C[M,N] = epi(A[M,K] @ B[N,K]^T + bias); A,B bf16 (B pre-transposed [N][K]).
// 128x128 tile, BK=64, XOR-swizzled LDS, DOUBLE-BUFFERED with prefetch-before-
// compute (T3-minimum 2-phase: STAGE(next) -> ds_read+MFMA(cur) -> one
// vmcnt-drain barrier per tile).
// PARTIAL: C += z*M*ldc (split-K partial buffers, no atomics).
// RESSPLIT: cols < 2048 -> bf16 to upb (plain); cols >= 2048 -> silu bf16 to resb.
template<int SOFTPLUS, int PARTIAL, int RESSPLIT>
__global__ __launch_bounds__(256)
void gemm_kernel(const short* __restrict__ A, const short* __restrict__ Bm,
                 const float* __restrict__ bias, float* __restrict__ C,
                 short* __restrict__ upb, short* __restrict__ resb,
                 int M, int N, int K, int lda, int ldb, int ldc, int kChunk)
{
  __shared__ short sA[2][128 * 64];   // 2 x 16 KB
  __shared__ short sB[2][128 * 64];
  const int tid  = threadIdx.x;
  const int lane = tid & 63;
  const int wave = tid >> 6;
  const int wr = wave >> 1, wc = wave & 1;
  const int lr = lane & 15, lg = lane >> 4;
  const int m0 = blockIdx.y * 128;
  const int n0 = blockIdx.x * 128;
  const int kStart = blockIdx.z * kChunk;
  int kEnd = kStart + kChunk; if (kEnd > K) kEnd = K;
  const int nt = (kEnd - kStart) >> 6;

  if (PARTIAL) C += (size_t)blockIdx.z * M * ldc;

  // staging: wave covers 32 rows; one gload16 covers 8 rows x 64 k (1 KB).
  // source col-block XOR-swizzled by row&7 so swizzled ds_read sees G[row][cb].
  const int srow = lane >> 3;                 // 0..7 row within 8-row group
  const int scol = ((lane & 7) ^ srow) * 8;   // swizzled source col (bf16)
  const short* aS = A + (size_t)(m0 + wave * 32 + srow) * lda + scol + kStart;
  const short* bS = Bm + (size_t)(n0 + wave * 32 + srow) * ldb + scol + kStart;
  const int ldsOff = wave * 2048;             // wave's 32x64 region

#define STAGE(buf, koff)                                                   \
  {                                                                        \
    _Pragma("unroll")                                                      \
    for (int i_ = 0; i_ < 4; ++i_) {                                       \
      gload16(aS + (size_t)(i_ * 8) * lda + (koff), &sA[buf][ldsOff + i_ * 512]); \
      gload16(bS + (size_t)(i_ * 8) * ldb + (koff), &sB[buf][ldsOff + i_ * 512]); \
    }                                                                      \
  }

  f32x4 acc[4][4];
#pragma unroll
  for (int i = 0; i < 4; ++i)
#pragma unroll
    for (int j = 0; j < 4; ++j) acc[i][j] = (f32x4){0.f, 0.f, 0.f, 0.f};

  STAGE(0, 0);
  __syncthreads();

  for (int t = 0; t < nt; ++t) {
    const int cur = t & 1;
    if (t + 1 < nt) STAGE(cur ^ 1, (t + 1) * 64);

#pragma unroll
    for (int kk = 0; kk < 2; ++kk) {
      bf16x8 aF[4], bF[4];
#pragma unroll
      for (int mi = 0; mi < 4; ++mi) {
        const int row = wr * 64 + mi * 16 + lr;
        aF[mi] = *reinterpret_cast<const bf16x8*>(
            &sA[cur][row * 64 + (((kk * 4 + lg) ^ (lr & 7)) * 8)]);
      }
#pragma unroll
      for (int ni = 0; ni < 4; ++ni) {
        const int row = wc * 64 + ni * 16 + lr;
        bF[ni] = *reinterpret_cast<const bf16x8*>(
            &sB[cur][row * 64 + (((kk * 4 + lg) ^ (lr & 7)) * 8)]);
      }
#pragma unroll
      for (int mi = 0; mi < 4; ++mi)
#pragma unroll
        for (int ni = 0; ni < 4; ++ni)
          acc[mi][ni] = __builtin_amdgcn_mfma_f32_16x16x32_bf16(
              aF[mi], bF[ni], acc[mi][ni], 0, 0, 0);
    }
    __syncthreads();   // drains vmcnt(0)+lgkmcnt(0): next tile staged, cur reads done
  }
#undef STAGE

  // epilogue: C/D layout col=lane&15, row=(lane>>4)*4+reg
#pragma unroll
  for (int mi = 0; mi < 4; ++mi) {
    const int row = m0 + wr * 64 + mi * 16 + lg * 4;
#pragma unroll
    for (int ni = 0; ni < 4; ++ni) {
      const int col = n0 + wc * 64 + ni * 16 + lr;
      if (RESSPLIT) {
        const float bv = bias[col];
        if (col < 2048) {
#pragma unroll
          for (int j = 0; j < 4; ++j)
            upb[(size_t)(row + j) * 2048 + col] = f2b(acc[mi][ni][j] + bv);
        } else {
#pragma unroll
          for (int j = 0; j < 4; ++j) {
            float v = acc[mi][ni][j] + bv;
            resb[(size_t)(row + j) * 2048 + (col - 2048)] =
                f2b(v / (1.f + __expf(-v)));
          }
        }
      } else if (col < N) {
        float bv = (bias != nullptr && blockIdx.z == 0) ? bias[col] : 0.f;
#pragma unroll
        for (int j = 0; j < 4; ++j) {
          float v = acc[mi][ni][j] + bv;
          if (SOFTPLUS) v = fmaxf(v, 0.f) + log1pf(__expf(-fabsf(v)));
          C[(size_t)(row + j) * ldc + col] = v;
        }
      }
    }
  }
}

// ---- fused prep: castA(x) + transpose-cast of all 4 weights, one dispatch ----
__device__ __forceinline__ void trans_body(const float* __restrict__ in,
                                           short* __restrict__ out,
                                           int R, int C, int bx, int by,
                                           short (*t)[33], int tidx)
{
  const int c0 = bx * 32, r0 = by * 32;
  const int cc = tidx & 31, rr = tidx >> 5;  // rr 0..7
#pragma unroll
  for (int i = 0; i < 4; ++i)
    t[rr + i * 8][cc] = f2b(in[(size_t)(r0 + rr + i * 8) * C + c0 + cc]);
  __syncthreads();
#pragma unroll
  for (int i = 0; i < 4; ++i)
    out[(size_t)(c0 + rr + i * 8) * R + r0 + cc] = t[cc][rr + i * 8];
}

#define PB_CAST  2048
#define PB_WIN   4096
#define PB_WX    192
#define PB_WDT   128
#define PB_WOUT  2048

__global__ __launch_bounds__(256)
void prep_kernel(const float* __restrict__ x,    const float* __restrict__ W_in,
                 const float* __restrict__ W_x,  const float* __restrict__ W_dt,
                 const float* __restrict__ W_out,
                 short* __restrict__ xb,  short* __restrict__ Wib,
                 short* __restrict__ Wxb, short* __restrict__ Wdtb,
                 short* __restrict__ Wob)
{
  __shared__ short t[32][33];
  const int bid = blockIdx.x, tidx = threadIdx.x;
  if (bid < PB_CAST) {
    const int i = bid * 256 + tidx;
    float4 v = *reinterpret_cast<const float4*>(x + (size_t)i * 4);
    *reinterpret_cast<short4*>(xb + (size_t)i * 4) =
        make_short4(f2b(v.x), f2b(v.y), f2b(v.z), f2b(v.w));
  } else if (bid < PB_CAST + PB_WIN) {
    const int b = bid - PB_CAST;
    trans_body(W_in, Wib, 1024, 4096, b % 128, b / 128, t, tidx);
  } else if (bid < PB_CAST + PB_WIN + PB_WX) {
    const int b = bid - PB_CAST - PB_WIN;
    trans_body(W_x, Wxb, 2048, 96, b % 3, b / 3, t, tidx);
  } else if (bid < PB_CAST + PB_WIN + PB_WX + PB_WDT) {
    const int b = bid - PB_CAST - PB_WIN - PB_WX;
    trans_body(W_dt, Wdtb, 64, 2048, b % 64, b / 64, t, tidx);
  } else {
    const int b = bid - PB_CAST - PB_WIN - PB_WX - PB_WDT;
    trans_body(W_out, Wob, 2048, 1024, b % 32, b / 32, t, tidx);
  }
}

// combine 16 split-K partials of GEMM2 -> xp fp32 [2048][96]; dt cols -> dtb bf16
__global__ __launch_bounds__(256)
void combine16_kernel(const float* __restrict__ part, float* __restrict__ xp,
                      short* __restrict__ dtb)
{
  const int gid = blockIdx.x * 256 + threadIdx.x;   // 0 .. 2048*24-1
  const int r = gid / 24, q = gid - r * 24;
  float4 s = make_float4(0.f, 0.f, 0.f, 0.f);
#pragma unroll
  for (int c = 0; c < 16; ++c) {
    const float4 v = *reinterpret_cast<const float4*>(
        part + (size_t)c * 2048 * 96 + (size_t)r * 96 + q * 4);
    s.x += v.x; s.y += v.y; s.z += v.z; s.w += v.w;
  }
  *reinterpret_cast<float4*>(xp + (size_t)r * 96 + q * 4) = s;
  if (q < 16)
    *reinterpret_cast<short4*>(dtb + (size_t)r * 64 + q * 4) =
        make_short4(f2b(s.x), f2b(s.y), f2b(s.z), f2b(s.w));
}

// combine 4 split-K partials of GEMM4 + bias -> out fp32 [2048][1024]
__global__ __launch_bounds__(256)
void combine4_kernel(const float* __restrict__ part, const float* __restrict__ bias,
                     float* __restrict__ out)
{
  const int gid = blockIdx.x * 256 + threadIdx.x;   // over 2048*256 float4s
  const int r = gid >> 8, c4 = gid & 255;
  const float4 bv = *reinterpret_cast<const float4*>(bias + c4 * 4);
  float4 s = bv;
#pragma unroll
  for (int z = 0; z < 4; ++z) {
    const float4 v = *reinterpret_cast<const float4*>(
        part + (size_t)z * 2048 * 1024 + (size_t)r * 1024 + c4 * 4);
    s.x += v.x; s.y += v.y; s.z += v.z; s.w += v.w;
  }
  *reinterpret_cast<float4*>(out + (size_t)r * 1024 + c4 * 4) = s;
}

// causal depthwise conv(K=3) + bias + silu; u_pre bf16 [t][2048] -> ub bf16
__global__ __launch_bounds__(256)
void conv_silu_kernel(const unsigned short* __restrict__ up, const float* __restrict__ cw,
                      const float* __restrict__ cb, short* __restrict__ ub)
{
  int i  = blockIdx.x * 256 + threadIdx.x;
  int t  = i >> 9;
  int dq = (i & 511) << 2;
  int l  = t & (SEQL - 1);
  float4 w0 = *reinterpret_cast<const float4*>(cw + dq * 3);
  float4 w1 = *reinterpret_cast<const float4*>(cw + dq * 3 + 4);
  float4 w2 = *reinterpret_cast<const float4*>(cw + dq * 3 + 8);
  float4 bb = *reinterpret_cast<const float4*>(cb + dq);
  ushort4 X2 = *reinterpret_cast<const ushort4*>(up + (size_t)t * 2048 + dq);
  ushort4 z4; z4.x = z4.y = z4.z = z4.w = 0;
  ushort4 X1 = (l >= 1) ? *reinterpret_cast<const ushort4*>(up + (size_t)(t - 1) * 2048 + dq) : z4;
  ushort4 X0 = (l >= 2) ? *reinterpret_cast<const ushort4*>(up + (size_t)(t - 2) * 2048 + dq) : z4;
  float r0 = bb.x + w0.x * b2f(X0.x) + w0.y * b2f(X1.x) + w0.z * b2f(X2.x);
  float r1 = bb.y + w0.w * b2f(X0.y) + w1.x * b2f(X1.y) + w1.y * b2f(X2.y);
  float r2 = bb.z + w1.z * b2f(X0.z) + w1.w * b2f(X1.z) + w2.x * b2f(X2.z);
  float r3 = bb.w + w2.y * b2f(X0.w) + w2.z * b2f(X1.w) + w2.w * b2f(X2.w);
  float o0 = r0 / (1.f + __expf(-r0));
  float o1 = r1 / (1.f + __expf(-r1));
  float o2 = r2 / (1.f + __expf(-r2));
  float o3 = r3 / (1.f + __expf(-r3));
  *reinterpret_cast<short4*>(ub + (size_t)t * 2048 + dq) =
      make_short4(f2b(o0), f2b(o1), f2b(o2), f2b(o3));
}

// ---- chunked selective scan: thread owns (b, chunk, d) with all 16 n ----
__global__ __launch_bounds__(256, 4)
void scan_pass1(const float* __restrict__ delta, const unsigned short* __restrict__ ub,
                const float* __restrict__ xp, const float* __restrict__ A_log,
                float* __restrict__ sdl, float* __restrict__ HS)
{
  const int d = blockIdx.y * 256 + threadIdx.x;
  const int c = blockIdx.x, b = blockIdx.z;
  const int t0 = (b << 10) + c * LC;
  float Ac[16];
#pragma unroll
  for (int q = 0; q < 4; ++q) {
    float4 a = *reinterpret_cast<const float4*>(A_log + (size_t)d * 16 + q * 4);
    Ac[q * 4 + 0] = -__expf(a.x); Ac[q * 4 + 1] = -__expf(a.y);
    Ac[q * 4 + 2] = -__expf(a.z); Ac[q * 4 + 3] = -__expf(a.w);
  }
  float h[16];
#pragma unroll
  for (int n = 0; n < 16; ++n) h[n] = 0.f;
  float sd = 0.f;
  const float* dp = delta + (size_t)t0 * 2048 + d;
  const unsigned short* up = ub + (size_t)t0 * 2048 + d;
  const float* xb = xp + (size_t)t0 * 96 + DT_RANK;
#pragma unroll 4
  for (int t = 0; t < LC; ++t) {
    float dl = dp[(size_t)t * 2048];
    float ul = b2f(up[(size_t)t * 2048]);
    float Bf[16];
#pragma unroll
    for (int q = 0; q < 4; ++q)
      *reinterpret_cast<float4*>(&Bf[q * 4]) =
          *reinterpret_cast<const float4*>(xb + (size_t)t * 96 + q * 4);
    float dlu = dl * ul;
    sd += dl;
#pragma unroll
    for (int n = 0; n < 16; ++n)
      h[n] = __expf(dl * Ac[n]) * h[n] + dlu * Bf[n];
  }
  sdl[((size_t)b * NC + c) * 2048 + d] = sd;
  float* hs = HS + (((size_t)b * NC + c) * 2048 + d) * 16;
#pragma unroll
  for (int q = 0; q < 4; ++q)
    *reinterpret_cast<float4*>(hs + q * 4) =
        make_float4(h[q * 4], h[q * 4 + 1], h[q * 4 + 2], h[q * 4 + 3]);
}

__global__ __launch_bounds__(256)
void scan_pass2(const float* __restrict__ sdl, const float* __restrict__ A_log,
                float* __restrict__ HS)
{
  const int gid = blockIdx.x * 256 + threadIdx.x;  // 0..65535
  const int b = gid >> 15, rest = gid & 32767;     // rest = d*16+n
  const int d = rest >> 4;
  const float Ac = -__expf(A_log[rest]);
  float h = 0.f;
  for (int c = 0; c < NC; ++c) {
    const size_t idx = (((size_t)b * NC + c) << 15) + rest;
    float S = HS[idx];
    float sd = sdl[((size_t)b * NC + c) * 2048 + d];
    HS[idx] = h;
    h = __expf(sd * Ac) * h + S;
  }
}

// pass3: scan from HS, local n-reduce, z = y * silu_res (rb already silu'd bf16)
__global__ __launch_bounds__(256, 4)
void scan_pass3(const float* __restrict__ delta, const unsigned short* __restrict__ ub,
                const float* __restrict__ xp, const float* __restrict__ A_log,
                const float* __restrict__ HS, const unsigned short* __restrict__ rb,
                short* __restrict__ zb)
{
  const int d = blockIdx.y * 256 + threadIdx.x;
  const int c = blockIdx.x, b = blockIdx.z;
  const int t0 = (b << 10) + c * LC;
  float Ac[16];
#pragma unroll
  for (int q = 0; q < 4; ++q) {
    float4 a = *reinterpret_cast<const float4*>(A_log + (size_t)d * 16 + q * 4);
    Ac[q * 4 + 0] = -__expf(a.x); Ac[q * 4 + 1] = -__expf(a.y);
    Ac[q * 4 + 2] = -__expf(a.z); Ac[q * 4 + 3] = -__expf(a.w);
  }
  float h[16];
  const float* hs = HS + (((size_t)b * NC + c) * 2048 + d) * 16;
#pragma unroll
  for (int q = 0; q < 4; ++q) {
    float4 v = *reinterpret_cast<const float4*>(hs + q * 4);
    h[q * 4 + 0] = v.x; h[q * 4 + 1] = v.y; h[q * 4 + 2] = v.z; h[q * 4 + 3] = v.w;
  }
  const float* dp = delta + (size_t)t0 * 2048 + d;
  const unsigned short* up = ub + (size_t)t0 * 2048 + d;
  const float* xb = xp + (size_t)t0 * 96 + DT_RANK;
  const float* xc = xp + (size_t)t0 * 96 + DT_RANK + N_ST;
  const unsigned short* rp = rb + (size_t)t0 * 2048 + d;
  short* zp = zb + (size_t)t0 * 2048 + d;
#pragma unroll 4
  for (int t = 0; t < LC; ++t) {
    float dl = dp[(size_t)t * 2048];
    float ul = b2f(up[(size_t)t * 2048]);
    float rv = b2f(rp[(size_t)t * 2048]);   // silu(res) already applied
    float Bf[16], Cf[16];
#pragma unroll
    for (int q = 0; q < 4; ++q) {
      *reinterpret_cast<float4*>(&Bf[q * 4]) =
          *reinterpret_cast<const float4*>(xb + (size_t)t * 96 + q * 4);
      *reinterpret_cast<float4*>(&Cf[q * 4]) =
          *reinterpret_cast<const float4*>(xc + (size_t)t * 96 + q * 4);
    }
    float dlu = dl * ul;
    float p0 = 0.f, p1 = 0.f, p2 = 0.f, p3 = 0.f;
#pragma unroll
    for (int n = 0; n < 16; ++n) {
      h[n] = __expf(dl * Ac[n]) * h[n] + dlu * Bf[n];
      float t2 = h[n] * Cf[n];
      if ((n & 3) == 0) p0 += t2;
      else if ((n & 3) == 1) p1 += t2;
      else if ((n & 3) == 2) p2 += t2;
      else p3 += t2;
    }
    float p = (p0 + p1) + (p2 + p3);
    zp[(size_t)t * 2048] = f2b(p * rv);
  }
}

extern "C" void kernel_launch(void* const* d_in, const int* in_sizes, int n_in,
                              void* d_out, int out_size, void* d_ws, size_t ws_size,
                              hipStream_t stream)
{
  const float* x      = (const float*)d_in[0];
  const float* A_log  = (const float*)d_in[1];
  const float* W_in   = (const float*)d_in[2];
  const float* b_in   = (const float*)d_in[3];
  const float* conv_w = (const float*)d_in[4];
  const float* conv_b = (const float*)d_in[5];
  const float* W_x    = (const float*)d_in[6];
  const float* W_dt   = (const float*)d_in[7];
  const float* b_dt   = (const float*)d_in[8];
  const float* W_out  = (const float*)d_in[9];
  const float* b_out  = (const float*)d_in[10];
  float* out = (float*)d_out;

  // workspace layout (~115 MB)
  char* p = (char*)d_ws;
  short* upb    = (short*)p; p += (size_t)NTOK * 2048 * 2;          // 8MB u_pre bf16
  short* rb     = (short*)p; p += (size_t)NTOK * 2048 * 2;          // 8MB silu(res) bf16
  short* ub     = (short*)p; p += (size_t)NTOK * 2048 * 2;          // 8MB
  float* xp     = (float*)p; p += (size_t)NTOK * 96 * 4;            // .75MB dt|B|C fp32
  short* dtb    = (short*)p; p += (size_t)NTOK * 64 * 2;            // .25MB
  float* delta  = (float*)p; p += (size_t)NTOK * 2048 * 4;          // 16MB
  short* zb     = (short*)p; p += (size_t)NTOK * 2048 * 2;          // 8MB
  short* xb     = (short*)p; p += (size_t)NTOK * 1024 * 2;          // 4MB
  short* Wib    = (short*)p; p += (size_t)4096 * 1024 * 2;          // 8MB
  short* Wxb    = (short*)p; p += (size_t)128 * 2048 * 2;           // .5MB (96 rows + pad)
  short* Wdtb   = (short*)p; p += (size_t)2048 * 64 * 2;            // .25MB
  short* Wob    = (short*)p; p += (size_t)1024 * 2048 * 2;          // 4MB
  float* scr    = (float*)p; p += (size_t)4 * 2048 * 1024 * 4;      // 32MB shared scratch
  float* xppart = scr;   // 16 x 2048 x 96 fp32 = 12MB (lifetime: GEMM2..combine16)
  float* opart  = scr;   // 4 x 2048 x 1024 fp32 = 32MB (lifetime: GEMM4..combine4)
  float* sdl    = (float*)p; p += (size_t)BSZ * NC * 2048 * 4;      // 1MB
  float* HS     = (float*)p; p += (size_t)BSZ * NC * 2048 * 16 * 4; // 16MB

  // all pre-casts/transposes in one dispatch
  prep_kernel<<<dim3(PB_CAST + PB_WIN + PB_WX + PB_WDT + PB_WOUT), 256, 0, stream>>>(
      x, W_in, W_x, W_dt, W_out, xb, Wib, Wxb, Wdtb, Wob);

  // upb(u_pre bf16) | rb(silu(res) bf16) = x @ W_in + b_in
  gemm_kernel<0, 0, 1><<<dim3(32, 16, 1), 256, 0, stream>>>(
      xb, Wib, b_in, nullptr, upb, rb, NTOK, 4096, 1024, 1024, 1024, 0, 1024);
  // u = silu(conv(u_pre) + conv_b), bf16
  conv_silu_kernel<<<dim3(4096), 256, 0, stream>>>(
      (const unsigned short*)upb, conv_w, conv_b, ub);
  // xp partials = u @ W_x (split-K 16, no atomics)
  gemm_kernel<0, 1, 0><<<dim3(1, 16, 16), 256, 0, stream>>>(
      ub, Wxb, nullptr, xppart, nullptr, nullptr, NTOK, 96, 2048, 2048, 2048, 96, 128);
  // xp = sum(partials); dtb = bf16(dt cols)
  combine16_kernel<<<dim3(192), 256, 0, stream>>>(xppart, xp, dtb);
  // delta = softplus(dt @ W_dt + b_dt)
  gemm_kernel<1, 0, 0><<<dim3(16, 16, 1), 256, 0, stream>>>(
      dtb, Wdtb, b_dt, delta, nullptr, nullptr, NTOK, 2048, 64, 64, 64, 2048, 64);
  // chunked selective scan -> zb (bf16, zmul fused)
  scan_pass1<<<dim3(NC, 8, BSZ), 256, 0, stream>>>(
      delta, (const unsigned short*)ub, xp, A_log, sdl, HS);
  scan_pass2<<<dim3(256), 256, 0, stream>>>(sdl, A_log, HS);
  scan_pass3<<<dim3(NC, 8, BSZ), 256, 0, stream>>>(
      delta, (const unsigned short*)ub, xp, A_log, HS, (const unsigned short*)rb, zb);
  // opart = z @ W_out partials (split-K 4, no atomics)
  gemm_kernel<0, 1, 0><<<dim3(8, 16, 4), 256, 0, stream>>>(
      zb, Wob, nullptr, opart, nullptr, nullptr, NTOK, 1024, 2048, 2048, 2048, 1024, 512);
  // out = sum(partials) + b_out
  combine4_kernel<<<dim3(2048), 256, 0, stream>>>(opart, b_out, out);
}

// Round 9
// 151.348 us; speedup vs baseline: 3.4303x; 1.0440x over previous
//
#include <hip/hip_runtime.h>

#define D_MODEL 1024
#define D_INNER 2048
#define N_ST    16
#define DT_RANK 64
#define BSZ     2
#define SEQL    1024
#define NTOK    (BSZ*SEQL)   // 2048
#define NC      64           // scan chunks
#define LC      (SEQL/NC)    // 16 steps per chunk

typedef __attribute__((ext_vector_type(4))) float f32x4;
typedef __attribute__((ext_vector_type(8))) short bf16x8;

__device__ __forceinline__ short f2b(float f) {
  unsigned u = __builtin_bit_cast(unsigned, f);
  u += 0x7fffu + ((u >> 16) & 1u);           // round-to-nearest-even
  return (short)(u >> 16);
}

__device__ __forceinline__ float b2f(unsigned short s) {
  return __builtin_bit_cast(float, (unsigned)s << 16);
}

__device__ __forceinline__ void gload16(const void* g, void* l) {
  __builtin_amdgcn_global_load_lds(
      (const __attribute__((address_space(1))) void*)g,
      (__attribute__((address_space(3))) void*)l, 16, 0, 0);
}

// C[M,N] = epi(A[M,K] @ B[N,K]^T + bias); A,B bf16 (B pre-transposed [N][K]).
// 128x128 tile, BK=64, XOR-swizzled LDS, double-buffered with T4 counted-vmcnt:
// STAGE(t+1) -> s_waitcnt vmcnt(8) (tile-t loads done, t+1's 8 stay in flight)
// -> barrier -> ds_read+MFMA(t) -> barrier. Never drains vmcnt to 0 mid-loop.
// PARTIAL: C += z*M*ldc (split-K partial buffers, no atomics).
// RESSPLIT: cols < 2048 -> bf16 to upb; cols >= 2048 -> silu bf16 to resb.
// OUTB16: store epi result as bf16 to upb at ldc stride.
template<int SOFTPLUS, int PARTIAL, int RESSPLIT, int OUTB16>
__global__ __launch_bounds__(256)
void gemm_kernel(const short* __restrict__ A, const short* __restrict__ Bm,
                 const float* __restrict__ bias, float* __restrict__ C,
                 short* __restrict__ upb, short* __restrict__ resb,
                 int M, int N, int K, int lda, int ldb, int ldc, int kChunk)
{
  __shared__ short sA[2][128 * 64];   // 2 x 16 KB
  __shared__ short sB[2][128 * 64];
  const int tid  = threadIdx.x;
  const int lane = tid & 63;
  const int wave = tid >> 6;
  const int wr = wave >> 1, wc = wave & 1;
  const int lr = lane & 15, lg = lane >> 4;
  const int m0 = blockIdx.y * 128;
  const int n0 = blockIdx.x * 128;
  const int kStart = blockIdx.z * kChunk;
  int kEnd = kStart + kChunk; if (kEnd > K) kEnd = K;
  const int nt = (kEnd - kStart) >> 6;

  if (PARTIAL) C += (size_t)blockIdx.z * M * ldc;

  // staging: wave covers 32 rows; one gload16 covers 8 rows x 64 k (1 KB).
  // source col-block XOR-swizzled by row&7 so swizzled ds_read sees G[row][cb].
  const int srow = lane >> 3;                 // 0..7 row within 8-row group
  const int scol = ((lane & 7) ^ srow) * 8;   // swizzled source col (bf16)
  const short* aS = A + (size_t)(m0 + wave * 32 + srow) * lda + scol + kStart;
  const short* bS = Bm + (size_t)(n0 + wave * 32 + srow) * ldb + scol + kStart;
  const int ldsOff = wave * 2048;             // wave's 32x64 region

#define STAGE(buf, koff)                                                   \
  {                                                                        \
    _Pragma("unroll")                                                      \
    for (int i_ = 0; i_ < 4; ++i_) {                                       \
      gload16(aS + (size_t)(i_ * 8) * lda + (koff), &sA[buf][ldsOff + i_ * 512]); \
      gload16(bS + (size_t)(i_ * 8) * ldb + (koff), &sB[buf][ldsOff + i_ * 512]); \
    }                                                                      \
  }

  f32x4 acc[4][4];
#pragma unroll
  for (int i = 0; i < 4; ++i)
#pragma unroll
    for (int j = 0; j < 4; ++j) acc[i][j] = (f32x4){0.f, 0.f, 0.f, 0.f};

  STAGE(0, 0);

  for (int t = 0; t < nt; ++t) {
    const int cur = t & 1;
    if (t + 1 < nt) {
      STAGE(cur ^ 1, (t + 1) * 64);
      asm volatile("s_waitcnt vmcnt(8)" ::: "memory");  // tile-t staged; t+1 in flight
    } else {
      asm volatile("s_waitcnt vmcnt(0)" ::: "memory");
    }
    __builtin_amdgcn_s_barrier();   // all waves' tile-t data visible in LDS

#pragma unroll
    for (int kk = 0; kk < 2; ++kk) {
      bf16x8 aF[4], bF[4];
#pragma unroll
      for (int mi = 0; mi < 4; ++mi) {
        const int row = wr * 64 + mi * 16 + lr;
        aF[mi] = *reinterpret_cast<const bf16x8*>(
            &sA[cur][row * 64 + (((kk * 4 + lg) ^ (lr & 7)) * 8)]);
      }
#pragma unroll
      for (int ni = 0; ni < 4; ++ni) {
        const int row = wc * 64 + ni * 16 + lr;
        bF[ni] = *reinterpret_cast<const bf16x8*>(
            &sB[cur][row * 64 + (((kk * 4 + lg) ^ (lr & 7)) * 8)]);
      }
#pragma unroll
      for (int mi = 0; mi < 4; ++mi)
#pragma unroll
        for (int ni = 0; ni < 4; ++ni)
          acc[mi][ni] = __builtin_amdgcn_mfma_f32_16x16x32_bf16(
              aF[mi], bF[ni], acc[mi][ni], 0, 0, 0);
    }
    __builtin_amdgcn_s_barrier();   // buf[cur] free for STAGE at t+1
  }
#undef STAGE

  // epilogue: C/D layout col=lane&15, row=(lane>>4)*4+reg
#pragma unroll
  for (int mi = 0; mi < 4; ++mi) {
    const int row = m0 + wr * 64 + mi * 16 + lg * 4;
#pragma unroll
    for (int ni = 0; ni < 4; ++ni) {
      const int col = n0 + wc * 64 + ni * 16 + lr;
      if (RESSPLIT) {
        const float bv = bias[col];
        if (col < 2048) {
#pragma unroll
          for (int j = 0; j < 4; ++j)
            upb[(size_t)(row + j) * 2048 + col] = f2b(acc[mi][ni][j] + bv);
        } else {
#pragma unroll
          for (int j = 0; j < 4; ++j) {
            float v = acc[mi][ni][j] + bv;
            resb[(size_t)(row + j) * 2048 + (col - 2048)] =
                f2b(v / (1.f + __expf(-v)));
          }
        }
      } else if (OUTB16) {
        const float bv = bias[col];
#pragma unroll
        for (int j = 0; j < 4; ++j) {
          float v = acc[mi][ni][j] + bv;
          if (SOFTPLUS) v = fmaxf(v, 0.f) + log1pf(__expf(-fabsf(v)));
          upb[(size_t)(row + j) * ldc + col] = f2b(v);
        }
      } else if (col < N) {
        float bv = (bias != nullptr && blockIdx.z == 0) ? bias[col] : 0.f;
#pragma unroll
        for (int j = 0; j < 4; ++j) {
          float v = acc[mi][ni][j] + bv;
          if (SOFTPLUS) v = fmaxf(v, 0.f) + log1pf(__expf(-fabsf(v)));
          C[(size_t)(row + j) * ldc + col] = v;
        }
      }
    }
  }
}

// ---- fused prep: castA(x) + transpose-cast of all 4 weights, one dispatch ----
__device__ __forceinline__ void trans_body(const float* __restrict__ in,
                                           short* __restrict__ out,
                                           int R, int C, int bx, int by,
                                           short (*t)[33], int tidx)
{
  const int c0 = bx * 32, r0 = by * 32;
  const int cc = tidx & 31, rr = tidx >> 5;  // rr 0..7
#pragma unroll
  for (int i = 0; i < 4; ++i)
    t[rr + i * 8][cc] = f2b(in[(size_t)(r0 + rr + i * 8) * C + c0 + cc]);
  __syncthreads();
#pragma unroll
  for (int i = 0; i < 4; ++i)
    out[(size_t)(c0 + rr + i * 8) * R + r0 + cc] = t[cc][rr + i * 8];
}

#define PB_CAST  2048
#define PB_WIN   4096
#define PB_WX    192
#define PB_WDT   128
#define PB_WOUT  2048

__global__ __launch_bounds__(256)
void prep_kernel(const float* __restrict__ x,    const float* __restrict__ W_in,
                 const float* __restrict__ W_x,  const float* __restrict__ W_dt,
                 const float* __restrict__ W_out,
                 short* __restrict__ xb,  short* __restrict__ Wib,
                 short* __restrict__ Wxb, short* __restrict__ Wdtb,
                 short* __restrict__ Wob)
{
  __shared__ short t[32][33];
  const int bid = blockIdx.x, tidx = threadIdx.x;
  if (bid < PB_CAST) {
    const int i = bid * 256 + tidx;
    float4 v = *reinterpret_cast<const float4*>(x + (size_t)i * 4);
    *reinterpret_cast<short4*>(xb + (size_t)i * 4) =
        make_short4(f2b(v.x), f2b(v.y), f2b(v.z), f2b(v.w));
  } else if (bid < PB_CAST + PB_WIN) {
    const int b = bid - PB_CAST;
    trans_body(W_in, Wib, 1024, 4096, b % 128, b / 128, t, tidx);
  } else if (bid < PB_CAST + PB_WIN + PB_WX) {
    const int b = bid - PB_CAST - PB_WIN;
    trans_body(W_x, Wxb, 2048, 96, b % 3, b / 3, t, tidx);
  } else if (bid < PB_CAST + PB_WIN + PB_WX + PB_WDT) {
    const int b = bid - PB_CAST - PB_WIN - PB_WX;
    trans_body(W_dt, Wdtb, 64, 2048, b % 64, b / 64, t, tidx);
  } else {
    const int b = bid - PB_CAST - PB_WIN - PB_WX - PB_WDT;
    trans_body(W_out, Wob, 2048, 1024, b % 32, b / 32, t, tidx);
  }
}

// combine 16 split-K partials of GEMM2 -> xp fp32 [2048][96]; dt cols -> dtb bf16
__global__ __launch_bounds__(256)
void combine16_kernel(const float* __restrict__ part, float* __restrict__ xp,
                      short* __restrict__ dtb)
{
  const int gid = blockIdx.x * 256 + threadIdx.x;   // 0 .. 2048*24-1
  const int r = gid / 24, q = gid - r * 24;
  float4 s = make_float4(0.f, 0.f, 0.f, 0.f);
#pragma unroll
  for (int c = 0; c < 16; ++c) {
    const float4 v = *reinterpret_cast<const float4*>(
        part + (size_t)c * 2048 * 96 + (size_t)r * 96 + q * 4);
    s.x += v.x; s.y += v.y; s.z += v.z; s.w += v.w;
  }
  *reinterpret_cast<float4*>(xp + (size_t)r * 96 + q * 4) = s;
  if (q < 16)
    *reinterpret_cast<short4*>(dtb + (size_t)r * 64 + q * 4) =
        make_short4(f2b(s.x), f2b(s.y), f2b(s.z), f2b(s.w));
}

// combine 4 split-K partials of GEMM4 + bias -> out fp32 [2048][1024]
__global__ __launch_bounds__(256)
void combine4_kernel(const float* __restrict__ part, const float* __restrict__ bias,
                     float* __restrict__ out)
{
  const int gid = blockIdx.x * 256 + threadIdx.x;   // over 2048*256 float4s
  const int r = gid >> 8, c4 = gid & 255;
  const float4 bv = *reinterpret_cast<const float4*>(bias + c4 * 4);
  float4 s = bv;
#pragma unroll
  for (int z = 0; z < 4; ++z) {
    const float4 v = *reinterpret_cast<const float4*>(
        part + (size_t)z * 2048 * 1024 + (size_t)r * 1024 + c4 * 4);
    s.x += v.x; s.y += v.y; s.z += v.z; s.w += v.w;
  }
  *reinterpret_cast<float4*>(out + (size_t)r * 1024 + c4 * 4) = s;
}

// causal depthwise conv(K=3) + bias + silu; u_pre bf16 [t][2048] -> ub bf16
__global__ __launch_bounds__(256)
void conv_silu_kernel(const unsigned short* __restrict__ up, const float* __restrict__ cw,
                      const float* __restrict__ cb, short* __restrict__ ub)
{
  int i  = blockIdx.x * 256 + threadIdx.x;
  int t  = i >> 9;
  int dq = (i & 511) << 2;
  int l  = t & (SEQL - 1);
  float4 w0 = *reinterpret_cast<const float4*>(cw + dq * 3);
  float4 w1 = *reinterpret_cast<const float4*>(cw + dq * 3 + 4);
  float4 w2 = *reinterpret_cast<const float4*>(cw + dq * 3 + 8);
  float4 bb = *reinterpret_cast<const float4*>(cb + dq);
  ushort4 X2 = *reinterpret_cast<const ushort4*>(up + (size_t)t * 2048 + dq);
  ushort4 z4; z4.x = z4.y = z4.z = z4.w = 0;
  ushort4 X1 = (l >= 1) ? *reinterpret_cast<const ushort4*>(up + (size_t)(t - 1) * 2048 + dq) : z4;
  ushort4 X0 = (l >= 2) ? *reinterpret_cast<const ushort4*>(up + (size_t)(t - 2) * 2048 + dq) : z4;
  float r0 = bb.x + w0.x * b2f(X0.x) + w0.y * b2f(X1.x) + w0.z * b2f(X2.x);
  float r1 = bb.y + w0.w * b2f(X0.y) + w1.x * b2f(X1.y) + w1.y * b2f(X2.y);
  float r2 = bb.z + w1.z * b2f(X0.z) + w1.w * b2f(X1.z) + w2.x * b2f(X2.z);
  float r3 = bb.w + w2.y * b2f(X0.w) + w2.z * b2f(X1.w) + w2.w * b2f(X2.w);
  float o0 = r0 / (1.f + __expf(-r0));
  float o1 = r1 / (1.f + __expf(-r1));
  float o2 = r2 / (1.f + __expf(-r2));
  float o3 = r3 / (1.f + __expf(-r3));
  *reinterpret_cast<short4*>(ub + (size_t)t * 2048 + dq) =
      make_short4(f2b(o0), f2b(o1), f2b(o2), f2b(o3));
}

// ---- chunked selective scan: thread owns (b, chunk, d) with all 16 n ----
__global__ __launch_bounds__(256, 4)
void scan_pass1(const unsigned short* __restrict__ deltab, const unsigned short* __restrict__ ub,
                const float* __restrict__ xp, const float* __restrict__ A_log,
                float* __restrict__ sdl, float* __restrict__ HS)
{
  const int d = blockIdx.y * 256 + threadIdx.x;
  const int c = blockIdx.x, b = blockIdx.z;
  const int t0 = (b << 10) + c * LC;
  float Ac[16];
#pragma unroll
  for (int q = 0; q < 4; ++q) {
    float4 a = *reinterpret_cast<const float4*>(A_log + (size_t)d * 16 + q * 4);
    Ac[q * 4 + 0] = -__expf(a.x); Ac[q * 4 + 1] = -__expf(a.y);
    Ac[q * 4 + 2] = -__expf(a.z); Ac[q * 4 + 3] = -__expf(a.w);
  }
  float h[16];
#pragma unroll
  for (int n = 0; n < 16; ++n) h[n] = 0.f;
  float sd = 0.f;
  const unsigned short* dp = deltab + (size_t)t0 * 2048 + d;
  const unsigned short* up = ub + (size_t)t0 * 2048 + d;
  const float* xb = xp + (size_t)t0 * 96 + DT_RANK;
#pragma unroll 4
  for (int t = 0; t < LC; ++t) {
    float dl = b2f(dp[(size_t)t * 2048]);
    float ul = b2f(up[(size_t)t * 2048]);
    float Bf[16];
#pragma unroll
    for (int q = 0; q < 4; ++q)
      *reinterpret_cast<float4*>(&Bf[q * 4]) =
          *reinterpret_cast<const float4*>(xb + (size_t)t * 96 + q * 4);
    float dlu = dl * ul;
    sd += dl;
#pragma unroll
    for (int n = 0; n < 16; ++n)
      h[n] = __expf(dl * Ac[n]) * h[n] + dlu * Bf[n];
  }
  sdl[((size_t)b * NC + c) * 2048 + d] = sd;
  float* hs = HS + (((size_t)b * NC + c) * 2048 + d) * 16;
#pragma unroll
  for (int q = 0; q < 4; ++q)
    *reinterpret_cast<float4*>(hs + q * 4) =
        make_float4(h[q * 4], h[q * 4 + 1], h[q * 4 + 2], h[q * 4 + 3]);
}

// pass2: in-place combine over chunks, fully unrolled (all loads independent,
// only the 64-fma chain is serial)
__global__ __launch_bounds__(256)
void scan_pass2(const float* __restrict__ sdl, const float* __restrict__ A_log,
                float* __restrict__ HS)
{
  const int gid = blockIdx.x * 256 + threadIdx.x;  // 0..65535
  const int b = gid >> 15, rest = gid & 32767;     // rest = d*16+n
  const int d = rest >> 4;
  const float Ac = -__expf(A_log[rest]);
  float P[NC], S[NC];
#pragma unroll
  for (int c = 0; c < NC; ++c)
    P[c] = sdl[(((size_t)b * NC + c) << 11) + d];
#pragma unroll
  for (int c = 0; c < NC; ++c)
    S[c] = HS[(((size_t)b * NC + c) << 15) + rest];
#pragma unroll
  for (int c = 0; c < NC; ++c)
    P[c] = __expf(P[c] * Ac);
  float h = 0.f;
#pragma unroll
  for (int c = 0; c < NC; ++c) {
    HS[(((size_t)b * NC + c) << 15) + rest] = h;
    h = P[c] * h + S[c];
  }
}

// pass3: scan from HS, local n-reduce, z = y * silu_res (rb already silu'd bf16)
__global__ __launch_bounds__(256, 4)
void scan_pass3(const unsigned short* __restrict__ deltab, const unsigned short* __restrict__ ub,
                const float* __restrict__ xp, const float* __restrict__ A_log,
                const float* __restrict__ HS, const unsigned short* __restrict__ rb,
                short* __restrict__ zb)
{
  const int d = blockIdx.y * 256 + threadIdx.x;
  const int c = blockIdx.x, b = blockIdx.z;
  const int t0 = (b << 10) + c * LC;
  float Ac[16];
#pragma unroll
  for (int q = 0; q < 4; ++q) {
    float4 a = *reinterpret_cast<const float4*>(A_log + (size_t)d * 16 + q * 4);
    Ac[q * 4 + 0] = -__expf(a.x); Ac[q * 4 + 1] = -__expf(a.y);
    Ac[q * 4 + 2] = -__expf(a.z); Ac[q * 4 + 3] = -__expf(a.w);
  }
  float h[16];
  const float* hs = HS + (((size_t)b * NC + c) * 2048 + d) * 16;
#pragma unroll
  for (int q = 0; q < 4; ++q) {
    float4 v = *reinterpret_cast<const float4*>(hs + q * 4);
    h[q * 4 + 0] = v.x; h[q * 4 + 1] = v.y; h[q * 4 + 2] = v.z; h[q * 4 + 3] = v.w;
  }
  const unsigned short* dp = deltab + (size_t)t0 * 2048 + d;
  const unsigned short* up = ub + (size_t)t0 * 2048 + d;
  const float* xb = xp + (size_t)t0 * 96 + DT_RANK;
  const float* xc = xp + (size_t)t0 * 96 + DT_RANK + N_ST;
  const unsigned short* rp = rb + (size_t)t0 * 2048 + d;
  short* zp = zb + (size_t)t0 * 2048 + d;
#pragma unroll 4
  for (int t = 0; t < LC; ++t) {
    float dl = b2f(dp[(size_t)t * 2048]);
    float ul = b2f(up[(size_t)t * 2048]);
    float rv = b2f(rp[(size_t)t * 2048]);   // silu(res) already applied
    float Bf[16], Cf[16];
#pragma unroll
    for (int q = 0; q < 4; ++q) {
      *reinterpret_cast<float4*>(&Bf[q * 4]) =
          *reinterpret_cast<const float4*>(xb + (size_t)t * 96 + q * 4);
      *reinterpret_cast<float4*>(&Cf[q * 4]) =
          *reinterpret_cast<const float4*>(xc + (size_t)t * 96 + q * 4);
    }
    float dlu = dl * ul;
    float p0 = 0.f, p1 = 0.f, p2 = 0.f, p3 = 0.f;
#pragma unroll
    for (int n = 0; n < 16; ++n) {
      h[n] = __expf(dl * Ac[n]) * h[n] + dlu * Bf[n];
      float t2 = h[n] * Cf[n];
      if ((n & 3) == 0) p0 += t2;
      else if ((n & 3) == 1) p1 += t2;
      else if ((n & 3) == 2) p2 += t2;
      else p3 += t2;
    }
    float p = (p0 + p1) + (p2 + p3);
    zp[(size_t)t * 2048] = f2b(p * rv);
  }
}

extern "C" void kernel_launch(void* const* d_in, const int* in_sizes, int n_in,
                              void* d_out, int out_size, void* d_ws, size_t ws_size,
                              hipStream_t stream)
{
  const float* x      = (const float*)d_in[0];
  const float* A_log  = (const float*)d_in[1];
  const float* W_in   = (const float*)d_in[2];
  const float* b_in   = (const float*)d_in[3];
  const float* conv_w = (const float*)d_in[4];
  const float* conv_b = (const float*)d_in[5];
  const float* W_x    = (const float*)d_in[6];
  const float* W_dt   = (const float*)d_in[7];
  const float* b_dt   = (const float*)d_in[8];
  const float* W_out  = (const float*)d_in[9];
  const float* b_out  = (const float*)d_in[10];
  float* out = (float*)d_out;

  // workspace layout (~107 MB)
  char* p = (char*)d_ws;
  short* upb    = (short*)p; p += (size_t)NTOK * 2048 * 2;          // 8MB u_pre bf16
  short* rb     = (short*)p; p += (size_t)NTOK * 2048 * 2;          // 8MB silu(res) bf16
  short* ub     = (short*)p; p += (size_t)NTOK * 2048 * 2;          // 8MB
  float* xp     = (float*)p; p += (size_t)NTOK * 96 * 4;            // .75MB dt|B|C fp32
  short* dtb    = (short*)p; p += (size_t)NTOK * 64 * 2;            // .25MB
  short* deltab = (short*)p; p += (size_t)NTOK * 2048 * 2;          // 8MB bf16
  short* zb     = (short*)p; p += (size_t)NTOK * 2048 * 2;          // 8MB
  short* xb     = (short*)p; p += (size_t)NTOK * 1024 * 2;          // 4MB
  short* Wib    = (short*)p; p += (size_t)4096 * 1024 * 2;          // 8MB
  short* Wxb    = (short*)p; p += (size_t)128 * 2048 * 2;           // .5MB (96 rows + pad)
  short* Wdtb   = (short*)p; p += (size_t)2048 * 64 * 2;            // .25MB
  short* Wob    = (short*)p; p += (size_t)1024 * 2048 * 2;          // 4MB
  float* scr    = (float*)p; p += (size_t)4 * 2048 * 1024 * 4;      // 32MB shared scratch
  float* xppart = scr;   // 16 x 2048 x 96 fp32 = 12MB (lifetime: GEMM2..combine16)
  float* opart  = scr;   // 4 x 2048 x 1024 fp32 = 32MB (lifetime: GEMM4..combine4)
  float* sdl    = (float*)p; p += (size_t)BSZ * NC * 2048 * 4;      // 1MB
  float* HS     = (float*)p; p += (size_t)BSZ * NC * 2048 * 16 * 4; // 16MB

  // all pre-casts/transposes in one dispatch
  prep_kernel<<<dim3(PB_CAST + PB_WIN + PB_WX + PB_WDT + PB_WOUT), 256, 0, stream>>>(
      x, W_in, W_x, W_dt, W_out, xb, Wib, Wxb, Wdtb, Wob);

  // upb(u_pre bf16) | rb(silu(res) bf16) = x @ W_in + b_in
  gemm_kernel<0, 0, 1, 0><<<dim3(32, 16, 1), 256, 0, stream>>>(
      xb, Wib, b_in, nullptr, upb, rb, NTOK, 4096, 1024, 1024, 1024, 0, 1024);
  // u = silu(conv(u_pre) + conv_b), bf16
  conv_silu_kernel<<<dim3(4096), 256, 0, stream>>>(
      (const unsigned short*)upb, conv_w, conv_b, ub);
  // xp partials = u @ W_x (split-K 16, no atomics)
  gemm_kernel<0, 1, 0, 0><<<dim3(1, 16, 16), 256, 0, stream>>>(
      ub, Wxb, nullptr, xppart, nullptr, nullptr, NTOK, 96, 2048, 2048, 2048, 96, 128);
  // xp = sum(partials); dtb = bf16(dt cols)
  combine16_kernel<<<dim3(192), 256, 0, stream>>>(xppart, xp, dtb);
  // deltab = bf16(softplus(dt @ W_dt + b_dt))
  gemm_kernel<1, 0, 0, 1><<<dim3(16, 16, 1), 256, 0, stream>>>(
      dtb, Wdtb, b_dt, nullptr, deltab, nullptr, NTOK, 2048, 64, 64, 64, 2048, 64);
  // chunked selective scan -> zb (bf16, zmul fused)
  scan_pass1<<<dim3(NC, 8, BSZ), 256, 0, stream>>>(
      (const unsigned short*)deltab, (const unsigned short*)ub, xp, A_log, sdl, HS);
  scan_pass2<<<dim3(256), 256, 0, stream>>>(sdl, A_log, HS);
  scan_pass3<<<dim3(NC, 8, BSZ), 256, 0, stream>>>(
      (const unsigned short*)deltab, (const unsigned short*)ub, xp, A_log, HS,
      (const unsigned short*)rb, zb);
  // opart = z @ W_out partials (split-K 4, no atomics)
  gemm_kernel<0, 1, 0, 0><<<dim3(8, 16, 4), 256, 0, stream>>>(
      zb, Wob, nullptr, opart, nullptr, nullptr, NTOK, 1024, 2048, 2048, 2048, 1024, 512);
  // out = sum(partials) + b_out
  combine4_kernel<<<dim3(2048), 256, 0, stream>>>(opart, b_out, out);
}

// Round 10
// 146.838 us; speedup vs baseline: 3.5357x; 1.0307x over previous
//
#include <hip/hip_runtime.h>

#define D_MODEL 1024
#define D_INNER 2048
#define N_ST    16
#define DT_RANK 64
#define BSZ     2
#define SEQL    1024
#define NTOK    (BSZ*SEQL)   // 2048
#define NC      32           // scan chunks
#define LC      (SEQL/NC)    // 32 steps per chunk

typedef __attribute__((ext_vector_type(4))) float f32x4;
typedef __attribute__((ext_vector_type(8))) short bf16x8;

__device__ __forceinline__ short f2b(float f) {
  unsigned u = __builtin_bit_cast(unsigned, f);
  u += 0x7fffu + ((u >> 16) & 1u);           // round-to-nearest-even
  return (short)(u >> 16);
}

__device__ __forceinline__ float b2f(unsigned short s) {
  return __builtin_bit_cast(float, (unsigned)s << 16);
}

__device__ __forceinline__ void gload16(const void* g, void* l) {
  __builtin_amdgcn_global_load_lds(
      (const __attribute__((address_space(1))) void*)g,
      (__attribute__((address_space(3))) void*)l, 16, 0, 0);
}

// C[M,N] = epi(A[M,K] @ B[N,K]^T + bias); A,B bf16 (B pre-transposed [N][K]).
// 128x128 tile, BK=64, XOR-swizzled LDS, dbuf + counted vmcnt(8).
// PARTIAL: 1 = fp32 partials at z*M*ldc; 2 = bf16 partials.
// RESSPLIT (GEMM1): XCD-chunked y-major block remap; cols<2048 -> u_pre:
//   boundary rows to upb, fused conv+silu rows 2..127 to ub (via LDS tile);
//   cols>=2048 -> silu bf16 to resb.
// OUTB16: store epi result bf16 to upb at ldc stride.
template<int SOFTPLUS, int PARTIAL, int RESSPLIT, int OUTB16>
__global__ __launch_bounds__(256)
void gemm_kernel(const short* __restrict__ A, const short* __restrict__ Bm,
                 const float* __restrict__ bias, float* __restrict__ C,
                 short* __restrict__ upb, short* __restrict__ resb,
                 const float* __restrict__ cw, const float* __restrict__ cb,
                 short* __restrict__ ubuf,
                 int M, int N, int K, int lda, int ldb, int ldc, int kChunk)
{
  __shared__ short sA[2][128 * 64];   // 2 x 16 KB
  __shared__ short sB[2][128 * 64];
  const int tid  = threadIdx.x;
  const int lane = tid & 63;
  const int wave = tid >> 6;
  const int wr = wave >> 1, wc = wave & 1;
  const int lr = lane & 15, lg = lane >> 4;

  int bx = blockIdx.x, by = blockIdx.y;
  if (RESSPLIT) {   // grid (32,16): XCD-chunked, y-major within XCD
    const int lin = by * 32 + bx;
    const int lb = (lin & 7) * 64 + (lin >> 3);
    bx = lb >> 4; by = lb & 15;
  }
  const int m0 = by * 128;
  const int n0 = bx * 128;
  const int kStart = blockIdx.z * kChunk;
  int kEnd = kStart + kChunk; if (kEnd > K) kEnd = K;
  const int nt = (kEnd - kStart) >> 6;

  // staging: wave covers 32 rows; one gload16 covers 8 rows x 64 k (1 KB).
  const int srow = lane >> 3;                 // 0..7 row within 8-row group
  const int scol = ((lane & 7) ^ srow) * 8;   // swizzled source col (bf16)
  const short* aS = A + (size_t)(m0 + wave * 32 + srow) * lda + scol + kStart;
  const short* bS = Bm + (size_t)(n0 + wave * 32 + srow) * ldb + scol + kStart;
  const int ldsOff = wave * 2048;             // wave's 32x64 region

#define STAGE(buf, koff)                                                   \
  {                                                                        \
    _Pragma("unroll")                                                      \
    for (int i_ = 0; i_ < 4; ++i_) {                                       \
      gload16(aS + (size_t)(i_ * 8) * lda + (koff), &sA[buf][ldsOff + i_ * 512]); \
      gload16(bS + (size_t)(i_ * 8) * ldb + (koff), &sB[buf][ldsOff + i_ * 512]); \
    }                                                                      \
  }

  f32x4 acc[4][4];
#pragma unroll
  for (int i = 0; i < 4; ++i)
#pragma unroll
    for (int j = 0; j < 4; ++j) acc[i][j] = (f32x4){0.f, 0.f, 0.f, 0.f};

  STAGE(0, 0);

  for (int t = 0; t < nt; ++t) {
    const int cur = t & 1;
    if (t + 1 < nt) {
      STAGE(cur ^ 1, (t + 1) * 64);
      asm volatile("s_waitcnt vmcnt(8)" ::: "memory");  // tile-t staged; t+1 in flight
    } else {
      asm volatile("s_waitcnt vmcnt(0)" ::: "memory");
    }
    __builtin_amdgcn_s_barrier();

#pragma unroll
    for (int kk = 0; kk < 2; ++kk) {
      bf16x8 aF[4], bF[4];
#pragma unroll
      for (int mi = 0; mi < 4; ++mi) {
        const int row = wr * 64 + mi * 16 + lr;
        aF[mi] = *reinterpret_cast<const bf16x8*>(
            &sA[cur][row * 64 + (((kk * 4 + lg) ^ (lr & 7)) * 8)]);
      }
#pragma unroll
      for (int ni = 0; ni < 4; ++ni) {
        const int row = wc * 64 + ni * 16 + lr;
        bF[ni] = *reinterpret_cast<const bf16x8*>(
            &sB[cur][row * 64 + (((kk * 4 + lg) ^ (lr & 7)) * 8)]);
      }
#pragma unroll
      for (int mi = 0; mi < 4; ++mi)
#pragma unroll
        for (int ni = 0; ni < 4; ++ni)
          acc[mi][ni] = __builtin_amdgcn_mfma_f32_16x16x32_bf16(
              aF[mi], bF[ni], acc[mi][ni], 0, 0, 0);
    }
    __builtin_amdgcn_s_barrier();
  }
#undef STAGE

  // epilogue: C/D layout col=lane&15, row=(lane>>4)*4+reg
  if (RESSPLIT) {
    if (n0 < 2048) {
      // u_pre tile -> LDS (reuse sA: 128x128 bf16 = 32KB); boundary rows -> upb
      short (*sU)[128] = reinterpret_cast<short (*)[128]>(&sA[0][0]);
#pragma unroll
      for (int mi = 0; mi < 4; ++mi) {
#pragma unroll
        for (int ni = 0; ni < 4; ++ni) {
          const int cl = wc * 64 + ni * 16 + lr;
          const float bv = bias[n0 + cl];
#pragma unroll
          for (int j = 0; j < 4; ++j) {
            const int rl = wr * 64 + mi * 16 + lg * 4 + j;
            const short s = f2b(acc[mi][ni][j] + bv);
            sU[rl][cl] = s;
            if (rl < 2 || rl >= 126)
              upb[(size_t)(m0 + rl) * 2048 + (n0 + cl)] = s;
          }
        }
      }
      __syncthreads();
      // fused causal conv(K=3) + bias + silu for rows 2..127
#pragma unroll
      for (int ni = 0; ni < 4; ++ni) {
        const int cl = wc * 64 + ni * 16 + lr;
        const int col = n0 + cl;
        const float w0 = cw[col * 3], w1 = cw[col * 3 + 1], w2 = cw[col * 3 + 2];
        const float cbv = cb[col];
#pragma unroll
        for (int mi = 0; mi < 4; ++mi) {
#pragma unroll
          for (int j = 0; j < 4; ++j) {
            const int rl = wr * 64 + mi * 16 + lg * 4 + j;
            if (rl >= 2) {
              float r = cbv + w0 * b2f((unsigned short)sU[rl - 2][cl])
                            + w1 * b2f((unsigned short)sU[rl - 1][cl])
                            + w2 * b2f((unsigned short)sU[rl][cl]);
              ubuf[(size_t)(m0 + rl) * 2048 + col] = f2b(r / (1.f + __expf(-r)));
            }
          }
        }
      }
    } else {
#pragma unroll
      for (int mi = 0; mi < 4; ++mi) {
        const int row = m0 + wr * 64 + mi * 16 + lg * 4;
#pragma unroll
        for (int ni = 0; ni < 4; ++ni) {
          const int col = n0 + wc * 64 + ni * 16 + lr;
          const float bv = bias[col];
#pragma unroll
          for (int j = 0; j < 4; ++j) {
            float v = acc[mi][ni][j] + bv;
            resb[(size_t)(row + j) * 2048 + (col - 2048)] =
                f2b(v / (1.f + __expf(-v)));
          }
        }
      }
    }
    return;
  }

#pragma unroll
  for (int mi = 0; mi < 4; ++mi) {
    const int row = m0 + wr * 64 + mi * 16 + lg * 4;
#pragma unroll
    for (int ni = 0; ni < 4; ++ni) {
      const int col = n0 + wc * 64 + ni * 16 + lr;
      if (OUTB16) {
        const float bv = bias[col];
#pragma unroll
        for (int j = 0; j < 4; ++j) {
          float v = acc[mi][ni][j] + bv;
          if (SOFTPLUS) v = fmaxf(v, 0.f) + log1pf(__expf(-fabsf(v)));
          upb[(size_t)(row + j) * ldc + col] = f2b(v);
        }
      } else if (PARTIAL == 2) {
        short* Cs = (short*)C + (size_t)blockIdx.z * M * ldc;
#pragma unroll
        for (int j = 0; j < 4; ++j)
          Cs[(size_t)(row + j) * ldc + col] = f2b(acc[mi][ni][j]);
      } else if (col < N) {
        float* Cp = PARTIAL ? C + (size_t)blockIdx.z * M * ldc : C;
        float bv = (bias != nullptr && blockIdx.z == 0) ? bias[col] : 0.f;
#pragma unroll
        for (int j = 0; j < 4; ++j) {
          float v = acc[mi][ni][j] + bv;
          if (SOFTPLUS) v = fmaxf(v, 0.f) + log1pf(__expf(-fabsf(v)));
          Cp[(size_t)(row + j) * ldc + col] = v;
        }
      }
    }
  }
}

// ---- fused prep: castA(x) + transpose-cast of all 4 weights, one dispatch ----
__device__ __forceinline__ void trans_body(const float* __restrict__ in,
                                           short* __restrict__ out,
                                           int R, int C, int bx, int by,
                                           short (*t)[33], int tidx)
{
  const int c0 = bx * 32, r0 = by * 32;
  const int cc = tidx & 31, rr = tidx >> 5;  // rr 0..7
#pragma unroll
  for (int i = 0; i < 4; ++i)
    t[rr + i * 8][cc] = f2b(in[(size_t)(r0 + rr + i * 8) * C + c0 + cc]);
  __syncthreads();
#pragma unroll
  for (int i = 0; i < 4; ++i)
    out[(size_t)(c0 + rr + i * 8) * R + r0 + cc] = t[cc][rr + i * 8];
}

#define PB_CAST  2048
#define PB_WIN   4096
#define PB_WX    192
#define PB_WDT   128
#define PB_WOUT  2048

__global__ __launch_bounds__(256)
void prep_kernel(const float* __restrict__ x,    const float* __restrict__ W_in,
                 const float* __restrict__ W_x,  const float* __restrict__ W_dt,
                 const float* __restrict__ W_out,
                 short* __restrict__ xb,  short* __restrict__ Wib,
                 short* __restrict__ Wxb, short* __restrict__ Wdtb,
                 short* __restrict__ Wob)
{
  __shared__ short t[32][33];
  const int bid = blockIdx.x, tidx = threadIdx.x;
  if (bid < PB_CAST) {
    const int i = bid * 256 + tidx;
    float4 v = *reinterpret_cast<const float4*>(x + (size_t)i * 4);
    *reinterpret_cast<short4*>(xb + (size_t)i * 4) =
        make_short4(f2b(v.x), f2b(v.y), f2b(v.z), f2b(v.w));
  } else if (bid < PB_CAST + PB_WIN) {
    const int b = bid - PB_CAST;
    trans_body(W_in, Wib, 1024, 4096, b % 128, b / 128, t, tidx);
  } else if (bid < PB_CAST + PB_WIN + PB_WX) {
    const int b = bid - PB_CAST - PB_WIN;
    trans_body(W_x, Wxb, 2048, 96, b % 3, b / 3, t, tidx);
  } else if (bid < PB_CAST + PB_WIN + PB_WX + PB_WDT) {
    const int b = bid - PB_CAST - PB_WIN - PB_WX;
    trans_body(W_dt, Wdtb, 64, 2048, b % 64, b / 64, t, tidx);
  } else {
    const int b = bid - PB_CAST - PB_WIN - PB_WX - PB_WDT;
    trans_body(W_out, Wob, 2048, 1024, b % 32, b / 32, t, tidx);
  }
}

// conv fixup for boundary rows (t % 128 < 2): full conv with l-masking
__global__ __launch_bounds__(256)
void conv_fixup_kernel(const unsigned short* __restrict__ upb,
                       const float* __restrict__ cw, const float* __restrict__ cb,
                       short* __restrict__ ub)
{
  const int i  = blockIdx.x * 256 + threadIdx.x;   // 64 tokens * 512
  const int ti = i >> 9;
  const int dq = (i & 511) << 2;
  const int t  = (ti >> 1) * 128 + (ti & 1);
  const int l  = t & (SEQL - 1);
  float4 w0 = *reinterpret_cast<const float4*>(cw + dq * 3);
  float4 w1 = *reinterpret_cast<const float4*>(cw + dq * 3 + 4);
  float4 w2 = *reinterpret_cast<const float4*>(cw + dq * 3 + 8);
  float4 bb = *reinterpret_cast<const float4*>(cb + dq);
  ushort4 X2 = *reinterpret_cast<const ushort4*>(upb + (size_t)t * 2048 + dq);
  ushort4 z4; z4.x = z4.y = z4.z = z4.w = 0;
  ushort4 X1 = (l >= 1) ? *reinterpret_cast<const ushort4*>(upb + (size_t)(t - 1) * 2048 + dq) : z4;
  ushort4 X0 = (l >= 2) ? *reinterpret_cast<const ushort4*>(upb + (size_t)(t - 2) * 2048 + dq) : z4;
  float r0 = bb.x + w0.x * b2f(X0.x) + w0.y * b2f(X1.x) + w0.z * b2f(X2.x);
  float r1 = bb.y + w0.w * b2f(X0.y) + w1.x * b2f(X1.y) + w1.y * b2f(X2.y);
  float r2 = bb.z + w1.z * b2f(X0.z) + w1.w * b2f(X1.z) + w2.x * b2f(X2.z);
  float r3 = bb.w + w2.y * b2f(X0.w) + w2.z * b2f(X1.w) + w2.w * b2f(X2.w);
  *reinterpret_cast<short4*>(ub + (size_t)t * 2048 + dq) = make_short4(
      f2b(r0 / (1.f + __expf(-r0))), f2b(r1 / (1.f + __expf(-r1))),
      f2b(r2 / (1.f + __expf(-r2))), f2b(r3 / (1.f + __expf(-r3))));
}

// combine 16 split-K partials of GEMM2 -> xp fp32 [2048][96]; dt cols -> dtb bf16
__global__ __launch_bounds__(256)
void combine16_kernel(const float* __restrict__ part, float* __restrict__ xp,
                      short* __restrict__ dtb)
{
  const int gid = blockIdx.x * 256 + threadIdx.x;   // 0 .. 2048*24-1
  const int r = gid / 24, q = gid - r * 24;
  float4 s = make_float4(0.f, 0.f, 0.f, 0.f);
#pragma unroll
  for (int c = 0; c < 16; ++c) {
    const float4 v = *reinterpret_cast<const float4*>(
        part + (size_t)c * 2048 * 96 + (size_t)r * 96 + q * 4);
    s.x += v.x; s.y += v.y; s.z += v.z; s.w += v.w;
  }
  *reinterpret_cast<float4*>(xp + (size_t)r * 96 + q * 4) = s;
  if (q < 16)
    *reinterpret_cast<short4*>(dtb + (size_t)r * 64 + q * 4) =
        make_short4(f2b(s.x), f2b(s.y), f2b(s.z), f2b(s.w));
}

// combine 4 bf16 split-K partials of GEMM4 + bias -> out fp32 [2048][1024]
__global__ __launch_bounds__(256)
void combine4_kernel(const unsigned short* __restrict__ part,
                     const float* __restrict__ bias, float* __restrict__ out)
{
  const int gid = blockIdx.x * 256 + threadIdx.x;   // over 2048*256 float4s
  const int r = gid >> 8, c4 = gid & 255;
  const float4 bv = *reinterpret_cast<const float4*>(bias + c4 * 4);
  float4 s = bv;
#pragma unroll
  for (int z = 0; z < 4; ++z) {
    const ushort4 v = *reinterpret_cast<const ushort4*>(
        part + (size_t)z * 2048 * 1024 + (size_t)r * 1024 + c4 * 4);
    s.x += b2f(v.x); s.y += b2f(v.y); s.z += b2f(v.z); s.w += b2f(v.w);
  }
  *reinterpret_cast<float4*>(out + (size_t)r * 1024 + c4 * 4) = s;
}

// ---- chunked selective scan: thread owns (b, chunk, d) with all 16 n ----
__global__ __launch_bounds__(256, 4)
void scan_pass1(const unsigned short* __restrict__ deltab, const unsigned short* __restrict__ ub,
                const float* __restrict__ xp, const float* __restrict__ A_log,
                float* __restrict__ sdl, float* __restrict__ HS)
{
  const int d = blockIdx.y * 256 + threadIdx.x;
  const int c = blockIdx.x, b = blockIdx.z;
  const int t0 = (b << 10) + c * LC;
  float Ac[16];
#pragma unroll
  for (int q = 0; q < 4; ++q) {
    float4 a = *reinterpret_cast<const float4*>(A_log + (size_t)d * 16 + q * 4);
    Ac[q * 4 + 0] = -__expf(a.x); Ac[q * 4 + 1] = -__expf(a.y);
    Ac[q * 4 + 2] = -__expf(a.z); Ac[q * 4 + 3] = -__expf(a.w);
  }
  float h[16];
#pragma unroll
  for (int n = 0; n < 16; ++n) h[n] = 0.f;
  float sd = 0.f;
  const unsigned short* dp = deltab + (size_t)t0 * 2048 + d;
  const unsigned short* up = ub + (size_t)t0 * 2048 + d;
  const float* xb = xp + (size_t)t0 * 96 + DT_RANK;
#pragma unroll 4
  for (int t = 0; t < LC; ++t) {
    float dl = b2f(dp[(size_t)t * 2048]);
    float ul = b2f(up[(size_t)t * 2048]);
    float Bf[16];
#pragma unroll
    for (int q = 0; q < 4; ++q)
      *reinterpret_cast<float4*>(&Bf[q * 4]) =
          *reinterpret_cast<const float4*>(xb + (size_t)t * 96 + q * 4);
    float dlu = dl * ul;
    sd += dl;
#pragma unroll
    for (int n = 0; n < 16; ++n)
      h[n] = __expf(dl * Ac[n]) * h[n] + dlu * Bf[n];
  }
  sdl[((size_t)b * NC + c) * 2048 + d] = sd;
  float* hs = HS + (((size_t)b * NC + c) * 2048 + d) * 16;
#pragma unroll
  for (int q = 0; q < 4; ++q)
    *reinterpret_cast<float4*>(hs + q * 4) =
        make_float4(h[q * 4], h[q * 4 + 1], h[q * 4 + 2], h[q * 4 + 3]);
}

// pass2: in-place combine over chunks, fully unrolled
__global__ __launch_bounds__(256)
void scan_pass2(const float* __restrict__ sdl, const float* __restrict__ A_log,
                float* __restrict__ HS)
{
  const int gid = blockIdx.x * 256 + threadIdx.x;  // 0..65535
  const int b = gid >> 15, rest = gid & 32767;     // rest = d*16+n
  const int d = rest >> 4;
  const float Ac = -__expf(A_log[rest]);
  float P[NC], S[NC];
#pragma unroll
  for (int c = 0; c < NC; ++c)
    P[c] = sdl[(((size_t)b * NC + c) << 11) + d];
#pragma unroll
  for (int c = 0; c < NC; ++c)
    S[c] = HS[(((size_t)b * NC + c) << 15) + rest];
#pragma unroll
  for (int c = 0; c < NC; ++c)
    P[c] = __expf(P[c] * Ac);
  float h = 0.f;
#pragma unroll
  for (int c = 0; c < NC; ++c) {
    HS[(((size_t)b * NC + c) << 15) + rest] = h;
    h = P[c] * h + S[c];
  }
}

// pass3: scan from HS, local n-reduce, z = y * silu_res (rb already silu'd bf16)
__global__ __launch_bounds__(256, 4)
void scan_pass3(const unsigned short* __restrict__ deltab, const unsigned short* __restrict__ ub,
                const float* __restrict__ xp, const float* __restrict__ A_log,
                const float* __restrict__ HS, const unsigned short* __restrict__ rb,
                short* __restrict__ zb)
{
  const int d = blockIdx.y * 256 + threadIdx.x;
  const int c = blockIdx.x, b = blockIdx.z;
  const int t0 = (b << 10) + c * LC;
  float Ac[16];
#pragma unroll
  for (int q = 0; q < 4; ++q) {
    float4 a = *reinterpret_cast<const float4*>(A_log + (size_t)d * 16 + q * 4);
    Ac[q * 4 + 0] = -__expf(a.x); Ac[q * 4 + 1] = -__expf(a.y);
    Ac[q * 4 + 2] = -__expf(a.z); Ac[q * 4 + 3] = -__expf(a.w);
  }
  float h[16];
  const float* hs = HS + (((size_t)b * NC + c) * 2048 + d) * 16;
#pragma unroll
  for (int q = 0; q < 4; ++q) {
    float4 v = *reinterpret_cast<const float4*>(hs + q * 4);
    h[q * 4 + 0] = v.x; h[q * 4 + 1] = v.y; h[q * 4 + 2] = v.z; h[q * 4 + 3] = v.w;
  }
  const unsigned short* dp = deltab + (size_t)t0 * 2048 + d;
  const unsigned short* up = ub + (size_t)t0 * 2048 + d;
  const float* xb = xp + (size_t)t0 * 96 + DT_RANK;
  const float* xc = xp + (size_t)t0 * 96 + DT_RANK + N_ST;
  const unsigned short* rp = rb + (size_t)t0 * 2048 + d;
  short* zp = zb + (size_t)t0 * 2048 + d;
#pragma unroll 4
  for (int t = 0; t < LC; ++t) {
    float dl = b2f(dp[(size_t)t * 2048]);
    float ul = b2f(up[(size_t)t * 2048]);
    float rv = b2f(rp[(size_t)t * 2048]);   // silu(res) already applied
    float Bf[16], Cf[16];
#pragma unroll
    for (int q = 0; q < 4; ++q) {
      *reinterpret_cast<float4*>(&Bf[q * 4]) =
          *reinterpret_cast<const float4*>(xb + (size_t)t * 96 + q * 4);
      *reinterpret_cast<float4*>(&Cf[q * 4]) =
          *reinterpret_cast<const float4*>(xc + (size_t)t * 96 + q * 4);
    }
    float dlu = dl * ul;
    float p0 = 0.f, p1 = 0.f, p2 = 0.f, p3 = 0.f;
#pragma unroll
    for (int n = 0; n < 16; ++n) {
      h[n] = __expf(dl * Ac[n]) * h[n] + dlu * Bf[n];
      float t2 = h[n] * Cf[n];
      if ((n & 3) == 0) p0 += t2;
      else if ((n & 3) == 1) p1 += t2;
      else if ((n & 3) == 2) p2 += t2;
      else p3 += t2;
    }
    float p = (p0 + p1) + (p2 + p3);
    zp[(size_t)t * 2048] = f2b(p * rv);
  }
}

extern "C" void kernel_launch(void* const* d_in, const int* in_sizes, int n_in,
                              void* d_out, int out_size, void* d_ws, size_t ws_size,
                              hipStream_t stream)
{
  const float* x      = (const float*)d_in[0];
  const float* A_log  = (const float*)d_in[1];
  const float* W_in   = (const float*)d_in[2];
  const float* b_in   = (const float*)d_in[3];
  const float* conv_w = (const float*)d_in[4];
  const float* conv_b = (const float*)d_in[5];
  const float* W_x    = (const float*)d_in[6];
  const float* W_dt   = (const float*)d_in[7];
  const float* b_dt   = (const float*)d_in[8];
  const float* W_out  = (const float*)d_in[9];
  const float* b_out  = (const float*)d_in[10];
  float* out = (float*)d_out;

  // workspace layout (~90 MB)
  char* p = (char*)d_ws;
  short* upb    = (short*)p; p += (size_t)NTOK * 2048 * 2;          // 8MB u_pre bf16 (boundary rows)
  short* rb     = (short*)p; p += (size_t)NTOK * 2048 * 2;          // 8MB silu(res) bf16
  short* ub     = (short*)p; p += (size_t)NTOK * 2048 * 2;          // 8MB
  float* xp     = (float*)p; p += (size_t)NTOK * 96 * 4;            // .75MB dt|B|C fp32
  short* dtb    = (short*)p; p += (size_t)NTOK * 64 * 2;            // .25MB
  short* deltab = (short*)p; p += (size_t)NTOK * 2048 * 2;          // 8MB bf16
  short* zb     = (short*)p; p += (size_t)NTOK * 2048 * 2;          // 8MB
  short* xb     = (short*)p; p += (size_t)NTOK * 1024 * 2;          // 4MB
  short* Wib    = (short*)p; p += (size_t)4096 * 1024 * 2;          // 8MB
  short* Wxb    = (short*)p; p += (size_t)128 * 2048 * 2;           // .5MB (96 rows + pad)
  short* Wdtb   = (short*)p; p += (size_t)2048 * 64 * 2;            // .25MB
  short* Wob    = (short*)p; p += (size_t)1024 * 2048 * 2;          // 4MB
  char*  scr    = p;         p += (size_t)16 * 1024 * 1024;         // 16MB shared scratch
  float* xppart = (float*)scr;  // 16 x 2048 x 96 fp32 = 12.6MB (GEMM2..combine16)
  short* opart  = (short*)scr;  // 4 x 2048 x 1024 bf16 = 16MB (GEMM4..combine4)
  float* sdl    = (float*)p; p += (size_t)BSZ * NC * 2048 * 4;      // .5MB
  float* HS     = (float*)p; p += (size_t)BSZ * NC * 2048 * 16 * 4; // 8MB

  // all pre-casts/transposes in one dispatch
  prep_kernel<<<dim3(PB_CAST + PB_WIN + PB_WX + PB_WDT + PB_WOUT), 256, 0, stream>>>(
      x, W_in, W_x, W_dt, W_out, xb, Wib, Wxb, Wdtb, Wob);

  // GEMM1: upb(boundary u_pre) | ub(conv+silu rows 2..127) | rb(silu(res))
  gemm_kernel<0, 0, 1, 0><<<dim3(32, 16, 1), 256, 0, stream>>>(
      xb, Wib, b_in, nullptr, upb, rb, conv_w, conv_b, ub,
      NTOK, 4096, 1024, 1024, 1024, 0, 1024);
  // finish conv for boundary rows (t % 128 < 2)
  conv_fixup_kernel<<<dim3(128), 256, 0, stream>>>(
      (const unsigned short*)upb, conv_w, conv_b, ub);
  // xp partials = u @ W_x (split-K 16, no atomics)
  gemm_kernel<0, 1, 0, 0><<<dim3(1, 16, 16), 256, 0, stream>>>(
      ub, Wxb, nullptr, xppart, nullptr, nullptr, nullptr, nullptr, nullptr,
      NTOK, 96, 2048, 2048, 2048, 96, 128);
  // xp = sum(partials); dtb = bf16(dt cols)
  combine16_kernel<<<dim3(192), 256, 0, stream>>>(xppart, xp, dtb);
  // deltab = bf16(softplus(dt @ W_dt + b_dt))
  gemm_kernel<1, 0, 0, 1><<<dim3(16, 16, 1), 256, 0, stream>>>(
      dtb, Wdtb, b_dt, nullptr, deltab, nullptr, nullptr, nullptr, nullptr,
      NTOK, 2048, 64, 64, 64, 2048, 64);
  // chunked selective scan -> zb (bf16, zmul fused)
  scan_pass1<<<dim3(NC, 8, BSZ), 256, 0, stream>>>(
      (const unsigned short*)deltab, (const unsigned short*)ub, xp, A_log, sdl, HS);
  scan_pass2<<<dim3(256), 256, 0, stream>>>(sdl, A_log, HS);
  scan_pass3<<<dim3(NC, 8, BSZ), 256, 0, stream>>>(
      (const unsigned short*)deltab, (const unsigned short*)ub, xp, A_log, HS,
      (const unsigned short*)rb, zb);
  // opart(bf16) = z @ W_out partials (split-K 4, no atomics)
  gemm_kernel<0, 2, 0, 0><<<dim3(8, 16, 4), 256, 0, stream>>>(
      zb, Wob, nullptr, (float*)opart, nullptr, nullptr, nullptr, nullptr, nullptr,
      NTOK, 1024, 2048, 2048, 2048, 1024, 512);
  // out = sum(partials) + b_out
  combine4_kernel<<<dim3(2048), 256, 0, stream>>>(
      (const unsigned short*)opart, b_out, out);
}

// Round 11
// 143.634 us; speedup vs baseline: 3.6145x; 1.0223x over previous
//
#include <hip/hip_runtime.h>

#define D_MODEL 1024
#define D_INNER 2048
#define N_ST    16
#define DT_RANK 64
#define BSZ     2
#define SEQL    1024
#define NTOK    (BSZ*SEQL)   // 2048
#define NC      32           // scan chunks
#define LC      (SEQL/NC)    // 32 steps per chunk

typedef __attribute__((ext_vector_type(4))) float f32x4;
typedef __attribute__((ext_vector_type(8))) short bf16x8;

__device__ __forceinline__ short f2b(float f) {
  unsigned u = __builtin_bit_cast(unsigned, f);
  u += 0x7fffu + ((u >> 16) & 1u);           // round-to-nearest-even
  return (short)(u >> 16);
}

__device__ __forceinline__ float b2f(unsigned short s) {
  return __builtin_bit_cast(float, (unsigned)s << 16);
}

__device__ __forceinline__ void gload16(const void* g, void* l) {
  __builtin_amdgcn_global_load_lds(
      (const __attribute__((address_space(1))) void*)g,
      (__attribute__((address_space(3))) void*)l, 16, 0, 0);
}

// C[M,N] = epi(A[M,K] @ B[N,K]^T + bias); A,B bf16 (B pre-transposed [N][K]).
// 128x128 tile, BK=64, XOR-swizzled LDS, dbuf + counted vmcnt(8).
// PARTIAL: 1 = fp32 partials at z*M*ldc; 2 = bf16 partials.
// RESSPLIT (GEMM1): XCD-chunked y-major block remap; cols<2048 -> u_pre:
//   boundary rows to upb, fused conv+silu rows 2..127 to ubuf (via LDS tile);
//   cols>=2048 -> silu bf16 to resb.
// OUTB16: store epi result bf16 to upb at ldc stride.
// FIXUP (GEMM2): prologue finishes conv+silu for this block's 2 boundary
//   tokens x its 128-d slice (A region), writing ubuf before staging.
template<int SOFTPLUS, int PARTIAL, int RESSPLIT, int OUTB16, int FIXUP>
__global__ __launch_bounds__(256)
void gemm_kernel(const short* __restrict__ A, const short* __restrict__ Bm,
                 const float* __restrict__ bias, float* __restrict__ C,
                 short* __restrict__ upb, short* __restrict__ resb,
                 const float* __restrict__ cw, const float* __restrict__ cb,
                 short* __restrict__ ubuf,
                 int M, int N, int K, int lda, int ldb, int ldc, int kChunk)
{
  __shared__ short sA[2][128 * 64];   // 2 x 16 KB
  __shared__ short sB[2][128 * 64];
  const int tid  = threadIdx.x;
  const int lane = tid & 63;
  const int wave = tid >> 6;
  const int wr = wave >> 1, wc = wave & 1;
  const int lr = lane & 15, lg = lane >> 4;

  int bx = blockIdx.x, by = blockIdx.y;
  if (RESSPLIT) {   // grid (32,16): XCD-chunked, y-major within XCD
    const int lin = by * 32 + bx;
    const int lb = (lin & 7) * 64 + (lin >> 3);
    bx = lb >> 4; by = lb & 15;
  }
  const int m0 = by * 128;
  const int n0 = bx * 128;
  const int kStart = blockIdx.z * kChunk;
  int kEnd = kStart + kChunk; if (kEnd > K) kEnd = K;
  const int nt = (kEnd - kStart) >> 6;

  if (FIXUP) {
    // finish conv+silu for boundary tokens {m0, m0+1} x d-slice [kStart,+128)
    const int tt = m0 + (tid >> 7);
    const int dd = kStart + (tid & 127);
    const int l  = tt & (SEQL - 1);
    float u2 = b2f((unsigned short)upb[(size_t)tt * 2048 + dd]);
    float u1 = (l >= 1) ? b2f((unsigned short)upb[(size_t)(tt - 1) * 2048 + dd]) : 0.f;
    float u0 = (l >= 2) ? b2f((unsigned short)upb[(size_t)(tt - 2) * 2048 + dd]) : 0.f;
    float r = cb[dd] + cw[dd * 3] * u0 + cw[dd * 3 + 1] * u1 + cw[dd * 3 + 2] * u2;
    ubuf[(size_t)tt * 2048 + dd] = f2b(r / (1.f + __expf(-r)));
    asm volatile("s_waitcnt vmcnt(0)" ::: "memory");  // stores retired to L2
    __syncthreads();                                  // before any gload16 reads them
  }

  // staging: wave covers 32 rows; one gload16 covers 8 rows x 64 k (1 KB).
  const int srow = lane >> 3;                 // 0..7 row within 8-row group
  const int scol = ((lane & 7) ^ srow) * 8;   // swizzled source col (bf16)
  const short* aS = A + (size_t)(m0 + wave * 32 + srow) * lda + scol + kStart;
  const short* bS = Bm + (size_t)(n0 + wave * 32 + srow) * ldb + scol + kStart;
  const int ldsOff = wave * 2048;             // wave's 32x64 region

#define STAGE(buf, koff)                                                   \
  {                                                                        \
    _Pragma("unroll")                                                      \
    for (int i_ = 0; i_ < 4; ++i_) {                                       \
      gload16(aS + (size_t)(i_ * 8) * lda + (koff), &sA[buf][ldsOff + i_ * 512]); \
      gload16(bS + (size_t)(i_ * 8) * ldb + (koff), &sB[buf][ldsOff + i_ * 512]); \
    }                                                                      \
  }

  f32x4 acc[4][4];
#pragma unroll
  for (int i = 0; i < 4; ++i)
#pragma unroll
    for (int j = 0; j < 4; ++j) acc[i][j] = (f32x4){0.f, 0.f, 0.f, 0.f};

  STAGE(0, 0);

  for (int t = 0; t < nt; ++t) {
    const int cur = t & 1;
    if (t + 1 < nt) {
      STAGE(cur ^ 1, (t + 1) * 64);
      asm volatile("s_waitcnt vmcnt(8)" ::: "memory");  // tile-t staged; t+1 in flight
    } else {
      asm volatile("s_waitcnt vmcnt(0)" ::: "memory");
    }
    __builtin_amdgcn_s_barrier();

#pragma unroll
    for (int kk = 0; kk < 2; ++kk) {
      bf16x8 aF[4], bF[4];
#pragma unroll
      for (int mi = 0; mi < 4; ++mi) {
        const int row = wr * 64 + mi * 16 + lr;
        aF[mi] = *reinterpret_cast<const bf16x8*>(
            &sA[cur][row * 64 + (((kk * 4 + lg) ^ (lr & 7)) * 8)]);
      }
#pragma unroll
      for (int ni = 0; ni < 4; ++ni) {
        const int row = wc * 64 + ni * 16 + lr;
        bF[ni] = *reinterpret_cast<const bf16x8*>(
            &sB[cur][row * 64 + (((kk * 4 + lg) ^ (lr & 7)) * 8)]);
      }
#pragma unroll
      for (int mi = 0; mi < 4; ++mi)
#pragma unroll
        for (int ni = 0; ni < 4; ++ni)
          acc[mi][ni] = __builtin_amdgcn_mfma_f32_16x16x32_bf16(
              aF[mi], bF[ni], acc[mi][ni], 0, 0, 0);
    }
    __builtin_amdgcn_s_barrier();
  }
#undef STAGE

  // epilogue: C/D layout col=lane&15, row=(lane>>4)*4+reg
  if (RESSPLIT) {
    if (n0 < 2048) {
      // u_pre tile -> LDS (reuse sA: 128x128 bf16 = 32KB); boundary rows -> upb
      short (*sU)[128] = reinterpret_cast<short (*)[128]>(&sA[0][0]);
#pragma unroll
      for (int mi = 0; mi < 4; ++mi) {
#pragma unroll
        for (int ni = 0; ni < 4; ++ni) {
          const int cl = wc * 64 + ni * 16 + lr;
          const float bv = bias[n0 + cl];
#pragma unroll
          for (int j = 0; j < 4; ++j) {
            const int rl = wr * 64 + mi * 16 + lg * 4 + j;
            const short s = f2b(acc[mi][ni][j] + bv);
            sU[rl][cl] = s;
            if (rl < 2 || rl >= 126)
              upb[(size_t)(m0 + rl) * 2048 + (n0 + cl)] = s;
          }
        }
      }
      __syncthreads();
      // fused causal conv(K=3) + bias + silu for rows 2..127
#pragma unroll
      for (int ni = 0; ni < 4; ++ni) {
        const int cl = wc * 64 + ni * 16 + lr;
        const int col = n0 + cl;
        const float w0 = cw[col * 3], w1 = cw[col * 3 + 1], w2 = cw[col * 3 + 2];
        const float cbv = cb[col];
#pragma unroll
        for (int mi = 0; mi < 4; ++mi) {
#pragma unroll
          for (int j = 0; j < 4; ++j) {
            const int rl = wr * 64 + mi * 16 + lg * 4 + j;
            if (rl >= 2) {
              float r = cbv + w0 * b2f((unsigned short)sU[rl - 2][cl])
                            + w1 * b2f((unsigned short)sU[rl - 1][cl])
                            + w2 * b2f((unsigned short)sU[rl][cl]);
              ubuf[(size_t)(m0 + rl) * 2048 + col] = f2b(r / (1.f + __expf(-r)));
            }
          }
        }
      }
    } else {
#pragma unroll
      for (int mi = 0; mi < 4; ++mi) {
        const int row = m0 + wr * 64 + mi * 16 + lg * 4;
#pragma unroll
        for (int ni = 0; ni < 4; ++ni) {
          const int col = n0 + wc * 64 + ni * 16 + lr;
          const float bv = bias[col];
#pragma unroll
          for (int j = 0; j < 4; ++j) {
            float v = acc[mi][ni][j] + bv;
            resb[(size_t)(row + j) * 2048 + (col - 2048)] =
                f2b(v / (1.f + __expf(-v)));
          }
        }
      }
    }
    return;
  }

#pragma unroll
  for (int mi = 0; mi < 4; ++mi) {
    const int row = m0 + wr * 64 + mi * 16 + lg * 4;
#pragma unroll
    for (int ni = 0; ni < 4; ++ni) {
      const int col = n0 + wc * 64 + ni * 16 + lr;
      if (OUTB16) {
        const float bv = bias[col];
#pragma unroll
        for (int j = 0; j < 4; ++j) {
          float v = acc[mi][ni][j] + bv;
          if (SOFTPLUS) v = fmaxf(v, 0.f) + log1pf(__expf(-fabsf(v)));
          upb[(size_t)(row + j) * ldc + col] = f2b(v);
        }
      } else if (PARTIAL == 2) {
        short* Cs = (short*)C + (size_t)blockIdx.z * M * ldc;
#pragma unroll
        for (int j = 0; j < 4; ++j)
          Cs[(size_t)(row + j) * ldc + col] = f2b(acc[mi][ni][j]);
      } else if (col < N) {
        float* Cp = PARTIAL ? C + (size_t)blockIdx.z * M * ldc : C;
        float bv = (bias != nullptr && blockIdx.z == 0) ? bias[col] : 0.f;
#pragma unroll
        for (int j = 0; j < 4; ++j) {
          float v = acc[mi][ni][j] + bv;
          if (SOFTPLUS) v = fmaxf(v, 0.f) + log1pf(__expf(-fabsf(v)));
          Cp[(size_t)(row + j) * ldc + col] = v;
        }
      }
    }
  }
}

// ---- fused prep: castA(x) + transpose-cast of all 4 weights, one dispatch ----
__device__ __forceinline__ void trans_body(const float* __restrict__ in,
                                           short* __restrict__ out,
                                           int R, int C, int bx, int by,
                                           short (*t)[33], int tidx)
{
  const int c0 = bx * 32, r0 = by * 32;
  const int cc = tidx & 31, rr = tidx >> 5;  // rr 0..7
#pragma unroll
  for (int i = 0; i < 4; ++i)
    t[rr + i * 8][cc] = f2b(in[(size_t)(r0 + rr + i * 8) * C + c0 + cc]);
  __syncthreads();
#pragma unroll
  for (int i = 0; i < 4; ++i)
    out[(size_t)(c0 + rr + i * 8) * R + r0 + cc] = t[cc][rr + i * 8];
}

#define PB_CAST  2048
#define PB_WIN   4096
#define PB_WX    192
#define PB_WDT   128
#define PB_WOUT  2048

__global__ __launch_bounds__(256)
void prep_kernel(const float* __restrict__ x,    const float* __restrict__ W_in,
                 const float* __restrict__ W_x,  const float* __restrict__ W_dt,
                 const float* __restrict__ W_out,
                 short* __restrict__ xb,  short* __restrict__ Wib,
                 short* __restrict__ Wxb, short* __restrict__ Wdtb,
                 short* __restrict__ Wob)
{
  __shared__ short t[32][33];
  const int bid = blockIdx.x, tidx = threadIdx.x;
  if (bid < PB_CAST) {
    const int i = bid * 256 + tidx;
    float4 v = *reinterpret_cast<const float4*>(x + (size_t)i * 4);
    *reinterpret_cast<short4*>(xb + (size_t)i * 4) =
        make_short4(f2b(v.x), f2b(v.y), f2b(v.z), f2b(v.w));
  } else if (bid < PB_CAST + PB_WIN) {
    const int b = bid - PB_CAST;
    trans_body(W_in, Wib, 1024, 4096, b % 128, b / 128, t, tidx);
  } else if (bid < PB_CAST + PB_WIN + PB_WX) {
    const int b = bid - PB_CAST - PB_WIN;
    trans_body(W_x, Wxb, 2048, 96, b % 3, b / 3, t, tidx);
  } else if (bid < PB_CAST + PB_WIN + PB_WX + PB_WDT) {
    const int b = bid - PB_CAST - PB_WIN - PB_WX;
    trans_body(W_dt, Wdtb, 64, 2048, b % 64, b / 64, t, tidx);
  } else {
    const int b = bid - PB_CAST - PB_WIN - PB_WX - PB_WDT;
    trans_body(W_out, Wob, 2048, 1024, b % 32, b / 32, t, tidx);
  }
}

// combine 16 split-K partials of GEMM2 -> xp fp32 [2048][96]; dt cols -> dtb bf16
__global__ __launch_bounds__(256)
void combine16_kernel(const float* __restrict__ part, float* __restrict__ xp,
                      short* __restrict__ dtb)
{
  const int gid = blockIdx.x * 256 + threadIdx.x;   // 0 .. 2048*24-1
  const int r = gid / 24, q = gid - r * 24;
  float4 s = make_float4(0.f, 0.f, 0.f, 0.f);
#pragma unroll
  for (int c = 0; c < 16; ++c) {
    const float4 v = *reinterpret_cast<const float4*>(
        part + (size_t)c * 2048 * 96 + (size_t)r * 96 + q * 4);
    s.x += v.x; s.y += v.y; s.z += v.z; s.w += v.w;
  }
  *reinterpret_cast<float4*>(xp + (size_t)r * 96 + q * 4) = s;
  if (q < 16)
    *reinterpret_cast<short4*>(dtb + (size_t)r * 64 + q * 4) =
        make_short4(f2b(s.x), f2b(s.y), f2b(s.z), f2b(s.w));
}

// combine 4 bf16 split-K partials of GEMM4 + bias -> out fp32 [2048][1024]
__global__ __launch_bounds__(256)
void combine4_kernel(const unsigned short* __restrict__ part,
                     const float* __restrict__ bias, float* __restrict__ out)
{
  const int gid = blockIdx.x * 256 + threadIdx.x;   // over 2048*256 float4s
  const int r = gid >> 8, c4 = gid & 255;
  const float4 bv = *reinterpret_cast<const float4*>(bias + c4 * 4);
  float4 s = bv;
#pragma unroll
  for (int z = 0; z < 4; ++z) {
    const ushort4 v = *reinterpret_cast<const ushort4*>(
        part + (size_t)z * 2048 * 1024 + (size_t)r * 1024 + c4 * 4);
    s.x += b2f(v.x); s.y += b2f(v.y); s.z += b2f(v.z); s.w += b2f(v.w);
  }
  *reinterpret_cast<float4*>(out + (size_t)r * 1024 + c4 * 4) = s;
}

// ---- chunked selective scan: thread owns (b, chunk, d) with all 16 n ----
__global__ __launch_bounds__(256, 4)
void scan_pass1(const unsigned short* __restrict__ deltab, const unsigned short* __restrict__ ub,
                const float* __restrict__ xp, const float* __restrict__ A_log,
                float* __restrict__ sdl, float* __restrict__ HS)
{
  const int d = blockIdx.y * 256 + threadIdx.x;
  const int c = blockIdx.x, b = blockIdx.z;
  const int t0 = (b << 10) + c * LC;
  float Ac[16];
#pragma unroll
  for (int q = 0; q < 4; ++q) {
    float4 a = *reinterpret_cast<const float4*>(A_log + (size_t)d * 16 + q * 4);
    Ac[q * 4 + 0] = -__expf(a.x); Ac[q * 4 + 1] = -__expf(a.y);
    Ac[q * 4 + 2] = -__expf(a.z); Ac[q * 4 + 3] = -__expf(a.w);
  }
  float h[16];
#pragma unroll
  for (int n = 0; n < 16; ++n) h[n] = 0.f;
  float sd = 0.f;
  const unsigned short* dp = deltab + (size_t)t0 * 2048 + d;
  const unsigned short* up = ub + (size_t)t0 * 2048 + d;
  const float* xb = xp + (size_t)t0 * 96 + DT_RANK;
#pragma unroll 4
  for (int t = 0; t < LC; ++t) {
    float dl = b2f(dp[(size_t)t * 2048]);
    float ul = b2f(up[(size_t)t * 2048]);
    float Bf[16];
#pragma unroll
    for (int q = 0; q < 4; ++q)
      *reinterpret_cast<float4*>(&Bf[q * 4]) =
          *reinterpret_cast<const float4*>(xb + (size_t)t * 96 + q * 4);
    float dlu = dl * ul;
    sd += dl;
#pragma unroll
    for (int n = 0; n < 16; ++n)
      h[n] = __expf(dl * Ac[n]) * h[n] + dlu * Bf[n];
  }
  sdl[((size_t)b * NC + c) * 2048 + d] = sd;
  float* hs = HS + (((size_t)b * NC + c) * 2048 + d) * 16;
#pragma unroll
  for (int q = 0; q < 4; ++q)
    *reinterpret_cast<float4*>(hs + q * 4) =
        make_float4(h[q * 4], h[q * 4 + 1], h[q * 4 + 2], h[q * 4 + 3]);
}

// pass2: in-place combine over chunks, fully unrolled
__global__ __launch_bounds__(256)
void scan_pass2(const float* __restrict__ sdl, const float* __restrict__ A_log,
                float* __restrict__ HS)
{
  const int gid = blockIdx.x * 256 + threadIdx.x;  // 0..65535
  const int b = gid >> 15, rest = gid & 32767;     // rest = d*16+n
  const int d = rest >> 4;
  const float Ac = -__expf(A_log[rest]);
  float P[NC], S[NC];
#pragma unroll
  for (int c = 0; c < NC; ++c)
    P[c] = sdl[(((size_t)b * NC + c) << 11) + d];
#pragma unroll
  for (int c = 0; c < NC; ++c)
    S[c] = HS[(((size_t)b * NC + c) << 15) + rest];
#pragma unroll
  for (int c = 0; c < NC; ++c)
    P[c] = __expf(P[c] * Ac);
  float h = 0.f;
#pragma unroll
  for (int c = 0; c < NC; ++c) {
    HS[(((size_t)b * NC + c) << 15) + rest] = h;
    h = P[c] * h + S[c];
  }
}

// pass3: scan from HS, local n-reduce, z = y * silu_res (rb already silu'd bf16)
__global__ __launch_bounds__(256, 4)
void scan_pass3(const unsigned short* __restrict__ deltab, const unsigned short* __restrict__ ub,
                const float* __restrict__ xp, const float* __restrict__ A_log,
                const float* __restrict__ HS, const unsigned short* __restrict__ rb,
                short* __restrict__ zb)
{
  const int d = blockIdx.y * 256 + threadIdx.x;
  const int c = blockIdx.x, b = blockIdx.z;
  const int t0 = (b << 10) + c * LC;
  float Ac[16];
#pragma unroll
  for (int q = 0; q < 4; ++q) {
    float4 a = *reinterpret_cast<const float4*>(A_log + (size_t)d * 16 + q * 4);
    Ac[q * 4 + 0] = -__expf(a.x); Ac[q * 4 + 1] = -__expf(a.y);
    Ac[q * 4 + 2] = -__expf(a.z); Ac[q * 4 + 3] = -__expf(a.w);
  }
  float h[16];
  const float* hs = HS + (((size_t)b * NC + c) * 2048 + d) * 16;
#pragma unroll
  for (int q = 0; q < 4; ++q) {
    float4 v = *reinterpret_cast<const float4*>(hs + q * 4);
    h[q * 4 + 0] = v.x; h[q * 4 + 1] = v.y; h[q * 4 + 2] = v.z; h[q * 4 + 3] = v.w;
  }
  const unsigned short* dp = deltab + (size_t)t0 * 2048 + d;
  const unsigned short* up = ub + (size_t)t0 * 2048 + d;
  const float* xb = xp + (size_t)t0 * 96 + DT_RANK;
  const float* xc = xp + (size_t)t0 * 96 + DT_RANK + N_ST;
  const unsigned short* rp = rb + (size_t)t0 * 2048 + d;
  short* zp = zb + (size_t)t0 * 2048 + d;
#pragma unroll 4
  for (int t = 0; t < LC; ++t) {
    float dl = b2f(dp[(size_t)t * 2048]);
    float ul = b2f(up[(size_t)t * 2048]);
    float rv = b2f(rp[(size_t)t * 2048]);   // silu(res) already applied
    float Bf[16], Cf[16];
#pragma unroll
    for (int q = 0; q < 4; ++q) {
      *reinterpret_cast<float4*>(&Bf[q * 4]) =
          *reinterpret_cast<const float4*>(xb + (size_t)t * 96 + q * 4);
      *reinterpret_cast<float4*>(&Cf[q * 4]) =
          *reinterpret_cast<const float4*>(xc + (size_t)t * 96 + q * 4);
    }
    float dlu = dl * ul;
    float p0 = 0.f, p1 = 0.f, p2 = 0.f, p3 = 0.f;
#pragma unroll
    for (int n = 0; n < 16; ++n) {
      h[n] = __expf(dl * Ac[n]) * h[n] + dlu * Bf[n];
      float t2 = h[n] * Cf[n];
      if ((n & 3) == 0) p0 += t2;
      else if ((n & 3) == 1) p1 += t2;
      else if ((n & 3) == 2) p2 += t2;
      else p3 += t2;
    }
    float p = (p0 + p1) + (p2 + p3);
    zp[(size_t)t * 2048] = f2b(p * rv);
  }
}

extern "C" void kernel_launch(void* const* d_in, const int* in_sizes, int n_in,
                              void* d_out, int out_size, void* d_ws, size_t ws_size,
                              hipStream_t stream)
{
  const float* x      = (const float*)d_in[0];
  const float* A_log  = (const float*)d_in[1];
  const float* W_in   = (const float*)d_in[2];
  const float* b_in   = (const float*)d_in[3];
  const float* conv_w = (const float*)d_in[4];
  const float* conv_b = (const float*)d_in[5];
  const float* W_x    = (const float*)d_in[6];
  const float* W_dt   = (const float*)d_in[7];
  const float* b_dt   = (const float*)d_in[8];
  const float* W_out  = (const float*)d_in[9];
  const float* b_out  = (const float*)d_in[10];
  float* out = (float*)d_out;

  // workspace layout (~90 MB)
  char* p = (char*)d_ws;
  short* upb    = (short*)p; p += (size_t)NTOK * 2048 * 2;          // 8MB u_pre bf16 (boundary rows)
  short* rb     = (short*)p; p += (size_t)NTOK * 2048 * 2;          // 8MB silu(res) bf16
  short* ub     = (short*)p; p += (size_t)NTOK * 2048 * 2;          // 8MB
  float* xp     = (float*)p; p += (size_t)NTOK * 96 * 4;            // .75MB dt|B|C fp32
  short* dtb    = (short*)p; p += (size_t)NTOK * 64 * 2;            // .25MB
  short* deltab = (short*)p; p += (size_t)NTOK * 2048 * 2;          // 8MB bf16
  short* zb     = (short*)p; p += (size_t)NTOK * 2048 * 2;          // 8MB
  short* xb     = (short*)p; p += (size_t)NTOK * 1024 * 2;          // 4MB
  short* Wib    = (short*)p; p += (size_t)4096 * 1024 * 2;          // 8MB
  short* Wxb    = (short*)p; p += (size_t)128 * 2048 * 2;           // .5MB (96 rows + pad)
  short* Wdtb   = (short*)p; p += (size_t)2048 * 64 * 2;            // .25MB
  short* Wob    = (short*)p; p += (size_t)1024 * 2048 * 2;          // 4MB
  char*  scr    = p;         p += (size_t)16 * 1024 * 1024;         // 16MB shared scratch
  float* xppart = (float*)scr;  // 16 x 2048 x 96 fp32 = 12.6MB (GEMM2..combine16)
  short* opart  = (short*)scr;  // 4 x 2048 x 1024 bf16 = 16MB (GEMM4..combine4)
  float* sdl    = (float*)p; p += (size_t)BSZ * NC * 2048 * 4;      // .5MB
  float* HS     = (float*)p; p += (size_t)BSZ * NC * 2048 * 16 * 4; // 8MB

  // all pre-casts/transposes in one dispatch
  prep_kernel<<<dim3(PB_CAST + PB_WIN + PB_WX + PB_WDT + PB_WOUT), 256, 0, stream>>>(
      x, W_in, W_x, W_dt, W_out, xb, Wib, Wxb, Wdtb, Wob);

  // GEMM1: upb(boundary u_pre) | ub(conv+silu rows 2..127) | rb(silu(res))
  gemm_kernel<0, 0, 1, 0, 0><<<dim3(32, 16, 1), 256, 0, stream>>>(
      xb, Wib, b_in, nullptr, upb, rb, conv_w, conv_b, ub,
      NTOK, 4096, 1024, 1024, 1024, 0, 1024);
  // xp partials = u @ W_x (split-K 16, no atomics); prologue fixes boundary ub
  gemm_kernel<0, 1, 0, 0, 1><<<dim3(1, 16, 16), 256, 0, stream>>>(
      ub, Wxb, nullptr, xppart, upb, nullptr, conv_w, conv_b, ub,
      NTOK, 96, 2048, 2048, 2048, 96, 128);
  // xp = sum(partials); dtb = bf16(dt cols)
  combine16_kernel<<<dim3(192), 256, 0, stream>>>(xppart, xp, dtb);
  // deltab = bf16(softplus(dt @ W_dt + b_dt))
  gemm_kernel<1, 0, 0, 1, 0><<<dim3(16, 16, 1), 256, 0, stream>>>(
      dtb, Wdtb, b_dt, nullptr, deltab, nullptr, nullptr, nullptr, nullptr,
      NTOK, 2048, 64, 64, 64, 2048, 64);
  // chunked selective scan -> zb (bf16, zmul fused)
  scan_pass1<<<dim3(NC, 8, BSZ), 256, 0, stream>>>(
      (const unsigned short*)deltab, (const unsigned short*)ub, xp, A_log, sdl, HS);
  scan_pass2<<<dim3(256), 256, 0, stream>>>(sdl, A_log, HS);
  scan_pass3<<<dim3(NC, 8, BSZ), 256, 0, stream>>>(
      (const unsigned short*)deltab, (const unsigned short*)ub, xp, A_log, HS,
      (const unsigned short*)rb, zb);
  // opart(bf16) = z @ W_out partials (split-K 4, no atomics)
  gemm_kernel<0, 2, 0, 0, 0><<<dim3(8, 16, 4), 256, 0, stream>>>(
      zb, Wob, nullptr, (float*)opart, nullptr, nullptr, nullptr, nullptr, nullptr,
      NTOK, 1024, 2048, 2048, 2048, 1024, 512);
  // out = sum(partials) + b_out
  combine4_kernel<<<dim3(2048), 256, 0, stream>>>(
      (const unsigned short*)opart, b_out, out);
}